// Round 2
// baseline (3314.127 us; speedup 1.0000x reference)
//
#include <hip/hip_runtime.h>
#include <stdint.h>

// ---------------------------------------------------------------------------
// PerceiverResampler on MI355X (gfx950)
// B=32, F=2048, DIM=1024, INNER=1024, H=16, DH=64, Q=64, DEPTH=6, MULT=2
//
//  - LN-fold: every _ln(x,g,b)@W becomes rownorm(x) @ (diag(g)W) + (b@W).
//  - Mask compaction: only unmasked rows flow through big GEMMs + attention.
//  - Big GEMMs (down-proj, fused K+V): 256x256 8-phase schedule (T2+T3+T4+T5),
//    512 threads, BK=64, counted vmcnt(4), chunk-XOR LDS swizzle.
//  - Small GEMMs (Q, FF1, FF2): 128x128 2-phase m97 structure.
//  - Flash attention: one block per (b,h), online softmax, fused-KV layout.
// ---------------------------------------------------------------------------

#define DEV static __device__ __forceinline__

typedef __attribute__((ext_vector_type(8))) short short8;
typedef __attribute__((ext_vector_type(4))) float f32x4;
typedef __attribute__((ext_vector_type(4))) unsigned short ushort4v;
typedef unsigned short ushort_t;

DEV float bf2f(ushort_t u){ union{uint32_t i; float f;} x; x.i = ((uint32_t)u)<<16; return x.f; }
DEV ushort_t f2bf(float f){
  union{float f; uint32_t i;} x; x.f = f;
  uint32_t r = x.i + 0x7fffu + ((x.i>>16)&1u);  // RNE
  return (ushort_t)(r>>16);
}

#define GLOAD16(gp, lp) __builtin_amdgcn_global_load_lds( \
    (const __attribute__((address_space(1))) uint32_t*)(gp), \
    (__attribute__((address_space(3))) uint32_t*)(lp), 16, 0, 0)

#define VMCNT(n) asm volatile("s_waitcnt vmcnt(" #n ")" ::: "memory")
#define CFENCE   asm volatile("" ::: "memory")
#define MFMA16(a,b,c) __builtin_amdgcn_mfma_f32_16x16x32_bf16(a,b,c,0,0,0)

// ---------------- block reduce (sum of two values, 256 threads) ------------
DEV void reduce2(float& a, float& b){
  #pragma unroll
  for (int d = 32; d; d >>= 1){ a += __shfl_down(a, d); b += __shfl_down(b, d); }
  __shared__ float sh[8];
  int w = threadIdx.x >> 6, l = threadIdx.x & 63;
  if (l == 0){ sh[w*2] = a; sh[w*2+1] = b; }
  __syncthreads();
  a = sh[0]+sh[2]+sh[4]+sh[6];
  b = sh[1]+sh[3]+sh[5]+sh[7];
}

// ---------------- mask compaction ------------------------------------------
__global__ __launch_bounds__(256) void k_compact(const int* __restrict__ mask,
                                                 int* __restrict__ idx, int* __restrict__ cnt){
  int b = blockIdx.x, t = threadIdx.x;
  const int* mb = mask + b*2048;
  int keep[8]; int c = 0;
  #pragma unroll
  for (int u = 0; u < 8; ++u){ keep[u] = (mb[t*8+u] != 0); c += keep[u]; }
  __shared__ int s[256];
  s[t] = c; __syncthreads();
  for (int off = 1; off < 256; off <<= 1){
    int v = (t >= off) ? s[t-off] : 0;
    __syncthreads();
    s[t] += v;
    __syncthreads();
  }
  int pos = s[t] - c;
  #pragma unroll
  for (int u = 0; u < 8; ++u) if (keep[u]) idx[b*2048 + pos++] = t*8 + u;
  if (t == 255) cnt[b] = s[255];
}

// ---------------- gather + rownorm features -> bf16 ------------------------
__global__ __launch_bounds__(256) void k_gather_norm(const float* __restrict__ feat,
        const int* __restrict__ idx, const int* __restrict__ cnt, ushort_t* __restrict__ outp){
  int blk = blockIdx.x; int b = blk >> 11, j = blk & 2047;
  if (j >= cnt[b]) return;
  int src = idx[b*2048 + j];
  const float* row = feat + ((size_t)(b*2048 + src))*1024;
  int t = threadIdx.x;
  float4 v = *(const float4*)(row + t*4);
  float s = v.x+v.y+v.z+v.w;
  float q = v.x*v.x+v.y*v.y+v.z*v.z+v.w*v.w;
  reduce2(s, q);
  float mean = s * (1.f/1024.f);
  float rstd = rsqrtf(q*(1.f/1024.f) - mean*mean + 1e-5f);
  ushort4v o;
  o.x = f2bf((v.x-mean)*rstd); o.y = f2bf((v.y-mean)*rstd);
  o.z = f2bf((v.z-mean)*rstd); o.w = f2bf((v.w-mean)*rstd);
  *(ushort4v*)(outp + ((size_t)(b*2048+j))*1024 + t*4) = o;
}

// ---------------- rownorm bf16 -> bf16 (optional skip) ---------------------
__global__ __launch_bounds__(256) void k_rownorm_bf16(const ushort_t* __restrict__ in,
        ushort_t* __restrict__ outp, const int* __restrict__ cnt){
  int blk = blockIdx.x;
  if (cnt){ int b = blk >> 11; if ((blk & 2047) >= cnt[b]) return; }
  int t = threadIdx.x;
  ushort4v u = *(const ushort4v*)(in + (size_t)blk*1024 + t*4);
  float f0 = bf2f(u.x), f1 = bf2f(u.y), f2 = bf2f(u.z), f3 = bf2f(u.w);
  float s = f0+f1+f2+f3, q = f0*f0+f1*f1+f2*f2+f3*f3;
  reduce2(s, q);
  float mean = s * (1.f/1024.f);
  float rstd = rsqrtf(q*(1.f/1024.f) - mean*mean + 1e-5f);
  ushort4v o;
  o.x = f2bf((f0-mean)*rstd); o.y = f2bf((f1-mean)*rstd);
  o.z = f2bf((f2-mean)*rstd); o.w = f2bf((f3-mean)*rstd);
  *(ushort4v*)(outp + (size_t)blk*1024 + t*4) = o;
}

// ---------------- rownorm f32 -> bf16 --------------------------------------
__global__ __launch_bounds__(256) void k_rownorm_f32(const float* __restrict__ in,
                                                     ushort_t* __restrict__ outp){
  int blk = blockIdx.x, t = threadIdx.x;
  float4 v = *(const float4*)(in + (size_t)blk*1024 + t*4);
  float s = v.x+v.y+v.z+v.w;
  float q = v.x*v.x+v.y*v.y+v.z*v.z+v.w*v.w;
  reduce2(s, q);
  float mean = s * (1.f/1024.f);
  float rstd = rsqrtf(q*(1.f/1024.f) - mean*mean + 1e-5f);
  ushort4v o;
  o.x = f2bf((v.x-mean)*rstd); o.y = f2bf((v.y-mean)*rstd);
  o.z = f2bf((v.z-mean)*rstd); o.w = f2bf((v.w-mean)*rstd);
  *(ushort4v*)(outp + (size_t)blk*1024 + t*4) = o;
}

// ---------------- final layernorm (affine) f32 -> f32 ----------------------
__global__ __launch_bounds__(256) void k_final_ln(const float* __restrict__ x,
        const float* __restrict__ g, const float* __restrict__ bb, float* __restrict__ outp){
  int blk = blockIdx.x, t = threadIdx.x;
  float4 v = *(const float4*)(x + (size_t)blk*1024 + t*4);
  float s = v.x+v.y+v.z+v.w;
  float q = v.x*v.x+v.y*v.y+v.z*v.z+v.w*v.w;
  reduce2(s, q);
  float mean = s * (1.f/1024.f);
  float rstd = rsqrtf(q*(1.f/1024.f) - mean*mean + 1e-5f);
  float4 gg = *(const float4*)(g + t*4);
  float4 bv = *(const float4*)(bb + t*4);
  float4 o;
  o.x = (v.x-mean)*rstd*gg.x + bv.x; o.y = (v.y-mean)*rstd*gg.y + bv.y;
  o.z = (v.z-mean)*rstd*gg.z + bv.z; o.w = (v.w-mean)*rstd*gg.w + bv.w;
  *(float4*)(outp + (size_t)blk*1024 + t*4) = o;
}

// ---------------- x init: broadcast latents --------------------------------
__global__ __launch_bounds__(256) void k_init_x(const float* __restrict__ lat, float* __restrict__ x){
  int v = blockIdx.x*256 + threadIdx.x;
  int row = v >> 8, cv = v & 255;
  ((float4*)x)[v] = ((const float4*)lat)[(row & 63)*256 + cv];
}

// ---------------- weight fold + transpose: Wt[n][k] = g[k]*scale*W[k][n] ---
DEV void foldT_body(const float* __restrict__ W, const float* __restrict__ g,
                    float scale, ushort_t* __restrict__ Wt, int K, int N,
                    int n0, int k0){
  __shared__ float Ts[64][65];
  int t = threadIdx.x;
  #pragma unroll
  for (int i = 0; i < 4; ++i){
    int flat = i*1024 + t*4; int r = flat >> 6, c = flat & 63;
    float4 v = *(const float4*)(W + (size_t)(k0+r)*N + n0 + c);
    float gg = (g ? g[k0+r] : 1.f) * scale;
    Ts[r][c] = v.x*gg; Ts[r][c+1] = v.y*gg; Ts[r][c+2] = v.z*gg; Ts[r][c+3] = v.w*gg;
  }
  __syncthreads();
  #pragma unroll
  for (int i = 0; i < 4; ++i){
    int flat = i*1024 + t*4; int rn = flat >> 6, ck = flat & 63;
    ushort4v o;
    o.x = f2bf(Ts[ck][rn]);   o.y = f2bf(Ts[ck+1][rn]);
    o.z = f2bf(Ts[ck+2][rn]); o.w = f2bf(Ts[ck+3][rn]);
    *(ushort4v*)(Wt + (size_t)(n0+rn)*K + k0 + ck) = o;
  }
}

__global__ __launch_bounds__(256) void k_foldT(const float* __restrict__ W,
        const float* __restrict__ g, float scale, ushort_t* __restrict__ Wt, int K, int N){
  foldT_body(W, g, scale, Wt, K, N, blockIdx.x*64, blockIdx.y*64);
}

// batched Q/K/V fold (z: 0=Q,1=K,2=V). all are 1024x1024.
__global__ __launch_bounds__(256) void k_foldT3(const float* __restrict__ Wq,
        const float* __restrict__ Wk, const float* __restrict__ Wv,
        const float* __restrict__ gq, const float* __restrict__ gkv, float scaleq,
        ushort_t* __restrict__ WQT, ushort_t* __restrict__ WKVT){
  int z = blockIdx.z;
  const float* W = (z==0) ? Wq : (z==1) ? Wk : Wv;
  const float* g = (z==0) ? gq : gkv;
  float sc = (z==0) ? scaleq : 1.f;
  ushort_t* outp = (z==0) ? WQT : WKVT + (size_t)(z-1)*1024*1024;
  foldT_body(W, g, sc, outp, 1024, 1024, blockIdx.x*64, blockIdx.y*64);
}

// ---------------- bias fold: bias[o] = scale * sum_c bvec[c]*W[c][o] -------
DEV void foldBias_body(const float* __restrict__ W, const float* __restrict__ bvec,
                       float scale, float* __restrict__ bias, int K, int N, int o0){
  int t = threadIdx.x;
  int ol = t & 31, kc = t >> 5;
  int o = o0 + ol;
  int chunk = K >> 3;
  int c0 = kc*chunk, c1 = c0 + chunk;
  float s0 = 0, s1 = 0, s2 = 0, s3 = 0;
  for (int c = c0; c < c1; c += 4){
    s0 += bvec[c+0]*W[(size_t)(c+0)*N + o];
    s1 += bvec[c+1]*W[(size_t)(c+1)*N + o];
    s2 += bvec[c+2]*W[(size_t)(c+2)*N + o];
    s3 += bvec[c+3]*W[(size_t)(c+3)*N + o];
  }
  __shared__ float red[8][32];
  red[kc][ol] = (s0+s1)+(s2+s3);
  __syncthreads();
  if (kc == 0){
    float tot = 0;
    #pragma unroll
    for (int jj = 0; jj < 8; ++jj) tot += red[jj][ol];
    bias[o] = tot * scale;
  }
}

__global__ __launch_bounds__(256) void k_foldBias(const float* __restrict__ W,
        const float* __restrict__ bvec, float scale, float* __restrict__ bias, int K, int N){
  foldBias_body(W, bvec, scale, bias, K, N, blockIdx.x*32);
}

__global__ __launch_bounds__(256) void k_foldBias3(const float* __restrict__ Wq,
        const float* __restrict__ Wk, const float* __restrict__ Wv,
        const float* __restrict__ bq, const float* __restrict__ bkv, float scaleq,
        float* __restrict__ BQ, float* __restrict__ BKV){
  int z = blockIdx.z;
  const float* W = (z==0) ? Wq : (z==1) ? Wk : Wv;
  const float* bv = (z==0) ? bq : bkv;
  float sc = (z==0) ? scaleq : 1.f;
  float* outp = (z==0) ? BQ : BKV + (z-1)*1024;
  foldBias_body(W, bv, sc, outp, 1024, 1024, blockIdx.x*32);
}

// ---------------- 128x128 2-phase GEMM (small shapes) ----------------------
// OUTMODE: 0 = bf16 store, 1 = bf16 relu store, 2 = f32 accumulate (C += v)
template<int OUTMODE, bool SKIP>
__global__ __launch_bounds__(256) void k_gemm(const ushort_t* __restrict__ A,
        const ushort_t* __restrict__ Bt, const float* __restrict__ bias,
        void* __restrict__ Cp, int M, int N, int K, const int* __restrict__ cnt){
  const int n0 = blockIdx.x * 128;
  const int m0 = blockIdx.y * 128;
  if (SKIP){ int b = m0 >> 11; if ((m0 & 2047) >= cnt[b]) return; }
  __shared__ ushort_t sA[2][128*32];
  __shared__ ushort_t sB[2][128*32];
  const int tid = threadIdx.x;
  const int wave = tid >> 6, lane = tid & 63;
  const int lo = lane & 15, hi = lane >> 4;
  const int wr = wave >> 1, wc = wave & 1;

  auto stage = [&](int buf, int k0){
    #pragma unroll
    for (int p = 0; p < 2; ++p){
      int r = p*64 + wave*16 + (lane >> 2);
      int c = lane & 3;
      {
        const ushort_t* gp = A + (size_t)(m0 + r)*K + k0 + c*8;
        char* lp = (char*)(&sA[buf][0]) + p*4096 + wave*1024;
        GLOAD16(gp, lp);
      }
      {
        const ushort_t* gp = Bt + (size_t)(n0 + r)*K + k0 + c*8;
        char* lp = (char*)(&sB[buf][0]) + p*4096 + wave*1024;
        GLOAD16(gp, lp);
      }
    }
  };

  f32x4 acc[4][4] = {};
  stage(0, 0);
  const int nk = K >> 5;
  for (int ks = 0; ks < nk; ++ks){
    __syncthreads();
    if (ks + 1 < nk) stage((ks+1)&1, (ks+1) << 5);
    const int buf = ks & 1;
    short8 af[4], bfr[4];
    #pragma unroll
    for (int mi = 0; mi < 4; ++mi)
      af[mi] = *(const short8*)(&sA[buf][(wr*64 + mi*16 + lo)*32 + hi*8]);
    #pragma unroll
    for (int ni = 0; ni < 4; ++ni)
      bfr[ni] = *(const short8*)(&sB[buf][(wc*64 + ni*16 + lo)*32 + hi*8]);
    #pragma unroll
    for (int mi = 0; mi < 4; ++mi)
      #pragma unroll
      for (int ni = 0; ni < 4; ++ni)
        acc[mi][ni] = MFMA16(af[mi], bfr[ni], acc[mi][ni]);
  }
  #pragma unroll
  for (int ni = 0; ni < 4; ++ni){
    int col = n0 + wc*64 + ni*16 + lo;
    float bv = bias ? bias[col] : 0.f;
    #pragma unroll
    for (int mi = 0; mi < 4; ++mi){
      int rbase = m0 + wr*64 + mi*16 + hi*4;
      #pragma unroll
      for (int rr = 0; rr < 4; ++rr){
        float v = acc[mi][ni][rr] + bv;
        size_t off = (size_t)(rbase + rr)*N + col;
        if (OUTMODE == 0)      ((ushort_t*)Cp)[off] = f2bf(v);
        else if (OUTMODE == 1) ((ushort_t*)Cp)[off] = f2bf(fmaxf(v, 0.f));
        else                   ((float*)Cp)[off] += v;
      }
    }
  }
}

// ---------------- 256x256 8-phase GEMM (big shapes) ------------------------
// T2 chunk-XOR swizzle + T3/T4 counted-vmcnt 8-phase + T5 setprio.
// 512 threads (8 waves: wm=wave>>2 in {0,1}, wn=wave&3 in {0..3}).
// Wave output: rows {a*128 + wm*64 + [0,64)} x cols {b*128 + wn*32 + [0,32)},
// a,b = quadrant. Phase reads only A-half a / B-half b => staging a half-tile
// per phase is race-free with barriers only (no vmcnt(0) in main loop).
template<bool SKIP>
__global__ __launch_bounds__(512, 2) void k_gemm256(const ushort_t* __restrict__ A,
        const ushort_t* __restrict__ Bt, const float* __restrict__ bias,
        ushort_t* __restrict__ Cp, int M, int N, int K, const int* __restrict__ cnt){
  const int n0 = blockIdx.x * 256;
  const int m0 = blockIdx.y * 256;
  if (SKIP){ int b = m0 >> 11; if ((m0 & 2047) >= cnt[b]) return; }
  __shared__ __align__(16) ushort_t sA[2][256*64];
  __shared__ __align__(16) ushort_t sB[2][256*64];
  const int tid = threadIdx.x;
  const int wave = tid >> 6, lane = tid & 63;
  const int lo = lane & 15, hi = lane >> 4;
  const int wm = wave >> 2, wn = wave & 3;
  const int srow = lane >> 3;                 // 0..7 within wave's 8-row stripe
  const int schunk = (lane & 7) ^ srow;       // pre-swizzled global chunk

  // one call stages 64 rows (8/wave); half-tile = 2 calls (128 rows, 1 operand)
  auto stageHalf = [&](ushort_t* dst, const ushort_t* __restrict__ G, int grow0,
                       int half, int k0){
    #pragma unroll
    for (int p = 0; p < 2; ++p){
      int rbase = half*128 + p*64 + wave*8;
      const ushort_t* gp = G + (size_t)(grow0 + rbase + srow)*K + k0 + schunk*8;
      char* lp = (char*)dst + (size_t)rbase*128;
      GLOAD16(gp, lp);
    }
  };
  auto ldsA = [&](int buf, int row, int kk)->short8{
    int ch = ((kk<<2) + hi) ^ (row & 7);
    return *(const short8*)((const char*)sA + (size_t)buf*32768 + (size_t)row*128 + ch*16);
  };
  auto ldsB = [&](int buf, int row, int kk)->short8{
    int ch = ((kk<<2) + hi) ^ (row & 7);
    return *(const short8*)((const char*)sB + (size_t)buf*32768 + (size_t)row*128 + ch*16);
  };

  f32x4 acc[8][4] = {};

#define PH(BUF, AH, BH, FEN, ...) do { \
    short8 af_[4][2], bg_[2][2]; \
    _Pragma("unroll") for (int mi4_ = 0; mi4_ < 4; ++mi4_) \
      _Pragma("unroll") for (int kk_ = 0; kk_ < 2; ++kk_) \
        af_[mi4_][kk_] = ldsA(BUF, (AH)*128 + wm*64 + mi4_*16 + lo, kk_); \
    _Pragma("unroll") for (int nj_ = 0; nj_ < 2; ++nj_) \
      _Pragma("unroll") for (int kk_ = 0; kk_ < 2; ++kk_) \
        bg_[nj_][kk_] = ldsB(BUF, (BH)*128 + wn*32 + nj_*16 + lo, kk_); \
    __VA_ARGS__; \
    FEN; \
    __builtin_amdgcn_s_barrier(); \
    CFENCE; \
    __builtin_amdgcn_s_setprio(1); \
    _Pragma("unroll") for (int mi4_ = 0; mi4_ < 4; ++mi4_) \
      _Pragma("unroll") for (int nj_ = 0; nj_ < 2; ++nj_) \
        _Pragma("unroll") for (int kk_ = 0; kk_ < 2; ++kk_) \
          acc[(AH)*4+mi4_][(BH)*2+nj_] = \
            MFMA16(af_[mi4_][kk_], bg_[nj_][kk_], acc[(AH)*4+mi4_][(BH)*2+nj_]); \
    __builtin_amdgcn_s_setprio(0); \
    CFENCE; \
    __builtin_amdgcn_s_barrier(); \
    CFENCE; \
  } while(0)

  // prologue: tile0 -> buf0 (all 4 halves), tile1 -> buf1 (A-H0, B-H0)
  stageHalf(&sA[0][0], A,  m0, 0, 0);
  stageHalf(&sB[0][0], Bt, n0, 0, 0);
  stageHalf(&sA[0][0], A,  m0, 1, 0);
  stageHalf(&sB[0][0], Bt, n0, 1, 0);
  stageHalf(&sA[1][0], A,  m0, 0, 64);
  stageHalf(&sB[1][0], Bt, n0, 0, 64);
  VMCNT(4);                      // tile0 (first 8 calls) complete
  __builtin_amdgcn_s_barrier();
  CFENCE;

  const int NI = K >> 7;         // 2 K-tiles (of 64) per iteration
  for (int i = 0; i < NI; ++i){
    const int kt0 = i << 7;
    const bool lastI = (i == NI-1);
    // phases 1-4: tile 2i from buf0; phases 5-8: tile 2i+1 from buf1
    PH(0, 0, 0, (void)0,                       stageHalf(&sA[1][0], A,  m0, 1, kt0+64));
    PH(0, 0, 1, (void)0,                       stageHalf(&sB[1][0], Bt, n0, 1, kt0+64));
    PH(0, 1, 0, (void)0,                       if(!lastI) stageHalf(&sA[0][0], A,  m0, 0, kt0+128));
    PH(0, 1, 1, if(lastI){VMCNT(0);}else{VMCNT(4);}, if(!lastI) stageHalf(&sB[0][0], Bt, n0, 0, kt0+128));
    PH(1, 0, 0, (void)0,                       if(!lastI) stageHalf(&sA[0][0], A,  m0, 1, kt0+128));
    PH(1, 0, 1, (void)0,                       if(!lastI) stageHalf(&sB[0][0], Bt, n0, 1, kt0+128));
    PH(1, 1, 0, (void)0,                       if(!lastI) stageHalf(&sA[1][0], A,  m0, 0, kt0+192));
    PH(1, 1, 1, if(!lastI){VMCNT(4);},         if(!lastI) stageHalf(&sB[1][0], Bt, n0, 0, kt0+192));
  }
#undef PH

  // epilogue: bias + bf16 store
  #pragma unroll
  for (int b2 = 0; b2 < 2; ++b2)
    #pragma unroll
    for (int nj = 0; nj < 2; ++nj){
      int col = n0 + b2*128 + wn*32 + nj*16 + lo;
      float bv = bias ? bias[col] : 0.f;
      #pragma unroll
      for (int a2 = 0; a2 < 2; ++a2)
        #pragma unroll
        for (int mi4 = 0; mi4 < 4; ++mi4){
          int rbase = m0 + a2*128 + wm*64 + mi4*16 + hi*4;
          #pragma unroll
          for (int rr = 0; rr < 4; ++rr){
            float v = acc[a2*4+mi4][b2*2+nj][rr] + bv;
            Cp[(size_t)(rbase + rr)*N + col] = f2bf(v);
          }
        }
    }
}

// ---------------- flash attention: one block per (b,h), fused KV -----------
// kvb layout: [b*2048 + j][2048]; cols 0..1023 = K row, 1024..2047 = V row.
__global__ __launch_bounds__(256) void k_attn(const ushort_t* __restrict__ qb,
        const ushort_t* __restrict__ kvb, const int* __restrict__ cnt,
        ushort_t* __restrict__ outb){
  const int bh = blockIdx.x;
  const int b = bh >> 4, h = bh & 15;
  const int t = threadIdx.x;
  const int wave = t >> 6, lane = t & 63, lo = lane & 15, hi = lane >> 4;
  __shared__ ushort_t Qs[64*64];       // [q][d], chunk-swizzled
  __shared__ ushort_t Ks[64*64];       // [j][d], chunk-swizzled
  __shared__ ushort_t Vt[64][72];      // [d][j], padded
  __shared__ ushort_t Ps[4][16][72];   // per-wave P stripe [q][j], padded

  const int count = cnt[b];

  #pragma unroll
  for (int p = 0; p < 2; ++p){
    int r = p*32 + wave*8 + (lane >> 3);
    int c = (lane & 7) ^ (r & 7);
    const ushort_t* gp = qb + (size_t)(b*64 + r)*1024 + h*64 + c*8;
    char* lp = (char*)Qs + p*4096 + wave*1024;
    GLOAD16(gp, lp);
  }

  f32x4 oacc[4] = {};
  float m[4], l[4];
  #pragma unroll
  for (int rr = 0; rr < 4; ++rr){ m[rr] = -__builtin_inff(); l[rr] = 0.f; }

  const int ntiles = (count + 63) >> 6;
  for (int tt = 0; tt < ntiles; ++tt){
    __syncthreads();
    // stage K tile
    #pragma unroll
    for (int p = 0; p < 2; ++p){
      int r = p*32 + wave*8 + (lane >> 3);
      int c = (lane & 7) ^ (r & 7);
      const ushort_t* gp = kvb + (size_t)(b*2048 + tt*64 + r)*2048 + h*64 + c*8;
      char* lp = (char*)Ks + p*4096 + wave*1024;
      GLOAD16(gp, lp);
    }
    // stage V^T (pair-packed b32 stores); zero tail rows
    {
      int jj = (t & 31)*2, c = (t >> 5)*8;
      const ushort_t* g0 = kvb + (size_t)(b*2048 + tt*64 + jj)*2048 + 1024 + h*64 + c;
      ushort4v a0 = *(const ushort4v*)(g0);
      ushort4v a1 = *(const ushort4v*)(g0 + 4);
      ushort4v b0 = *(const ushort4v*)(g0 + 2048);
      ushort4v b1 = *(const ushort4v*)(g0 + 2052);
      bool va  = (tt*64 + jj)     < count;
      bool vb2 = (tt*64 + jj + 1) < count;
      #pragma unroll
      for (int u = 0; u < 8; ++u){
        ushort_t ea = (u < 4) ? ((ushort_t*)&a0)[u] : ((ushort_t*)&a1)[u-4];
        ushort_t eb = (u < 4) ? ((ushort_t*)&b0)[u] : ((ushort_t*)&b1)[u-4];
        uint32_t word = (va ? (uint32_t)ea : 0u) | ((vb2 ? (uint32_t)eb : 0u) << 16);
        *(uint32_t*)(&Vt[c+u][jj]) = word;
      }
    }
    __syncthreads();

    // S = Q @ K^T
    f32x4 s[4] = {};
    #pragma unroll
    for (int kk = 0; kk < 2; ++kk){
      int rA = wave*16 + lo;
      short8 aq = *(const short8*)(&Qs[rA*64 + (((kk*4 + hi) ^ (rA & 7))*8)]);
      #pragma unroll
      for (int ni = 0; ni < 4; ++ni){
        int rB = ni*16 + lo;
        short8 bk = *(const short8*)(&Ks[rB*64 + (((kk*4 + hi) ^ (rB & 7))*8)]);
        s[ni] = MFMA16(aq, bk, s[ni]);
      }
    }
    #pragma unroll
    for (int ni = 0; ni < 4; ++ni){
      if (tt*64 + ni*16 + lo >= count){
        s[ni][0] = s[ni][1] = s[ni][2] = s[ni][3] = -__builtin_inff();
      }
    }
    // online softmax
    float p[4][4];
    #pragma unroll
    for (int rr = 0; rr < 4; ++rr){
      float mx = fmaxf(fmaxf(s[0][rr], s[1][rr]), fmaxf(s[2][rr], s[3][rr]));
      #pragma unroll
      for (int d = 1; d < 16; d <<= 1) mx = fmaxf(mx, __shfl_xor(mx, d));
      float mnew = fmaxf(m[rr], mx);
      float sc = __expf(m[rr] - mnew);
      float rsum = 0.f;
      #pragma unroll
      for (int ni = 0; ni < 4; ++ni){
        float pv = __expf(s[ni][rr] - mnew);
        p[ni][rr] = pv;
        rsum += pv;
      }
      #pragma unroll
      for (int d = 1; d < 16; d <<= 1) rsum += __shfl_xor(rsum, d);
      l[rr] = l[rr]*sc + rsum;
      m[rr] = mnew;
      #pragma unroll
      for (int ni = 0; ni < 4; ++ni) oacc[ni][rr] *= sc;
    }
    // P -> LDS (C-layout), re-read as A-layout for PV
    #pragma unroll
    for (int ni = 0; ni < 4; ++ni)
      #pragma unroll
      for (int rr = 0; rr < 4; ++rr)
        Ps[wave][hi*4+rr][ni*16+lo] = f2bf(p[ni][rr]);
    asm volatile("s_waitcnt lgkmcnt(0)" ::: "memory");
    #pragma unroll
    for (int kk = 0; kk < 2; ++kk){
      short8 pa = *(const short8*)(&Ps[wave][lo][kk*32 + hi*8]);
      #pragma unroll
      for (int ni = 0; ni < 4; ++ni){
        short8 bv = *(const short8*)(&Vt[ni*16 + lo][kk*32 + hi*8]);
        oacc[ni] = MFMA16(pa, bv, oacc[ni]);
      }
    }
  }
  #pragma unroll
  for (int rr = 0; rr < 4; ++rr){
    float inv = (l[rr] > 0.f) ? 1.f/l[rr] : 0.f;
    #pragma unroll
    for (int ni = 0; ni < 4; ++ni){
      size_t off = (size_t)(b*64 + wave*16 + hi*4 + rr)*1024 + h*64 + ni*16 + lo;
      outb[off] = f2bf(oacc[ni][rr] * inv);
    }
  }
}

// ---------------------------------------------------------------------------
extern "C" void kernel_launch(void* const* d_in, const int* in_sizes, int n_in,
                              void* d_out, int out_size, void* d_ws, size_t ws_size,
                              hipStream_t stream){
  const float* features = (const float*)d_in[0];
  const int*   mask     = (const int*)  d_in[1];
  const float* latents  = (const float*)d_in[2];
  const float* W_down   = (const float*)d_in[3];
  const float* nin_g    = (const float*)d_in[4];
  const float* nin_b    = (const float*)d_in[5];
  const float* lf_g     = (const float*)d_in[6];
  const float* lf_b     = (const float*)d_in[7];
  const float* ll_g     = (const float*)d_in[8];
  const float* ll_b     = (const float*)d_in[9];
  const float* Wq       = (const float*)d_in[10];
  const float* Wk       = (const float*)d_in[11];
  const float* Wv       = (const float*)d_in[12];
  const float* ffln_g   = (const float*)d_in[13];
  const float* ffln_b   = (const float*)d_in[14];
  const float* ff_w1    = (const float*)d_in[15];
  const float* ff_w2    = (const float*)d_in[16];
  const float* nout_g   = (const float*)d_in[17];
  const float* nout_b   = (const float*)d_in[18];

  char* ws = (char*)d_ws;
  size_t off = 0;
  auto alloc = [&](size_t bytes)->char*{
    char* p = ws + off;
    off += (bytes + 255) & ~(size_t)255;
    return p;
  };
  ushort_t* FHAT  = (ushort_t*)alloc((size_t)65536*1024*2);   // 128 MB
  ushort_t* KVBUF = (ushort_t*)alloc((size_t)65536*2048*2);   // 256 MB
  ushort_t* WQT   = (ushort_t*)alloc((size_t)1024*1024*2);
  ushort_t* WKVT  = (ushort_t*)alloc((size_t)2048*1024*2);
  ushort_t* W1T   = (ushort_t*)alloc((size_t)2048*1024*2);
  ushort_t* W2T   = (ushort_t*)alloc((size_t)2048*1024*2);
  ushort_t* WDT   = (ushort_t*)alloc((size_t)1024*1024*2);
  float* BD  = (float*)alloc(1024*4);
  float* BQv = (float*)alloc(1024*4);
  float* BKV = (float*)alloc(2048*4);
  float* B1v = (float*)alloc(2048*4);
  float*    X    = (float*)   alloc((size_t)2048*1024*4);
  ushort_t* XHAT = (ushort_t*)alloc((size_t)2048*1024*2);
  ushort_t* QP   = (ushort_t*)alloc((size_t)2048*1024*2);
  ushort_t* OUTB = (ushort_t*)alloc((size_t)2048*1024*2);
  ushort_t* OUTH = (ushort_t*)alloc((size_t)2048*1024*2);
  ushort_t* H1   = (ushort_t*)alloc((size_t)2048*2048*2);
  int* CNT = (int*)alloc(32*4);
  int* IDX = (int*)alloc((size_t)65536*4);
  ushort_t* FNORM = KVBUF;   // transient alias (consumed before KV GEMM writes)
  (void)ws_size; (void)in_sizes; (void)n_in; (void)out_size;

  // ---- setup ----
  k_compact    <<<32,    256, 0, stream>>>(mask, IDX, CNT);
  k_gather_norm<<<65536, 256, 0, stream>>>(features, IDX, CNT, FNORM);
  k_foldT      <<<dim3(16,16), 256, 0, stream>>>(W_down, nin_g, 1.f, WDT, 1024, 1024);
  k_foldBias   <<<32,    256, 0, stream>>>(W_down, nin_b, 1.f, BD, 1024, 1024);
  k_gemm256<true><<<dim3(4,256), 512, 0, stream>>>(FNORM, WDT, BD, FHAT, 65536, 1024, 1024, CNT);
  k_rownorm_bf16<<<65536, 256, 0, stream>>>(FHAT, FHAT, CNT);
  k_init_x     <<<2048,  256, 0, stream>>>(latents, X);

  const float scale = 0.125f;  // DH^-0.5
  for (int i = 0; i < 6; ++i){
    const float* Wqi = Wq + (size_t)i*1024*1024;
    const float* Wki = Wk + (size_t)i*1024*1024;
    const float* Wvi = Wv + (size_t)i*1024*1024;
    const float* W1i = ff_w1 + (size_t)i*1024*2048;
    const float* W2i = ff_w2 + (size_t)i*2048*1024;

    k_foldT3  <<<dim3(16,16,3), 256, 0, stream>>>(Wqi, Wki, Wvi,
                  ll_g + i*1024, lf_g + i*1024, scale, WQT, WKVT);
    k_foldBias3<<<dim3(32,1,3), 256, 0, stream>>>(Wqi, Wki, Wvi,
                  ll_b + i*1024, lf_b + i*1024, scale, BQv, BKV);
    k_foldT   <<<dim3(32,16), 256, 0, stream>>>(W1i, ffln_g + i*1024, 1.f, W1T, 1024, 2048);
    k_foldBias<<<64, 256, 0, stream>>>(W1i, ffln_b + i*1024, 1.f, B1v, 1024, 2048);
    k_foldT   <<<dim3(16,32), 256, 0, stream>>>(W2i, nullptr, 1.f, W2T, 2048, 1024);

    k_rownorm_f32<<<2048, 256, 0, stream>>>(X, XHAT);
    k_gemm<0,false><<<dim3(8,16),  256, 0, stream>>>(XHAT, WQT, BQv, QP, 2048, 1024, 1024, nullptr);
    k_gemm256<true><<<dim3(8,256), 512, 0, stream>>>(FHAT, WKVT, BKV, KVBUF, 65536, 2048, 1024, CNT);
    k_attn<<<512, 256, 0, stream>>>(QP, KVBUF, CNT, OUTB);
    k_rownorm_bf16<<<2048, 256, 0, stream>>>(OUTB, OUTH, nullptr);
    k_gemm<1,false><<<dim3(16,16), 256, 0, stream>>>(OUTH, W1T, B1v, H1, 2048, 2048, 1024, nullptr);
    k_gemm<2,false><<<dim3(8,16),  256, 0, stream>>>(H1, W2T, nullptr, X, 2048, 1024, 2048, nullptr);
  }
  k_final_ln<<<2048, 256, 0, stream>>>(X, nout_g, nout_b, (float*)d_out);
}

// Round 3
// 2638.333 us; speedup vs baseline: 1.2561x; 1.2561x over previous
//
#include <hip/hip_runtime.h>
#include <stdint.h>

// ---------------------------------------------------------------------------
// PerceiverResampler on MI355X (gfx950)
// B=32, F=2048, DIM=1024, INNER=1024, H=16, DH=64, Q=64, DEPTH=6, MULT=2
//
// Round 3: XCD-locality remap for all big GEMMs + 3-way A/B of GEMM structure
// on the 6 identical KV GEMMs (depths {0,3}=8-phase256, {1,4}=2-phase256,
// {2,5}=2-phase128). rocprof separates them by dispatch.
// ---------------------------------------------------------------------------

#define DEV static __device__ __forceinline__

typedef __attribute__((ext_vector_type(8))) short short8;
typedef __attribute__((ext_vector_type(4))) float f32x4;
typedef __attribute__((ext_vector_type(4))) unsigned short ushort4v;
typedef unsigned short ushort_t;

DEV float bf2f(ushort_t u){ union{uint32_t i; float f;} x; x.i = ((uint32_t)u)<<16; return x.f; }
DEV ushort_t f2bf(float f){
  union{float f; uint32_t i;} x; x.f = f;
  uint32_t r = x.i + 0x7fffu + ((x.i>>16)&1u);  // RNE
  return (ushort_t)(r>>16);
}

#define GLOAD16(gp, lp) __builtin_amdgcn_global_load_lds( \
    (const __attribute__((address_space(1))) uint32_t*)(gp), \
    (__attribute__((address_space(3))) uint32_t*)(lp), 16, 0, 0)

#define VMCNT(n) asm volatile("s_waitcnt vmcnt(" #n ")" ::: "memory")
#define CFENCE   asm volatile("" ::: "memory")
#define MFMA16(a,b,c) __builtin_amdgcn_mfma_f32_16x16x32_bf16(a,b,c,0,0,0)

// XCD-locality remap: all NXB N-blocks of one M-row land on the same XCD.
// g in [0, NYB*NXB), NYB*NXB % 8 == 0. xcd = g&7 (round-robin dispatch).
template<int LOG_NXB>
DEV void xcd_remap(int g, int total, int& x, int& y){
  int xcd = g & 7;
  int k = g >> 3;
  int rows_per_xcd = (total >> LOG_NXB) >> 3;
  y = xcd * rows_per_xcd + (k >> LOG_NXB);
  x = k & ((1 << LOG_NXB) - 1);
}

// ---------------- block reduce (sum of two values, 256 threads) ------------
DEV void reduce2(float& a, float& b){
  #pragma unroll
  for (int d = 32; d; d >>= 1){ a += __shfl_down(a, d); b += __shfl_down(b, d); }
  __shared__ float sh[8];
  int w = threadIdx.x >> 6, l = threadIdx.x & 63;
  if (l == 0){ sh[w*2] = a; sh[w*2+1] = b; }
  __syncthreads();
  a = sh[0]+sh[2]+sh[4]+sh[6];
  b = sh[1]+sh[3]+sh[5]+sh[7];
}

// ---------------- mask compaction ------------------------------------------
__global__ __launch_bounds__(256) void k_compact(const int* __restrict__ mask,
                                                 int* __restrict__ idx, int* __restrict__ cnt){
  int b = blockIdx.x, t = threadIdx.x;
  const int* mb = mask + b*2048;
  int keep[8]; int c = 0;
  #pragma unroll
  for (int u = 0; u < 8; ++u){ keep[u] = (mb[t*8+u] != 0); c += keep[u]; }
  __shared__ int s[256];
  s[t] = c; __syncthreads();
  for (int off = 1; off < 256; off <<= 1){
    int v = (t >= off) ? s[t-off] : 0;
    __syncthreads();
    s[t] += v;
    __syncthreads();
  }
  int pos = s[t] - c;
  #pragma unroll
  for (int u = 0; u < 8; ++u) if (keep[u]) idx[b*2048 + pos++] = t*8 + u;
  if (t == 255) cnt[b] = s[255];
}

// ---------------- gather + rownorm features -> bf16 ------------------------
__global__ __launch_bounds__(256) void k_gather_norm(const float* __restrict__ feat,
        const int* __restrict__ idx, const int* __restrict__ cnt, ushort_t* __restrict__ outp){
  int blk = blockIdx.x; int b = blk >> 11, j = blk & 2047;
  if (j >= cnt[b]) return;
  int src = idx[b*2048 + j];
  const float* row = feat + ((size_t)(b*2048 + src))*1024;
  int t = threadIdx.x;
  float4 v = *(const float4*)(row + t*4);
  float s = v.x+v.y+v.z+v.w;
  float q = v.x*v.x+v.y*v.y+v.z*v.z+v.w*v.w;
  reduce2(s, q);
  float mean = s * (1.f/1024.f);
  float rstd = rsqrtf(q*(1.f/1024.f) - mean*mean + 1e-5f);
  ushort4v o;
  o.x = f2bf((v.x-mean)*rstd); o.y = f2bf((v.y-mean)*rstd);
  o.z = f2bf((v.z-mean)*rstd); o.w = f2bf((v.w-mean)*rstd);
  *(ushort4v*)(outp + ((size_t)(b*2048+j))*1024 + t*4) = o;
}

// ---------------- rownorm bf16 -> bf16 (optional skip) ---------------------
__global__ __launch_bounds__(256) void k_rownorm_bf16(const ushort_t* __restrict__ in,
        ushort_t* __restrict__ outp, const int* __restrict__ cnt){
  int blk = blockIdx.x;
  if (cnt){ int b = blk >> 11; if ((blk & 2047) >= cnt[b]) return; }
  int t = threadIdx.x;
  ushort4v u = *(const ushort4v*)(in + (size_t)blk*1024 + t*4);
  float f0 = bf2f(u.x), f1 = bf2f(u.y), f2 = bf2f(u.z), f3 = bf2f(u.w);
  float s = f0+f1+f2+f3, q = f0*f0+f1*f1+f2*f2+f3*f3;
  reduce2(s, q);
  float mean = s * (1.f/1024.f);
  float rstd = rsqrtf(q*(1.f/1024.f) - mean*mean + 1e-5f);
  ushort4v o;
  o.x = f2bf((f0-mean)*rstd); o.y = f2bf((f1-mean)*rstd);
  o.z = f2bf((f2-mean)*rstd); o.w = f2bf((f3-mean)*rstd);
  *(ushort4v*)(outp + (size_t)blk*1024 + t*4) = o;
}

// ---------------- rownorm f32 -> bf16 --------------------------------------
__global__ __launch_bounds__(256) void k_rownorm_f32(const float* __restrict__ in,
                                                     ushort_t* __restrict__ outp){
  int blk = blockIdx.x, t = threadIdx.x;
  float4 v = *(const float4*)(in + (size_t)blk*1024 + t*4);
  float s = v.x+v.y+v.z+v.w;
  float q = v.x*v.x+v.y*v.y+v.z*v.z+v.w*v.w;
  reduce2(s, q);
  float mean = s * (1.f/1024.f);
  float rstd = rsqrtf(q*(1.f/1024.f) - mean*mean + 1e-5f);
  ushort4v o;
  o.x = f2bf((v.x-mean)*rstd); o.y = f2bf((v.y-mean)*rstd);
  o.z = f2bf((v.z-mean)*rstd); o.w = f2bf((v.w-mean)*rstd);
  *(ushort4v*)(outp + (size_t)blk*1024 + t*4) = o;
}

// ---------------- final layernorm (affine) f32 -> f32 ----------------------
__global__ __launch_bounds__(256) void k_final_ln(const float* __restrict__ x,
        const float* __restrict__ g, const float* __restrict__ bb, float* __restrict__ outp){
  int blk = blockIdx.x, t = threadIdx.x;
  float4 v = *(const float4*)(x + (size_t)blk*1024 + t*4);
  float s = v.x+v.y+v.z+v.w;
  float q = v.x*v.x+v.y*v.y+v.z*v.z+v.w*v.w;
  reduce2(s, q);
  float mean = s * (1.f/1024.f);
  float rstd = rsqrtf(q*(1.f/1024.f) - mean*mean + 1e-5f);
  float4 gg = *(const float4*)(g + t*4);
  float4 bv = *(const float4*)(bb + t*4);
  float4 o;
  o.x = (v.x-mean)*rstd*gg.x + bv.x; o.y = (v.y-mean)*rstd*gg.y + bv.y;
  o.z = (v.z-mean)*rstd*gg.z + bv.z; o.w = (v.w-mean)*rstd*gg.w + bv.w;
  *(float4*)(outp + (size_t)blk*1024 + t*4) = o;
}

// ---------------- x init: broadcast latents --------------------------------
__global__ __launch_bounds__(256) void k_init_x(const float* __restrict__ lat, float* __restrict__ x){
  int v = blockIdx.x*256 + threadIdx.x;
  int row = v >> 8, cv = v & 255;
  ((float4*)x)[v] = ((const float4*)lat)[(row & 63)*256 + cv];
}

// ---------------- weight fold + transpose: Wt[n][k] = g[k]*scale*W[k][n] ---
DEV void foldT_body(const float* __restrict__ W, const float* __restrict__ g,
                    float scale, ushort_t* __restrict__ Wt, int K, int N,
                    int n0, int k0){
  __shared__ float Ts[64][65];
  int t = threadIdx.x;
  #pragma unroll
  for (int i = 0; i < 4; ++i){
    int flat = i*1024 + t*4; int r = flat >> 6, c = flat & 63;
    float4 v = *(const float4*)(W + (size_t)(k0+r)*N + n0 + c);
    float gg = (g ? g[k0+r] : 1.f) * scale;
    Ts[r][c] = v.x*gg; Ts[r][c+1] = v.y*gg; Ts[r][c+2] = v.z*gg; Ts[r][c+3] = v.w*gg;
  }
  __syncthreads();
  #pragma unroll
  for (int i = 0; i < 4; ++i){
    int flat = i*1024 + t*4; int rn = flat >> 6, ck = flat & 63;
    ushort4v o;
    o.x = f2bf(Ts[ck][rn]);   o.y = f2bf(Ts[ck+1][rn]);
    o.z = f2bf(Ts[ck+2][rn]); o.w = f2bf(Ts[ck+3][rn]);
    *(ushort4v*)(Wt + (size_t)(n0+rn)*K + k0 + ck) = o;
  }
}

__global__ __launch_bounds__(256) void k_foldT(const float* __restrict__ W,
        const float* __restrict__ g, float scale, ushort_t* __restrict__ Wt, int K, int N){
  foldT_body(W, g, scale, Wt, K, N, blockIdx.x*64, blockIdx.y*64);
}

__global__ __launch_bounds__(256) void k_foldT3(const float* __restrict__ Wq,
        const float* __restrict__ Wk, const float* __restrict__ Wv,
        const float* __restrict__ gq, const float* __restrict__ gkv, float scaleq,
        ushort_t* __restrict__ WQT, ushort_t* __restrict__ WKVT){
  int z = blockIdx.z;
  const float* W = (z==0) ? Wq : (z==1) ? Wk : Wv;
  const float* g = (z==0) ? gq : gkv;
  float sc = (z==0) ? scaleq : 1.f;
  ushort_t* outp = (z==0) ? WQT : WKVT + (size_t)(z-1)*1024*1024;
  foldT_body(W, g, sc, outp, 1024, 1024, blockIdx.x*64, blockIdx.y*64);
}

// ---------------- bias fold: bias[o] = scale * sum_c bvec[c]*W[c][o] -------
DEV void foldBias_body(const float* __restrict__ W, const float* __restrict__ bvec,
                       float scale, float* __restrict__ bias, int K, int N, int o0){
  int t = threadIdx.x;
  int ol = t & 31, kc = t >> 5;
  int o = o0 + ol;
  int chunk = K >> 3;
  int c0 = kc*chunk, c1 = c0 + chunk;
  float s0 = 0, s1 = 0, s2 = 0, s3 = 0;
  for (int c = c0; c < c1; c += 4){
    s0 += bvec[c+0]*W[(size_t)(c+0)*N + o];
    s1 += bvec[c+1]*W[(size_t)(c+1)*N + o];
    s2 += bvec[c+2]*W[(size_t)(c+2)*N + o];
    s3 += bvec[c+3]*W[(size_t)(c+3)*N + o];
  }
  __shared__ float red[8][32];
  red[kc][ol] = (s0+s1)+(s2+s3);
  __syncthreads();
  if (kc == 0){
    float tot = 0;
    #pragma unroll
    for (int jj = 0; jj < 8; ++jj) tot += red[jj][ol];
    bias[o] = tot * scale;
  }
}

__global__ __launch_bounds__(256) void k_foldBias(const float* __restrict__ W,
        const float* __restrict__ bvec, float scale, float* __restrict__ bias, int K, int N){
  foldBias_body(W, bvec, scale, bias, K, N, blockIdx.x*32);
}

__global__ __launch_bounds__(256) void k_foldBias3(const float* __restrict__ Wq,
        const float* __restrict__ Wk, const float* __restrict__ Wv,
        const float* __restrict__ bq, const float* __restrict__ bkv, float scaleq,
        float* __restrict__ BQ, float* __restrict__ BKV){
  int z = blockIdx.z;
  const float* W = (z==0) ? Wq : (z==1) ? Wk : Wv;
  const float* bv = (z==0) ? bq : bkv;
  float sc = (z==0) ? scaleq : 1.f;
  float* outp = (z==0) ? BQ : BKV + (z-1)*1024;
  foldBias_body(W, bv, sc, outp, 1024, 1024, blockIdx.x*32);
}

// ---------------- 128x128 2-phase GEMM -------------------------------------
// OUTMODE: 0 = bf16 store, 1 = bf16 relu store, 2 = f32 accumulate (C += v)
template<int OUTMODE, bool SKIP, bool REMAP, int LOG_NXB>
__global__ __launch_bounds__(256) void k_gemm(const ushort_t* __restrict__ A,
        const ushort_t* __restrict__ Bt, const float* __restrict__ bias,
        void* __restrict__ Cp, int M, int N, int K, const int* __restrict__ cnt){
  int bx, by;
  if (REMAP) xcd_remap<LOG_NXB>(blockIdx.x, gridDim.x, bx, by);
  else { bx = blockIdx.x; by = blockIdx.y; }
  const int n0 = bx * 128;
  const int m0 = by * 128;
  if (SKIP){ int b = m0 >> 11; if ((m0 & 2047) >= cnt[b]) return; }
  __shared__ ushort_t sA[2][128*32];
  __shared__ ushort_t sB[2][128*32];
  const int tid = threadIdx.x;
  const int wave = tid >> 6, lane = tid & 63;
  const int lo = lane & 15, hi = lane >> 4;
  const int wr = wave >> 1, wc = wave & 1;

  auto stage = [&](int buf, int k0){
    #pragma unroll
    for (int p = 0; p < 2; ++p){
      int r = p*64 + wave*16 + (lane >> 2);
      int c = lane & 3;
      {
        const ushort_t* gp = A + (size_t)(m0 + r)*K + k0 + c*8;
        char* lp = (char*)(&sA[buf][0]) + p*4096 + wave*1024;
        GLOAD16(gp, lp);
      }
      {
        const ushort_t* gp = Bt + (size_t)(n0 + r)*K + k0 + c*8;
        char* lp = (char*)(&sB[buf][0]) + p*4096 + wave*1024;
        GLOAD16(gp, lp);
      }
    }
  };

  f32x4 acc[4][4] = {};
  stage(0, 0);
  const int nk = K >> 5;
  for (int ks = 0; ks < nk; ++ks){
    __syncthreads();
    if (ks + 1 < nk) stage((ks+1)&1, (ks+1) << 5);
    const int buf = ks & 1;
    short8 af[4], bfr[4];
    #pragma unroll
    for (int mi = 0; mi < 4; ++mi)
      af[mi] = *(const short8*)(&sA[buf][(wr*64 + mi*16 + lo)*32 + hi*8]);
    #pragma unroll
    for (int ni = 0; ni < 4; ++ni)
      bfr[ni] = *(const short8*)(&sB[buf][(wc*64 + ni*16 + lo)*32 + hi*8]);
    #pragma unroll
    for (int mi = 0; mi < 4; ++mi)
      #pragma unroll
      for (int ni = 0; ni < 4; ++ni)
        acc[mi][ni] = MFMA16(af[mi], bfr[ni], acc[mi][ni]);
  }
  #pragma unroll
  for (int ni = 0; ni < 4; ++ni){
    int col = n0 + wc*64 + ni*16 + lo;
    float bv = bias ? bias[col] : 0.f;
    #pragma unroll
    for (int mi = 0; mi < 4; ++mi){
      int rbase = m0 + wr*64 + mi*16 + hi*4;
      #pragma unroll
      for (int rr = 0; rr < 4; ++rr){
        float v = acc[mi][ni][rr] + bv;
        size_t off = (size_t)(rbase + rr)*N + col;
        if (OUTMODE == 0)      ((ushort_t*)Cp)[off] = f2bf(v);
        else if (OUTMODE == 1) ((ushort_t*)Cp)[off] = f2bf(fmaxf(v, 0.f));
        else                   ((float*)Cp)[off] += v;
      }
    }
  }
}

// ======= shared pieces for the 256x256 kernels (8 waves, 512 threads) ======
// LDS layout: [buf][row][chunk'] with chunk' = global_chunk ^ (row&7),
// achieved by pre-swizzling the global source chunk (gload_lds dest linear).
#define G256_COMMON \
  int bx, by; \
  xcd_remap<LOG_NXB>(blockIdx.x, gridDim.x, bx, by); \
  const int n0 = bx * 256; \
  const int m0 = by * 256; \
  if (SKIP){ int b = m0 >> 11; if ((m0 & 2047) >= cnt[b]) return; } \
  __shared__ __align__(16) ushort_t sA[2][256*64]; \
  __shared__ __align__(16) ushort_t sB[2][256*64]; \
  const int tid = threadIdx.x; \
  const int wave = tid >> 6, lane = tid & 63; \
  const int lo = lane & 15, hi = lane >> 4; \
  const int wm = wave >> 2, wn = wave & 3; \
  const int srow = lane >> 3; \
  const int schunk = (lane & 7) ^ srow; \
  auto stageHalf = [&](ushort_t* dst, const ushort_t* __restrict__ G, int grow0, \
                       int half, int k0){ \
    _Pragma("unroll") \
    for (int p = 0; p < 2; ++p){ \
      int rbase = half*128 + p*64 + wave*8; \
      const ushort_t* gp = G + (size_t)(grow0 + rbase + srow)*K + k0 + schunk*8; \
      char* lp = (char*)dst + (size_t)rbase*128; \
      GLOAD16(gp, lp); \
    } \
  }; \
  auto ldsA = [&](int buf, int row, int kk)->short8{ \
    int ch = ((kk<<2) + hi) ^ (row & 7); \
    return *(const short8*)((const char*)sA + (size_t)buf*32768 + (size_t)row*128 + ch*16); \
  }; \
  auto ldsB = [&](int buf, int row, int kk)->short8{ \
    int ch = ((kk<<2) + hi) ^ (row & 7); \
    return *(const short8*)((const char*)sB + (size_t)buf*32768 + (size_t)row*128 + ch*16); \
  }; \
  f32x4 acc[8][4] = {};

#define G256_EPILOGUE \
  _Pragma("unroll") \
  for (int b2 = 0; b2 < 2; ++b2) \
    _Pragma("unroll") \
    for (int nj = 0; nj < 2; ++nj){ \
      int col = n0 + b2*128 + wn*32 + nj*16 + lo; \
      float bv = bias ? bias[col] : 0.f; \
      _Pragma("unroll") \
      for (int a2 = 0; a2 < 2; ++a2) \
        _Pragma("unroll") \
        for (int mi4 = 0; mi4 < 4; ++mi4){ \
          int rbase = m0 + a2*128 + wm*64 + mi4*16 + hi*4; \
          _Pragma("unroll") \
          for (int rr = 0; rr < 4; ++rr){ \
            float v = acc[a2*4+mi4][b2*2+nj][rr] + bv; \
            Cp[(size_t)(rbase + rr)*N + col] = f2bf(v); \
          } \
        } \
    }

// ---------------- variant A: 256x256 8-phase, counted vmcnt ----------------
// Phase quadrant order (A0,B0)(A0,B1)(A1,B1)(A1,B0): A frags reused over
// phase pairs, B1 reused over ph2-3 (28 ds_reads / 4 phases instead of 48).
// Stage schedule (derived race-free, each staged region idle >=1 barrier):
//  ph1: buf1-A1@kt+64  ph2: buf1-B0@kt+64  ph3: buf0-A0@kt+128 ph4: buf0-B1@kt+128
//  ph5: buf0-A1@kt+128 ph6: buf0-B0@kt+128 ph7: buf1-A0@kt+192 ph8: buf1-B1@kt+192
// Fences: VMCNT(4) at ph4 and ph8 complete exactly the buffer read next.
template<bool SKIP, int LOG_NXB>
__global__ __launch_bounds__(512, 2) void k_gemm256p8(const ushort_t* __restrict__ A,
        const ushort_t* __restrict__ Bt, const float* __restrict__ bias,
        ushort_t* __restrict__ Cp, int M, int N, int K, const int* __restrict__ cnt){
  G256_COMMON

  short8 af[4][2], bg[2][2];
#define LOADA(BUF, AH) \
    _Pragma("unroll") for (int mi_ = 0; mi_ < 4; ++mi_) \
      _Pragma("unroll") for (int kk_ = 0; kk_ < 2; ++kk_) \
        af[mi_][kk_] = ldsA(BUF, (AH)*128 + wm*64 + mi_*16 + lo, kk_);
#define LOADB(BUF, BH) \
    _Pragma("unroll") for (int nj_ = 0; nj_ < 2; ++nj_) \
      _Pragma("unroll") for (int kk_ = 0; kk_ < 2; ++kk_) \
        bg[nj_][kk_] = ldsB(BUF, (BH)*128 + wn*32 + nj_*16 + lo, kk_);
#define MMQ(AH, BH) \
    __builtin_amdgcn_s_barrier(); CFENCE; \
    __builtin_amdgcn_s_setprio(1); \
    _Pragma("unroll") for (int mi_ = 0; mi_ < 4; ++mi_) \
      _Pragma("unroll") for (int nj_ = 0; nj_ < 2; ++nj_) \
        _Pragma("unroll") for (int kk_ = 0; kk_ < 2; ++kk_) \
          acc[(AH)*4+mi_][(BH)*2+nj_] = \
            MFMA16(af[mi_][kk_], bg[nj_][kk_], acc[(AH)*4+mi_][(BH)*2+nj_]); \
    __builtin_amdgcn_s_setprio(0); CFENCE; \
    __builtin_amdgcn_s_barrier(); CFENCE;

  // prologue: buf0 = tile0 (8 loads), buf1 = A0,B1 of tile1 (4 loads)
  stageHalf(&sA[0][0], A,  m0, 0, 0);
  stageHalf(&sB[0][0], Bt, n0, 0, 0);
  stageHalf(&sA[0][0], A,  m0, 1, 0);
  stageHalf(&sB[0][0], Bt, n0, 1, 0);
  stageHalf(&sA[1][0], A,  m0, 0, 64);
  stageHalf(&sB[1][0], Bt, n0, 1, 64);
  VMCNT(4);
  __builtin_amdgcn_s_barrier();
  CFENCE;

  const int NI = K >> 7;
  for (int i = 0; i < NI; ++i){
    const int kt = i << 7;
    const bool lastI = (i == NI-1);
    // ---- phases 1-4: buf0 (tile 2i) ----
    LOADA(0,0) LOADB(0,0)
    stageHalf(&sA[1][0], A,  m0, 1, kt+64);
    MMQ(0,0)
    LOADB(0,1)
    stageHalf(&sB[1][0], Bt, n0, 0, kt+64);
    MMQ(0,1)
    LOADA(0,1)
    if (!lastI) stageHalf(&sA[0][0], A,  m0, 0, kt+128);
    MMQ(1,1)
    LOADB(0,0)
    if (!lastI) stageHalf(&sB[0][0], Bt, n0, 1, kt+128);
    if (lastI){ VMCNT(0); } else { VMCNT(4); }
    MMQ(1,0)
    // ---- phases 5-8: buf1 (tile 2i+1) ----
    LOADA(1,0) LOADB(1,0)
    if (!lastI) stageHalf(&sA[0][0], A,  m0, 1, kt+128);
    MMQ(0,0)
    LOADB(1,1)
    if (!lastI) stageHalf(&sB[0][0], Bt, n0, 0, kt+128);
    MMQ(0,1)
    LOADA(1,1)
    if (!lastI) stageHalf(&sA[1][0], A,  m0, 0, kt+192);
    MMQ(1,1)
    LOADB(1,0)
    if (!lastI){ stageHalf(&sB[1][0], Bt, n0, 1, kt+192); VMCNT(4); }
    MMQ(1,0)
  }
#undef LOADA
#undef LOADB
#undef MMQ

  G256_EPILOGUE
}

// ---------------- variant B: 256x256 2-phase (minimum-T3 recipe) -----------
template<bool SKIP, int LOG_NXB>
__global__ __launch_bounds__(512, 2) void k_gemm256p2(const ushort_t* __restrict__ A,
        const ushort_t* __restrict__ Bt, const float* __restrict__ bias,
        ushort_t* __restrict__ Cp, int M, int N, int K, const int* __restrict__ cnt){
  G256_COMMON

  auto stageTile = [&](int buf, int k0){
    stageHalf(&sA[buf][0], A,  m0, 0, k0);
    stageHalf(&sA[buf][0], A,  m0, 1, k0);
    stageHalf(&sB[buf][0], Bt, n0, 0, k0);
    stageHalf(&sB[buf][0], Bt, n0, 1, k0);
  };

  stageTile(0, 0);
  VMCNT(0);
  __builtin_amdgcn_s_barrier();
  CFENCE;

  const int nk = K >> 6;
  for (int ks = 0; ks < nk; ++ks){
    if (ks + 1 < nk) stageTile((ks+1)&1, (ks+1) << 6);
    const int buf = ks & 1;
    short8 af[8][2], bg[4][2];
    #pragma unroll
    for (int a2 = 0; a2 < 2; ++a2)
      #pragma unroll
      for (int mi = 0; mi < 4; ++mi)
        #pragma unroll
        for (int kk = 0; kk < 2; ++kk)
          af[a2*4+mi][kk] = ldsA(buf, a2*128 + wm*64 + mi*16 + lo, kk);
    #pragma unroll
    for (int b2 = 0; b2 < 2; ++b2)
      #pragma unroll
      for (int nj = 0; nj < 2; ++nj)
        #pragma unroll
        for (int kk = 0; kk < 2; ++kk)
          bg[b2*2+nj][kk] = ldsB(buf, b2*128 + wn*32 + nj*16 + lo, kk);
    __builtin_amdgcn_s_setprio(1);
    #pragma unroll
    for (int mi8 = 0; mi8 < 8; ++mi8)
      #pragma unroll
      for (int nj4 = 0; nj4 < 4; ++nj4)
        #pragma unroll
        for (int kk = 0; kk < 2; ++kk)
          acc[mi8][nj4] = MFMA16(af[mi8][kk], bg[nj4][kk], acc[mi8][nj4]);
    __builtin_amdgcn_s_setprio(0);
    CFENCE;
    VMCNT(0);
    __builtin_amdgcn_s_barrier();
    CFENCE;
  }

  G256_EPILOGUE
}

// ---------------- flash attention: one block per (b,h), fused KV -----------
__global__ __launch_bounds__(256) void k_attn(const ushort_t* __restrict__ qb,
        const ushort_t* __restrict__ kvb, const int* __restrict__ cnt,
        ushort_t* __restrict__ outb){
  const int bh = blockIdx.x;
  const int b = bh >> 4, h = bh & 15;
  const int t = threadIdx.x;
  const int wave = t >> 6, lane = t & 63, lo = lane & 15, hi = lane >> 4;
  __shared__ ushort_t Qs[64*64];
  __shared__ ushort_t Ks[64*64];
  __shared__ ushort_t Vt[64][72];
  __shared__ ushort_t Ps[4][16][72];

  const int count = cnt[b];

  #pragma unroll
  for (int p = 0; p < 2; ++p){
    int r = p*32 + wave*8 + (lane >> 3);
    int c = (lane & 7) ^ (r & 7);
    const ushort_t* gp = qb + (size_t)(b*64 + r)*1024 + h*64 + c*8;
    char* lp = (char*)Qs + p*4096 + wave*1024;
    GLOAD16(gp, lp);
  }

  f32x4 oacc[4] = {};
  float m[4], l[4];
  #pragma unroll
  for (int rr = 0; rr < 4; ++rr){ m[rr] = -__builtin_inff(); l[rr] = 0.f; }

  const int ntiles = (count + 63) >> 6;
  for (int tt = 0; tt < ntiles; ++tt){
    __syncthreads();
    #pragma unroll
    for (int p = 0; p < 2; ++p){
      int r = p*32 + wave*8 + (lane >> 3);
      int c = (lane & 7) ^ (r & 7);
      const ushort_t* gp = kvb + (size_t)(b*2048 + tt*64 + r)*2048 + h*64 + c*8;
      char* lp = (char*)Ks + p*4096 + wave*1024;
      GLOAD16(gp, lp);
    }
    {
      int jj = (t & 31)*2, c = (t >> 5)*8;
      const ushort_t* g0 = kvb + (size_t)(b*2048 + tt*64 + jj)*2048 + 1024 + h*64 + c;
      ushort4v a0 = *(const ushort4v*)(g0);
      ushort4v a1 = *(const ushort4v*)(g0 + 4);
      ushort4v b0 = *(const ushort4v*)(g0 + 2048);
      ushort4v b1 = *(const ushort4v*)(g0 + 2052);
      bool va  = (tt*64 + jj)     < count;
      bool vb2 = (tt*64 + jj + 1) < count;
      #pragma unroll
      for (int u = 0; u < 8; ++u){
        ushort_t ea = (u < 4) ? ((ushort_t*)&a0)[u] : ((ushort_t*)&a1)[u-4];
        ushort_t eb = (u < 4) ? ((ushort_t*)&b0)[u] : ((ushort_t*)&b1)[u-4];
        uint32_t word = (va ? (uint32_t)ea : 0u) | ((vb2 ? (uint32_t)eb : 0u) << 16);
        *(uint32_t*)(&Vt[c+u][jj]) = word;
      }
    }
    __syncthreads();

    f32x4 s[4] = {};
    #pragma unroll
    for (int kk = 0; kk < 2; ++kk){
      int rA = wave*16 + lo;
      short8 aq = *(const short8*)(&Qs[rA*64 + (((kk*4 + hi) ^ (rA & 7))*8)]);
      #pragma unroll
      for (int ni = 0; ni < 4; ++ni){
        int rB = ni*16 + lo;
        short8 bk = *(const short8*)(&Ks[rB*64 + (((kk*4 + hi) ^ (rB & 7))*8)]);
        s[ni] = MFMA16(aq, bk, s[ni]);
      }
    }
    #pragma unroll
    for (int ni = 0; ni < 4; ++ni){
      if (tt*64 + ni*16 + lo >= count){
        s[ni][0] = s[ni][1] = s[ni][2] = s[ni][3] = -__builtin_inff();
      }
    }
    float p[4][4];
    #pragma unroll
    for (int rr = 0; rr < 4; ++rr){
      float mx = fmaxf(fmaxf(s[0][rr], s[1][rr]), fmaxf(s[2][rr], s[3][rr]));
      #pragma unroll
      for (int d = 1; d < 16; d <<= 1) mx = fmaxf(mx, __shfl_xor(mx, d));
      float mnew = fmaxf(m[rr], mx);
      float sc = __expf(m[rr] - mnew);
      float rsum = 0.f;
      #pragma unroll
      for (int ni = 0; ni < 4; ++ni){
        float pv = __expf(s[ni][rr] - mnew);
        p[ni][rr] = pv;
        rsum += pv;
      }
      #pragma unroll
      for (int d = 1; d < 16; d <<= 1) rsum += __shfl_xor(rsum, d);
      l[rr] = l[rr]*sc + rsum;
      m[rr] = mnew;
      #pragma unroll
      for (int ni = 0; ni < 4; ++ni) oacc[ni][rr] *= sc;
    }
    #pragma unroll
    for (int ni = 0; ni < 4; ++ni)
      #pragma unroll
      for (int rr = 0; rr < 4; ++rr)
        Ps[wave][hi*4+rr][ni*16+lo] = f2bf(p[ni][rr]);
    asm volatile("s_waitcnt lgkmcnt(0)" ::: "memory");
    #pragma unroll
    for (int kk = 0; kk < 2; ++kk){
      short8 pa = *(const short8*)(&Ps[wave][lo][kk*32 + hi*8]);
      #pragma unroll
      for (int ni = 0; ni < 4; ++ni){
        short8 bv = *(const short8*)(&Vt[ni*16 + lo][kk*32 + hi*8]);
        oacc[ni] = MFMA16(pa, bv, oacc[ni]);
      }
    }
  }
  #pragma unroll
  for (int rr = 0; rr < 4; ++rr){
    float inv = (l[rr] > 0.f) ? 1.f/l[rr] : 0.f;
    #pragma unroll
    for (int ni = 0; ni < 4; ++ni){
      size_t off = (size_t)(b*64 + wave*16 + hi*4 + rr)*1024 + h*64 + ni*16 + lo;
      outb[off] = f2bf(oacc[ni][rr] * inv);
    }
  }
}

// ---------------------------------------------------------------------------
extern "C" void kernel_launch(void* const* d_in, const int* in_sizes, int n_in,
                              void* d_out, int out_size, void* d_ws, size_t ws_size,
                              hipStream_t stream){
  const float* features = (const float*)d_in[0];
  const int*   mask     = (const int*)  d_in[1];
  const float* latents  = (const float*)d_in[2];
  const float* W_down   = (const float*)d_in[3];
  const float* nin_g    = (const float*)d_in[4];
  const float* nin_b    = (const float*)d_in[5];
  const float* lf_g     = (const float*)d_in[6];
  const float* lf_b     = (const float*)d_in[7];
  const float* ll_g     = (const float*)d_in[8];
  const float* ll_b     = (const float*)d_in[9];
  const float* Wq       = (const float*)d_in[10];
  const float* Wk       = (const float*)d_in[11];
  const float* Wv       = (const float*)d_in[12];
  const float* ffln_g   = (const float*)d_in[13];
  const float* ffln_b   = (const float*)d_in[14];
  const float* ff_w1    = (const float*)d_in[15];
  const float* ff_w2    = (const float*)d_in[16];
  const float* nout_g   = (const float*)d_in[17];
  const float* nout_b   = (const float*)d_in[18];

  char* ws = (char*)d_ws;
  size_t off = 0;
  auto alloc = [&](size_t bytes)->char*{
    char* p = ws + off;
    off += (bytes + 255) & ~(size_t)255;
    return p;
  };
  ushort_t* FHAT  = (ushort_t*)alloc((size_t)65536*1024*2);
  ushort_t* KVBUF = (ushort_t*)alloc((size_t)65536*2048*2);
  ushort_t* WQT   = (ushort_t*)alloc((size_t)1024*1024*2);
  ushort_t* WKVT  = (ushort_t*)alloc((size_t)2048*1024*2);
  ushort_t* W1T   = (ushort_t*)alloc((size_t)2048*1024*2);
  ushort_t* W2T   = (ushort_t*)alloc((size_t)2048*1024*2);
  ushort_t* WDT   = (ushort_t*)alloc((size_t)1024*1024*2);
  float* BD  = (float*)alloc(1024*4);
  float* BQv = (float*)alloc(1024*4);
  float* BKV = (float*)alloc(2048*4);
  float* B1v = (float*)alloc(2048*4);
  float*    X    = (float*)   alloc((size_t)2048*1024*4);
  ushort_t* XHAT = (ushort_t*)alloc((size_t)2048*1024*2);
  ushort_t* QP   = (ushort_t*)alloc((size_t)2048*1024*2);
  ushort_t* OUTB = (ushort_t*)alloc((size_t)2048*1024*2);
  ushort_t* OUTH = (ushort_t*)alloc((size_t)2048*1024*2);
  ushort_t* H1   = (ushort_t*)alloc((size_t)2048*2048*2);
  int* CNT = (int*)alloc(32*4);
  int* IDX = (int*)alloc((size_t)65536*4);
  ushort_t* FNORM = KVBUF;
  (void)ws_size; (void)in_sizes; (void)n_in; (void)out_size;

  // ---- setup ----
  k_compact    <<<32,    256, 0, stream>>>(mask, IDX, CNT);
  k_gather_norm<<<65536, 256, 0, stream>>>(features, IDX, CNT, FNORM);
  k_foldT      <<<dim3(16,16), 256, 0, stream>>>(W_down, nin_g, 1.f, WDT, 1024, 1024);
  k_foldBias   <<<32,    256, 0, stream>>>(W_down, nin_b, 1.f, BD, 1024, 1024);
  k_gemm256p8<true,2><<<1024, 512, 0, stream>>>(FNORM, WDT, BD, FHAT, 65536, 1024, 1024, CNT);
  k_rownorm_bf16<<<65536, 256, 0, stream>>>(FHAT, FHAT, CNT);
  k_init_x     <<<2048,  256, 0, stream>>>(latents, X);

  const float scale = 0.125f;  // DH^-0.5
  for (int i = 0; i < 6; ++i){
    const float* Wqi = Wq + (size_t)i*1024*1024;
    const float* Wki = Wk + (size_t)i*1024*1024;
    const float* Wvi = Wv + (size_t)i*1024*1024;
    const float* W1i = ff_w1 + (size_t)i*1024*2048;
    const float* W2i = ff_w2 + (size_t)i*2048*1024;

    k_foldT3  <<<dim3(16,16,3), 256, 0, stream>>>(Wqi, Wki, Wvi,
                  ll_g + i*1024, lf_g + i*1024, scale, WQT, WKVT);
    k_foldBias3<<<dim3(32,1,3), 256, 0, stream>>>(Wqi, Wki, Wvi,
                  ll_b + i*1024, lf_b + i*1024, scale, BQv, BKV);
    k_foldT   <<<dim3(32,16), 256, 0, stream>>>(W1i, ffln_g + i*1024, 1.f, W1T, 1024, 2048);
    k_foldBias<<<64, 256, 0, stream>>>(W1i, ffln_b + i*1024, 1.f, B1v, 1024, 2048);
    k_foldT   <<<dim3(16,32), 256, 0, stream>>>(W2i, nullptr, 1.f, W2T, 2048, 1024);

    k_rownorm_f32<<<2048, 256, 0, stream>>>(X, XHAT);
    k_gemm<0,false,false,0><<<dim3(8,16),  256, 0, stream>>>(XHAT, WQT, BQv, QP, 2048, 1024, 1024, nullptr);
    // ---- 3-way A/B on the identical KV GEMMs ----
    if (i == 0 || i == 3)
      k_gemm256p8<true,3><<<2048, 512, 0, stream>>>(FHAT, WKVT, BKV, KVBUF, 65536, 2048, 1024, CNT);
    else if (i == 1 || i == 4)
      k_gemm256p2<true,3><<<2048, 512, 0, stream>>>(FHAT, WKVT, BKV, KVBUF, 65536, 2048, 1024, CNT);
    else
      k_gemm<0,true,true,4><<<8192, 256, 0, stream>>>(FHAT, WKVT, BKV, KVBUF, 65536, 2048, 1024, CNT);
    k_attn<<<512, 256, 0, stream>>>(QP, KVBUF, CNT, OUTB);
    k_rownorm_bf16<<<2048, 256, 0, stream>>>(OUTB, OUTH, nullptr);
    k_gemm<1,false,false,0><<<dim3(16,16), 256, 0, stream>>>(OUTH, W1T, B1v, H1, 2048, 2048, 1024, nullptr);
    k_gemm<2,false,false,0><<<dim3(8,16),  256, 0, stream>>>(H1, W2T, nullptr, X, 2048, 1024, 2048, nullptr);
  }
  k_final_ln<<<2048, 256, 0, stream>>>(X, nout_g, nout_b, (float*)d_out);
}

// Round 4
// 2499.563 us; speedup vs baseline: 1.3259x; 1.0555x over previous
//
#include <hip/hip_runtime.h>
#include <stdint.h>

// ---------------------------------------------------------------------------
// PerceiverResampler on MI355X (gfx950)
// B=32, F=2048, DIM=1024, INNER=1024, H=16, DH=64, Q=64, DEPTH=6, MULT=2
//
// Round 4: all weight/bias folds hoisted to setup (descriptor-batched, 2
// launches); 6 KV GEMMs run back-to-back after FHAT for L3 A-reuse (gated on
// ws_size, fallback = per-depth); depths 0-2 p2 vs 3-5 p8 A/B preserved.
// ---------------------------------------------------------------------------

#define DEV static __device__ __forceinline__

typedef __attribute__((ext_vector_type(8))) short short8;
typedef __attribute__((ext_vector_type(4))) float f32x4;
typedef __attribute__((ext_vector_type(4))) unsigned short ushort4v;
typedef unsigned short ushort_t;

DEV float bf2f(ushort_t u){ union{uint32_t i; float f;} x; x.i = ((uint32_t)u)<<16; return x.f; }
DEV ushort_t f2bf(float f){
  union{float f; uint32_t i;} x; x.f = f;
  uint32_t r = x.i + 0x7fffu + ((x.i>>16)&1u);  // RNE
  return (ushort_t)(r>>16);
}

#define GLOAD16(gp, lp) __builtin_amdgcn_global_load_lds( \
    (const __attribute__((address_space(1))) uint32_t*)(gp), \
    (__attribute__((address_space(3))) uint32_t*)(lp), 16, 0, 0)

#define VMCNT(n) asm volatile("s_waitcnt vmcnt(" #n ")" ::: "memory")
#define CFENCE   asm volatile("" ::: "memory")
#define MFMA16(a,b,c) __builtin_amdgcn_mfma_f32_16x16x32_bf16(a,b,c,0,0,0)

// XCD-locality remap: all NXB N-blocks of one M-row land on the same XCD.
template<int LOG_NXB>
DEV void xcd_remap(int g, int total, int& x, int& y){
  int xcd = g & 7;
  int k = g >> 3;
  int rows_per_xcd = (total >> LOG_NXB) >> 3;
  y = xcd * rows_per_xcd + (k >> LOG_NXB);
  x = k & ((1 << LOG_NXB) - 1);
}

// ---------------- block reduce (sum of two values, 256 threads) ------------
DEV void reduce2(float& a, float& b){
  #pragma unroll
  for (int d = 32; d; d >>= 1){ a += __shfl_down(a, d); b += __shfl_down(b, d); }
  __shared__ float sh[8];
  int w = threadIdx.x >> 6, l = threadIdx.x & 63;
  if (l == 0){ sh[w*2] = a; sh[w*2+1] = b; }
  __syncthreads();
  a = sh[0]+sh[2]+sh[4]+sh[6];
  b = sh[1]+sh[3]+sh[5]+sh[7];
}

// ---------------- mask compaction ------------------------------------------
__global__ __launch_bounds__(256) void k_compact(const int* __restrict__ mask,
                                                 int* __restrict__ idx, int* __restrict__ cnt){
  int b = blockIdx.x, t = threadIdx.x;
  const int* mb = mask + b*2048;
  int keep[8]; int c = 0;
  #pragma unroll
  for (int u = 0; u < 8; ++u){ keep[u] = (mb[t*8+u] != 0); c += keep[u]; }
  __shared__ int s[256];
  s[t] = c; __syncthreads();
  for (int off = 1; off < 256; off <<= 1){
    int v = (t >= off) ? s[t-off] : 0;
    __syncthreads();
    s[t] += v;
    __syncthreads();
  }
  int pos = s[t] - c;
  #pragma unroll
  for (int u = 0; u < 8; ++u) if (keep[u]) idx[b*2048 + pos++] = t*8 + u;
  if (t == 255) cnt[b] = s[255];
}

// ---------------- gather + rownorm features -> bf16 ------------------------
__global__ __launch_bounds__(256) void k_gather_norm(const float* __restrict__ feat,
        const int* __restrict__ idx, const int* __restrict__ cnt, ushort_t* __restrict__ outp){
  int blk = blockIdx.x; int b = blk >> 11, j = blk & 2047;
  if (j >= cnt[b]) return;
  int src = idx[b*2048 + j];
  const float* row = feat + ((size_t)(b*2048 + src))*1024;
  int t = threadIdx.x;
  float4 v = *(const float4*)(row + t*4);
  float s = v.x+v.y+v.z+v.w;
  float q = v.x*v.x+v.y*v.y+v.z*v.z+v.w*v.w;
  reduce2(s, q);
  float mean = s * (1.f/1024.f);
  float rstd = rsqrtf(q*(1.f/1024.f) - mean*mean + 1e-5f);
  ushort4v o;
  o.x = f2bf((v.x-mean)*rstd); o.y = f2bf((v.y-mean)*rstd);
  o.z = f2bf((v.z-mean)*rstd); o.w = f2bf((v.w-mean)*rstd);
  *(ushort4v*)(outp + ((size_t)(b*2048+j))*1024 + t*4) = o;
}

// ---------------- rownorm bf16 -> bf16 (optional skip) ---------------------
__global__ __launch_bounds__(256) void k_rownorm_bf16(const ushort_t* __restrict__ in,
        ushort_t* __restrict__ outp, const int* __restrict__ cnt){
  int blk = blockIdx.x;
  if (cnt){ int b = blk >> 11; if ((blk & 2047) >= cnt[b]) return; }
  int t = threadIdx.x;
  ushort4v u = *(const ushort4v*)(in + (size_t)blk*1024 + t*4);
  float f0 = bf2f(u.x), f1 = bf2f(u.y), f2 = bf2f(u.z), f3 = bf2f(u.w);
  float s = f0+f1+f2+f3, q = f0*f0+f1*f1+f2*f2+f3*f3;
  reduce2(s, q);
  float mean = s * (1.f/1024.f);
  float rstd = rsqrtf(q*(1.f/1024.f) - mean*mean + 1e-5f);
  ushort4v o;
  o.x = f2bf((f0-mean)*rstd); o.y = f2bf((f1-mean)*rstd);
  o.z = f2bf((f2-mean)*rstd); o.w = f2bf((f3-mean)*rstd);
  *(ushort4v*)(outp + (size_t)blk*1024 + t*4) = o;
}

// ---------------- rownorm f32 -> bf16 --------------------------------------
__global__ __launch_bounds__(256) void k_rownorm_f32(const float* __restrict__ in,
                                                     ushort_t* __restrict__ outp){
  int blk = blockIdx.x, t = threadIdx.x;
  float4 v = *(const float4*)(in + (size_t)blk*1024 + t*4);
  float s = v.x+v.y+v.z+v.w;
  float q = v.x*v.x+v.y*v.y+v.z*v.z+v.w*v.w;
  reduce2(s, q);
  float mean = s * (1.f/1024.f);
  float rstd = rsqrtf(q*(1.f/1024.f) - mean*mean + 1e-5f);
  ushort4v o;
  o.x = f2bf((v.x-mean)*rstd); o.y = f2bf((v.y-mean)*rstd);
  o.z = f2bf((v.z-mean)*rstd); o.w = f2bf((v.w-mean)*rstd);
  *(ushort4v*)(outp + (size_t)blk*1024 + t*4) = o;
}

// ---------------- final layernorm (affine) f32 -> f32 ----------------------
__global__ __launch_bounds__(256) void k_final_ln(const float* __restrict__ x,
        const float* __restrict__ g, const float* __restrict__ bb, float* __restrict__ outp){
  int blk = blockIdx.x, t = threadIdx.x;
  float4 v = *(const float4*)(x + (size_t)blk*1024 + t*4);
  float s = v.x+v.y+v.z+v.w;
  float q = v.x*v.x+v.y*v.y+v.z*v.z+v.w*v.w;
  reduce2(s, q);
  float mean = s * (1.f/1024.f);
  float rstd = rsqrtf(q*(1.f/1024.f) - mean*mean + 1e-5f);
  float4 gg = *(const float4*)(g + t*4);
  float4 bv = *(const float4*)(bb + t*4);
  float4 o;
  o.x = (v.x-mean)*rstd*gg.x + bv.x; o.y = (v.y-mean)*rstd*gg.y + bv.y;
  o.z = (v.z-mean)*rstd*gg.z + bv.z; o.w = (v.w-mean)*rstd*gg.w + bv.w;
  *(float4*)(outp + (size_t)blk*1024 + t*4) = o;
}

// ---------------- x init: broadcast latents --------------------------------
__global__ __launch_bounds__(256) void k_init_x(const float* __restrict__ lat, float* __restrict__ x){
  int v = blockIdx.x*256 + threadIdx.x;
  int row = v >> 8, cv = v & 255;
  ((float4*)x)[v] = ((const float4*)lat)[(row & 63)*256 + cv];
}

// ---------------- batched weight fold + transpose --------------------------
// Wt[n][k] = g[k]*scale*W[k][n], done for all weights in ONE launch.
DEV void foldT_body(const float* __restrict__ W, const float* __restrict__ g,
                    float scale, ushort_t* __restrict__ Wt, int K, int N,
                    int n0, int k0){
  __shared__ float Ts[64][65];
  int t = threadIdx.x;
  #pragma unroll
  for (int i = 0; i < 4; ++i){
    int flat = i*1024 + t*4; int r = flat >> 6, c = flat & 63;
    float4 v = *(const float4*)(W + (size_t)(k0+r)*N + n0 + c);
    float gg = (g ? g[k0+r] : 1.f) * scale;
    Ts[r][c] = v.x*gg; Ts[r][c+1] = v.y*gg; Ts[r][c+2] = v.z*gg; Ts[r][c+3] = v.w*gg;
  }
  __syncthreads();
  #pragma unroll
  for (int i = 0; i < 4; ++i){
    int flat = i*1024 + t*4; int rn = flat >> 6, ck = flat & 63;
    ushort4v o;
    o.x = f2bf(Ts[ck][rn]);   o.y = f2bf(Ts[ck+1][rn]);
    o.z = f2bf(Ts[ck+2][rn]); o.w = f2bf(Ts[ck+3][rn]);
    *(ushort4v*)(Wt + (size_t)(n0+rn)*K + k0 + ck) = o;
  }
}

struct FDesc { const float* W; const float* g; ushort_t* dst; float scale; int K; int N; };
#define MAXFD 32
struct FoldTArgs { int cnt; FDesc d[MAXFD]; };

__global__ __launch_bounds__(256) void k_foldT_all(FoldTArgs a){
  const FDesc d = a.d[blockIdx.y];
  int nxb = d.N >> 6;
  int n0 = (blockIdx.x % nxb) * 64;
  int k0 = (blockIdx.x / nxb) * 64;
  if (k0 >= d.K) return;
  foldT_body(d.W, d.g, d.scale, d.dst, d.K, d.N, n0, k0);
}

// ---------------- batched bias fold ----------------------------------------
DEV void foldBias_body(const float* __restrict__ W, const float* __restrict__ bvec,
                       float scale, float* __restrict__ bias, int K, int N, int o0){
  int t = threadIdx.x;
  int ol = t & 31, kc = t >> 5;
  int o = o0 + ol;
  int chunk = K >> 3;
  int c0 = kc*chunk, c1 = c0 + chunk;
  float s0 = 0, s1 = 0, s2 = 0, s3 = 0;
  for (int c = c0; c < c1; c += 4){
    s0 += bvec[c+0]*W[(size_t)(c+0)*N + o];
    s1 += bvec[c+1]*W[(size_t)(c+1)*N + o];
    s2 += bvec[c+2]*W[(size_t)(c+2)*N + o];
    s3 += bvec[c+3]*W[(size_t)(c+3)*N + o];
  }
  __shared__ float red[8][32];
  red[kc][ol] = (s0+s1)+(s2+s3);
  __syncthreads();
  if (kc == 0){
    float tot = 0;
    #pragma unroll
    for (int jj = 0; jj < 8; ++jj) tot += red[jj][ol];
    bias[o] = tot * scale;
  }
}

struct BDesc { const float* W; const float* b; float* dst; float scale; int K; int N; };
#define MAXBD 25
struct BiasArgs { int cnt; BDesc d[MAXBD]; };

__global__ __launch_bounds__(256) void k_foldBias_all(BiasArgs a){
  const BDesc d = a.d[blockIdx.y];
  int o0 = blockIdx.x * 32;
  if (o0 >= d.N) return;
  foldBias_body(d.W, d.b, d.scale, d.dst, d.K, d.N, o0);
}

// ---------------- 128x128 2-phase GEMM -------------------------------------
// OUTMODE: 0 = bf16 store, 1 = bf16 relu store, 2 = f32 accumulate (C += v)
template<int OUTMODE, bool SKIP, bool REMAP, int LOG_NXB>
__global__ __launch_bounds__(256, 4) void k_gemm(const ushort_t* __restrict__ A,
        const ushort_t* __restrict__ Bt, const float* __restrict__ bias,
        void* __restrict__ Cp, int M, int N, int K, const int* __restrict__ cnt){
  int bx, by;
  if (REMAP) xcd_remap<LOG_NXB>(blockIdx.x, gridDim.x, bx, by);
  else { bx = blockIdx.x; by = blockIdx.y; }
  const int n0 = bx * 128;
  const int m0 = by * 128;
  if (SKIP){ int b = m0 >> 11; if ((m0 & 2047) >= cnt[b]) return; }
  __shared__ ushort_t sA[2][128*32];
  __shared__ ushort_t sB[2][128*32];
  const int tid = threadIdx.x;
  const int wave = tid >> 6, lane = tid & 63;
  const int lo = lane & 15, hi = lane >> 4;
  const int wr = wave >> 1, wc = wave & 1;

  auto stage = [&](int buf, int k0){
    #pragma unroll
    for (int p = 0; p < 2; ++p){
      int r = p*64 + wave*16 + (lane >> 2);
      int c = lane & 3;
      {
        const ushort_t* gp = A + (size_t)(m0 + r)*K + k0 + c*8;
        char* lp = (char*)(&sA[buf][0]) + p*4096 + wave*1024;
        GLOAD16(gp, lp);
      }
      {
        const ushort_t* gp = Bt + (size_t)(n0 + r)*K + k0 + c*8;
        char* lp = (char*)(&sB[buf][0]) + p*4096 + wave*1024;
        GLOAD16(gp, lp);
      }
    }
  };

  f32x4 acc[4][4] = {};
  stage(0, 0);
  const int nk = K >> 5;
  for (int ks = 0; ks < nk; ++ks){
    __syncthreads();
    if (ks + 1 < nk) stage((ks+1)&1, (ks+1) << 5);
    const int buf = ks & 1;
    short8 af[4], bfr[4];
    #pragma unroll
    for (int mi = 0; mi < 4; ++mi)
      af[mi] = *(const short8*)(&sA[buf][(wr*64 + mi*16 + lo)*32 + hi*8]);
    #pragma unroll
    for (int ni = 0; ni < 4; ++ni)
      bfr[ni] = *(const short8*)(&sB[buf][(wc*64 + ni*16 + lo)*32 + hi*8]);
    #pragma unroll
    for (int mi = 0; mi < 4; ++mi)
      #pragma unroll
      for (int ni = 0; ni < 4; ++ni)
        acc[mi][ni] = MFMA16(af[mi], bfr[ni], acc[mi][ni]);
  }
  #pragma unroll
  for (int ni = 0; ni < 4; ++ni){
    int col = n0 + wc*64 + ni*16 + lo;
    float bv = bias ? bias[col] : 0.f;
    #pragma unroll
    for (int mi = 0; mi < 4; ++mi){
      int rbase = m0 + wr*64 + mi*16 + hi*4;
      #pragma unroll
      for (int rr = 0; rr < 4; ++rr){
        float v = acc[mi][ni][rr] + bv;
        size_t off = (size_t)(rbase + rr)*N + col;
        if (OUTMODE == 0)      ((ushort_t*)Cp)[off] = f2bf(v);
        else if (OUTMODE == 1) ((ushort_t*)Cp)[off] = f2bf(fmaxf(v, 0.f));
        else                   ((float*)Cp)[off] += v;
      }
    }
  }
}

// ======= shared pieces for the 256x256 kernels (8 waves, 512 threads) ======
#define G256_COMMON \
  int bx, by; \
  xcd_remap<LOG_NXB>(blockIdx.x, gridDim.x, bx, by); \
  const int n0 = bx * 256; \
  const int m0 = by * 256; \
  if (SKIP){ int b = m0 >> 11; if ((m0 & 2047) >= cnt[b]) return; } \
  __shared__ __align__(16) ushort_t sA[2][256*64]; \
  __shared__ __align__(16) ushort_t sB[2][256*64]; \
  const int tid = threadIdx.x; \
  const int wave = tid >> 6, lane = tid & 63; \
  const int lo = lane & 15, hi = lane >> 4; \
  const int wm = wave >> 2, wn = wave & 3; \
  const int srow = lane >> 3; \
  const int schunk = (lane & 7) ^ srow; \
  auto stageHalf = [&](ushort_t* dst, const ushort_t* __restrict__ G, int grow0, \
                       int half, int k0){ \
    _Pragma("unroll") \
    for (int p = 0; p < 2; ++p){ \
      int rbase = half*128 + p*64 + wave*8; \
      const ushort_t* gp = G + (size_t)(grow0 + rbase + srow)*K + k0 + schunk*8; \
      char* lp = (char*)dst + (size_t)rbase*128; \
      GLOAD16(gp, lp); \
    } \
  }; \
  auto ldsA = [&](int buf, int row, int kk)->short8{ \
    int ch = ((kk<<2) + hi) ^ (row & 7); \
    return *(const short8*)((const char*)sA + (size_t)buf*32768 + (size_t)row*128 + ch*16); \
  }; \
  auto ldsB = [&](int buf, int row, int kk)->short8{ \
    int ch = ((kk<<2) + hi) ^ (row & 7); \
    return *(const short8*)((const char*)sB + (size_t)buf*32768 + (size_t)row*128 + ch*16); \
  }; \
  f32x4 acc[8][4] = {};

#define G256_EPILOGUE \
  _Pragma("unroll") \
  for (int b2 = 0; b2 < 2; ++b2) \
    _Pragma("unroll") \
    for (int nj = 0; nj < 2; ++nj){ \
      int col = n0 + b2*128 + wn*32 + nj*16 + lo; \
      float bv = bias ? bias[col] : 0.f; \
      _Pragma("unroll") \
      for (int a2 = 0; a2 < 2; ++a2) \
        _Pragma("unroll") \
        for (int mi4 = 0; mi4 < 4; ++mi4){ \
          int rbase = m0 + a2*128 + wm*64 + mi4*16 + hi*4; \
          _Pragma("unroll") \
          for (int rr = 0; rr < 4; ++rr){ \
            float v = acc[a2*4+mi4][b2*2+nj][rr] + bv; \
            Cp[(size_t)(rbase + rr)*N + col] = f2bf(v); \
          } \
        } \
    }

// ---------------- variant A: 256x256 8-phase, counted vmcnt ----------------
template<bool SKIP, int LOG_NXB>
__global__ __launch_bounds__(512, 2) void k_gemm256p8(const ushort_t* __restrict__ A,
        const ushort_t* __restrict__ Bt, const float* __restrict__ bias,
        ushort_t* __restrict__ Cp, int M, int N, int K, const int* __restrict__ cnt){
  G256_COMMON

  short8 af[4][2], bg[2][2];
#define LOADA(BUF, AH) \
    _Pragma("unroll") for (int mi_ = 0; mi_ < 4; ++mi_) \
      _Pragma("unroll") for (int kk_ = 0; kk_ < 2; ++kk_) \
        af[mi_][kk_] = ldsA(BUF, (AH)*128 + wm*64 + mi_*16 + lo, kk_);
#define LOADB(BUF, BH) \
    _Pragma("unroll") for (int nj_ = 0; nj_ < 2; ++nj_) \
      _Pragma("unroll") for (int kk_ = 0; kk_ < 2; ++kk_) \
        bg[nj_][kk_] = ldsB(BUF, (BH)*128 + wn*32 + nj_*16 + lo, kk_);
#define MMQ(AH, BH) \
    __builtin_amdgcn_s_barrier(); CFENCE; \
    __builtin_amdgcn_s_setprio(1); \
    _Pragma("unroll") for (int mi_ = 0; mi_ < 4; ++mi_) \
      _Pragma("unroll") for (int nj_ = 0; nj_ < 2; ++nj_) \
        _Pragma("unroll") for (int kk_ = 0; kk_ < 2; ++kk_) \
          acc[(AH)*4+mi_][(BH)*2+nj_] = \
            MFMA16(af[mi_][kk_], bg[nj_][kk_], acc[(AH)*4+mi_][(BH)*2+nj_]); \
    __builtin_amdgcn_s_setprio(0); CFENCE; \
    __builtin_amdgcn_s_barrier(); CFENCE;

  stageHalf(&sA[0][0], A,  m0, 0, 0);
  stageHalf(&sB[0][0], Bt, n0, 0, 0);
  stageHalf(&sA[0][0], A,  m0, 1, 0);
  stageHalf(&sB[0][0], Bt, n0, 1, 0);
  stageHalf(&sA[1][0], A,  m0, 0, 64);
  stageHalf(&sB[1][0], Bt, n0, 1, 64);
  VMCNT(4);
  __builtin_amdgcn_s_barrier();
  CFENCE;

  const int NI = K >> 7;
  for (int i = 0; i < NI; ++i){
    const int kt = i << 7;
    const bool lastI = (i == NI-1);
    LOADA(0,0) LOADB(0,0)
    stageHalf(&sA[1][0], A,  m0, 1, kt+64);
    MMQ(0,0)
    LOADB(0,1)
    stageHalf(&sB[1][0], Bt, n0, 0, kt+64);
    MMQ(0,1)
    LOADA(0,1)
    if (!lastI) stageHalf(&sA[0][0], A,  m0, 0, kt+128);
    MMQ(1,1)
    LOADB(0,0)
    if (!lastI) stageHalf(&sB[0][0], Bt, n0, 1, kt+128);
    if (lastI){ VMCNT(0); } else { VMCNT(4); }
    MMQ(1,0)
    LOADA(1,0) LOADB(1,0)
    if (!lastI) stageHalf(&sA[0][0], A,  m0, 1, kt+128);
    MMQ(0,0)
    LOADB(1,1)
    if (!lastI) stageHalf(&sB[0][0], Bt, n0, 0, kt+128);
    MMQ(0,1)
    LOADA(1,1)
    if (!lastI) stageHalf(&sA[1][0], A,  m0, 0, kt+192);
    MMQ(1,1)
    LOADB(1,0)
    if (!lastI){ stageHalf(&sB[1][0], Bt, n0, 1, kt+192); VMCNT(4); }
    MMQ(1,0)
  }
#undef LOADA
#undef LOADB
#undef MMQ

  G256_EPILOGUE
}

// ---------------- variant B: 256x256 2-phase (minimum-T3 recipe) -----------
template<bool SKIP, int LOG_NXB>
__global__ __launch_bounds__(512, 2) void k_gemm256p2(const ushort_t* __restrict__ A,
        const ushort_t* __restrict__ Bt, const float* __restrict__ bias,
        ushort_t* __restrict__ Cp, int M, int N, int K, const int* __restrict__ cnt){
  G256_COMMON

  auto stageTile = [&](int buf, int k0){
    stageHalf(&sA[buf][0], A,  m0, 0, k0);
    stageHalf(&sA[buf][0], A,  m0, 1, k0);
    stageHalf(&sB[buf][0], Bt, n0, 0, k0);
    stageHalf(&sB[buf][0], Bt, n0, 1, k0);
  };

  stageTile(0, 0);
  VMCNT(0);
  __builtin_amdgcn_s_barrier();
  CFENCE;

  const int nk = K >> 6;
  for (int ks = 0; ks < nk; ++ks){
    if (ks + 1 < nk) stageTile((ks+1)&1, (ks+1) << 6);
    const int buf = ks & 1;
    short8 af[8][2], bg[4][2];
    #pragma unroll
    for (int a2 = 0; a2 < 2; ++a2)
      #pragma unroll
      for (int mi = 0; mi < 4; ++mi)
        #pragma unroll
        for (int kk = 0; kk < 2; ++kk)
          af[a2*4+mi][kk] = ldsA(buf, a2*128 + wm*64 + mi*16 + lo, kk);
    #pragma unroll
    for (int b2 = 0; b2 < 2; ++b2)
      #pragma unroll
      for (int nj = 0; nj < 2; ++nj)
        #pragma unroll
        for (int kk = 0; kk < 2; ++kk)
          bg[b2*2+nj][kk] = ldsB(buf, b2*128 + wn*32 + nj*16 + lo, kk);
    __builtin_amdgcn_s_setprio(1);
    #pragma unroll
    for (int mi8 = 0; mi8 < 8; ++mi8)
      #pragma unroll
      for (int nj4 = 0; nj4 < 4; ++nj4)
        #pragma unroll
        for (int kk = 0; kk < 2; ++kk)
          acc[mi8][nj4] = MFMA16(af[mi8][kk], bg[nj4][kk], acc[mi8][nj4]);
    __builtin_amdgcn_s_setprio(0);
    CFENCE;
    VMCNT(0);
    __builtin_amdgcn_s_barrier();
    CFENCE;
  }

  G256_EPILOGUE
}

// ---------------- flash attention: one block per (b,h), fused KV -----------
__global__ __launch_bounds__(256) void k_attn(const ushort_t* __restrict__ qb,
        const ushort_t* __restrict__ kvb, const int* __restrict__ cnt,
        ushort_t* __restrict__ outb){
  const int bh = blockIdx.x;
  const int b = bh >> 4, h = bh & 15;
  const int t = threadIdx.x;
  const int wave = t >> 6, lane = t & 63, lo = lane & 15, hi = lane >> 4;
  __shared__ ushort_t Qs[64*64];
  __shared__ ushort_t Ks[64*64];
  __shared__ ushort_t Vt[64][72];
  __shared__ ushort_t Ps[4][16][72];

  const int count = cnt[b];

  #pragma unroll
  for (int p = 0; p < 2; ++p){
    int r = p*32 + wave*8 + (lane >> 3);
    int c = (lane & 7) ^ (r & 7);
    const ushort_t* gp = qb + (size_t)(b*64 + r)*1024 + h*64 + c*8;
    char* lp = (char*)Qs + p*4096 + wave*1024;
    GLOAD16(gp, lp);
  }

  f32x4 oacc[4] = {};
  float m[4], l[4];
  #pragma unroll
  for (int rr = 0; rr < 4; ++rr){ m[rr] = -__builtin_inff(); l[rr] = 0.f; }

  const int ntiles = (count + 63) >> 6;
  for (int tt = 0; tt < ntiles; ++tt){
    __syncthreads();
    #pragma unroll
    for (int p = 0; p < 2; ++p){
      int r = p*32 + wave*8 + (lane >> 3);
      int c = (lane & 7) ^ (r & 7);
      const ushort_t* gp = kvb + (size_t)(b*2048 + tt*64 + r)*2048 + h*64 + c*8;
      char* lp = (char*)Ks + p*4096 + wave*1024;
      GLOAD16(gp, lp);
    }
    {
      int jj = (t & 31)*2, c = (t >> 5)*8;
      const ushort_t* g0 = kvb + (size_t)(b*2048 + tt*64 + jj)*2048 + 1024 + h*64 + c;
      ushort4v a0 = *(const ushort4v*)(g0);
      ushort4v a1 = *(const ushort4v*)(g0 + 4);
      ushort4v b0 = *(const ushort4v*)(g0 + 2048);
      ushort4v b1 = *(const ushort4v*)(g0 + 2052);
      bool va  = (tt*64 + jj)     < count;
      bool vb2 = (tt*64 + jj + 1) < count;
      #pragma unroll
      for (int u = 0; u < 8; ++u){
        ushort_t ea = (u < 4) ? ((ushort_t*)&a0)[u] : ((ushort_t*)&a1)[u-4];
        ushort_t eb = (u < 4) ? ((ushort_t*)&b0)[u] : ((ushort_t*)&b1)[u-4];
        uint32_t word = (va ? (uint32_t)ea : 0u) | ((vb2 ? (uint32_t)eb : 0u) << 16);
        *(uint32_t*)(&Vt[c+u][jj]) = word;
      }
    }
    __syncthreads();

    f32x4 s[4] = {};
    #pragma unroll
    for (int kk = 0; kk < 2; ++kk){
      int rA = wave*16 + lo;
      short8 aq = *(const short8*)(&Qs[rA*64 + (((kk*4 + hi) ^ (rA & 7))*8)]);
      #pragma unroll
      for (int ni = 0; ni < 4; ++ni){
        int rB = ni*16 + lo;
        short8 bk = *(const short8*)(&Ks[rB*64 + (((kk*4 + hi) ^ (rB & 7))*8)]);
        s[ni] = MFMA16(aq, bk, s[ni]);
      }
    }
    #pragma unroll
    for (int ni = 0; ni < 4; ++ni){
      if (tt*64 + ni*16 + lo >= count){
        s[ni][0] = s[ni][1] = s[ni][2] = s[ni][3] = -__builtin_inff();
      }
    }
    float p[4][4];
    #pragma unroll
    for (int rr = 0; rr < 4; ++rr){
      float mx = fmaxf(fmaxf(s[0][rr], s[1][rr]), fmaxf(s[2][rr], s[3][rr]));
      #pragma unroll
      for (int d = 1; d < 16; d <<= 1) mx = fmaxf(mx, __shfl_xor(mx, d));
      float mnew = fmaxf(m[rr], mx);
      float sc = __expf(m[rr] - mnew);
      float rsum = 0.f;
      #pragma unroll
      for (int ni = 0; ni < 4; ++ni){
        float pv = __expf(s[ni][rr] - mnew);
        p[ni][rr] = pv;
        rsum += pv;
      }
      #pragma unroll
      for (int d = 1; d < 16; d <<= 1) rsum += __shfl_xor(rsum, d);
      l[rr] = l[rr]*sc + rsum;
      m[rr] = mnew;
      #pragma unroll
      for (int ni = 0; ni < 4; ++ni) oacc[ni][rr] *= sc;
    }
    #pragma unroll
    for (int ni = 0; ni < 4; ++ni)
      #pragma unroll
      for (int rr = 0; rr < 4; ++rr)
        Ps[wave][hi*4+rr][ni*16+lo] = f2bf(p[ni][rr]);
    asm volatile("s_waitcnt lgkmcnt(0)" ::: "memory");
    #pragma unroll
    for (int kk = 0; kk < 2; ++kk){
      short8 pa = *(const short8*)(&Ps[wave][lo][kk*32 + hi*8]);
      #pragma unroll
      for (int ni = 0; ni < 4; ++ni){
        short8 bv = *(const short8*)(&Vt[ni*16 + lo][kk*32 + hi*8]);
        oacc[ni] = MFMA16(pa, bv, oacc[ni]);
      }
    }
  }
  #pragma unroll
  for (int rr = 0; rr < 4; ++rr){
    float inv = (l[rr] > 0.f) ? 1.f/l[rr] : 0.f;
    #pragma unroll
    for (int ni = 0; ni < 4; ++ni){
      size_t off = (size_t)(b*64 + wave*16 + hi*4 + rr)*1024 + h*64 + ni*16 + lo;
      outb[off] = f2bf(oacc[ni][rr] * inv);
    }
  }
}

// ---------------------------------------------------------------------------
extern "C" void kernel_launch(void* const* d_in, const int* in_sizes, int n_in,
                              void* d_out, int out_size, void* d_ws, size_t ws_size,
                              hipStream_t stream){
  const float* features = (const float*)d_in[0];
  const int*   mask     = (const int*)  d_in[1];
  const float* latents  = (const float*)d_in[2];
  const float* W_down   = (const float*)d_in[3];
  const float* nin_g    = (const float*)d_in[4];
  const float* nin_b    = (const float*)d_in[5];
  const float* lf_g     = (const float*)d_in[6];
  const float* lf_b     = (const float*)d_in[7];
  const float* ll_g     = (const float*)d_in[8];
  const float* ll_b     = (const float*)d_in[9];
  const float* Wq       = (const float*)d_in[10];
  const float* Wk       = (const float*)d_in[11];
  const float* Wv       = (const float*)d_in[12];
  const float* ffln_g   = (const float*)d_in[13];
  const float* ffln_b   = (const float*)d_in[14];
  const float* ff_w1    = (const float*)d_in[15];
  const float* ff_w2    = (const float*)d_in[16];
  const float* nout_g   = (const float*)d_in[17];
  const float* nout_b   = (const float*)d_in[18];

  char* ws = (char*)d_ws;
  size_t off = 0;
  auto alloc = [&](size_t bytes)->char*{
    char* p = ws + off;
    off += (bytes + 255) & ~(size_t)255;
    return p;
  };
  const size_t SZW  = (size_t)1024*1024*2;      // 2 MB (1024x1024 bf16)
  const size_t SZKV = (size_t)65536*2048*2;     // 256 MB

  ushort_t* FHAT  = (ushort_t*)alloc((size_t)65536*1024*2);   // 128 MB
  ushort_t* WDT   = (ushort_t*)alloc(SZW);
  ushort_t* WQT6  = (ushort_t*)alloc(SZW*6);
  ushort_t* WKVT6 = (ushort_t*)alloc(SZW*2*6);
  ushort_t* W1T6  = (ushort_t*)alloc(SZW*2*6);
  ushort_t* W2T6  = (ushort_t*)alloc(SZW*2*6);
  float* BD   = (float*)alloc(1024*4);
  float* BQ6  = (float*)alloc(1024*4*6);
  float* BKV6 = (float*)alloc(2048*4*6);
  float* B16  = (float*)alloc(2048*4*6);
  float*    X    = (float*)   alloc((size_t)2048*1024*4);
  ushort_t* XHAT = (ushort_t*)alloc((size_t)2048*1024*2);
  ushort_t* QP   = (ushort_t*)alloc((size_t)2048*1024*2);
  ushort_t* OUTB = (ushort_t*)alloc((size_t)2048*1024*2);
  ushort_t* OUTH = (ushort_t*)alloc((size_t)2048*1024*2);
  ushort_t* H1   = (ushort_t*)alloc((size_t)2048*2048*2);
  int* CNT = (int*)alloc(32*4);
  int* IDX = (int*)alloc((size_t)65536*4);
  char* kvbase = ws + off;
  size_t avail = (ws_size > off) ? ws_size - off : 0;
  const bool bigws = avail >= 6*SZKV;
  auto kvslice = [&](int i)->ushort_t*{
    return (ushort_t*)(kvbase + (bigws ? (size_t)i*SZKV : 0));
  };
  ushort_t* FNORM = kvslice(0);
  (void)in_sizes; (void)n_in; (void)out_size;

  const float scale = 0.125f;  // DH^-0.5

  // ---- batched weight folds (all depth-independent) ----
  FoldTArgs fa; int nf = 0;
  auto addF = [&](const float* W, const float* g, float sc, ushort_t* dst, int K, int N){
    fa.d[nf++] = FDesc{W, g, dst, sc, K, N};
  };
  addF(W_down, nin_g, 1.f, WDT, 1024, 1024);
  for (int i = 0; i < 6; ++i){
    const float* Wqi = Wq + (size_t)i*1024*1024;
    const float* Wki = Wk + (size_t)i*1024*1024;
    const float* Wvi = Wv + (size_t)i*1024*1024;
    const float* W1i = ff_w1 + (size_t)i*1024*2048;
    const float* W2i = ff_w2 + (size_t)i*2048*1024;
    addF(Wqi, ll_g + i*1024, scale, WQT6  + i*(SZW/2),        1024, 1024);
    addF(Wki, lf_g + i*1024, 1.f,   WKVT6 + i*SZW,            1024, 1024);
    addF(Wvi, lf_g + i*1024, 1.f,   WKVT6 + i*SZW + (SZW/2),  1024, 1024);
    addF(W1i, ffln_g + i*1024, 1.f, W1T6  + i*SZW,            1024, 2048);
    addF(W2i, nullptr, 1.f,         W2T6  + i*SZW,            2048, 1024);
  }
  fa.cnt = nf;

  BiasArgs ba; int nb = 0;
  auto addB = [&](const float* W, const float* b, float sc, float* dst, int K, int N){
    ba.d[nb++] = BDesc{W, b, dst, sc, K, N};
  };
  addB(W_down, nin_b, 1.f, BD, 1024, 1024);
  for (int i = 0; i < 6; ++i){
    const float* Wqi = Wq + (size_t)i*1024*1024;
    const float* Wki = Wk + (size_t)i*1024*1024;
    const float* Wvi = Wv + (size_t)i*1024*1024;
    const float* W1i = ff_w1 + (size_t)i*1024*2048;
    addB(Wqi, ll_b + i*1024, scale, BQ6  + i*1024,        1024, 1024);
    addB(Wki, lf_b + i*1024, 1.f,   BKV6 + i*2048,        1024, 1024);
    addB(Wvi, lf_b + i*1024, 1.f,   BKV6 + i*2048 + 1024, 1024, 1024);
    addB(W1i, ffln_b + i*1024, 1.f, B16  + i*2048,        1024, 2048);
  }
  ba.cnt = nb;

  // ---- setup ----
  k_compact     <<<32,    256, 0, stream>>>(mask, IDX, CNT);
  k_gather_norm <<<65536, 256, 0, stream>>>(features, IDX, CNT, FNORM);
  k_foldT_all   <<<dim3(512, nf), 256, 0, stream>>>(fa);
  k_foldBias_all<<<dim3(64,  nb), 256, 0, stream>>>(ba);
  k_gemm256p2<true,2><<<1024, 512, 0, stream>>>(FNORM, WDT, BD, FHAT, 65536, 1024, 1024, CNT);
  k_rownorm_bf16<<<65536, 256, 0, stream>>>(FHAT, FHAT, CNT);
  k_init_x      <<<2048,  256, 0, stream>>>(latents, X);

  // ---- KV projections: back-to-back for L3 reuse of FHAT (bigws) ----
  auto launch_kv = [&](int i){
    if (i < 3)
      k_gemm256p2<true,3><<<2048, 512, 0, stream>>>(FHAT, WKVT6 + i*SZW, BKV6 + i*2048,
                                                    kvslice(i), 65536, 2048, 1024, CNT);
    else
      k_gemm256p8<true,3><<<2048, 512, 0, stream>>>(FHAT, WKVT6 + i*SZW, BKV6 + i*2048,
                                                    kvslice(i), 65536, 2048, 1024, CNT);
  };
  if (bigws) for (int i = 0; i < 6; ++i) launch_kv(i);

  for (int i = 0; i < 6; ++i){
    if (!bigws) launch_kv(i);
    k_rownorm_f32<<<2048, 256, 0, stream>>>(X, XHAT);
    k_gemm<0,false,false,0><<<dim3(8,16),  256, 0, stream>>>(XHAT, WQT6 + i*(SZW/2), BQ6 + i*1024,
                                                             QP, 2048, 1024, 1024, nullptr);
    k_attn<<<512, 256, 0, stream>>>(QP, kvslice(i), CNT, OUTB);
    k_rownorm_bf16<<<2048, 256, 0, stream>>>(OUTB, OUTH, nullptr);
    k_gemm<1,false,false,0><<<dim3(16,16), 256, 0, stream>>>(OUTH, W1T6 + i*SZW, B16 + i*2048,
                                                             H1, 2048, 2048, 1024, nullptr);
    k_gemm<2,false,false,0><<<dim3(8,16),  256, 0, stream>>>(H1, W2T6 + i*SZW, nullptr,
                                                             X, 2048, 1024, 2048, nullptr);
  }
  k_final_ln<<<2048, 256, 0, stream>>>(X, nout_g, nout_b, (float*)d_out);
}

// Round 6
// 2480.516 us; speedup vs baseline: 1.3361x; 1.0077x over previous
//
#include <hip/hip_runtime.h>
#include <stdint.h>

// ---------------------------------------------------------------------------
// PerceiverResampler on MI355X (gfx950)
// B=32, F=2048, DIM=1024, INNER=1024, H=16, DH=64, Q=64, DEPTH=6, MULT=2
//
// Round 6 (= R5 resubmit after infra flake): all big GEMMs on the 8-phase
// 256x256 schedule (p8 beat p2 in R4's A/B); attention rewritten with
// double-buffered K/V tiles + light barriers (no vmcnt drains in the loop ->
// HBM latency hides under softmax+PV).
// ---------------------------------------------------------------------------

#define DEV static __device__ __forceinline__

typedef __attribute__((ext_vector_type(8))) short short8;
typedef __attribute__((ext_vector_type(4))) float f32x4;
typedef __attribute__((ext_vector_type(4))) unsigned short ushort4v;
typedef unsigned short ushort_t;

DEV float bf2f(ushort_t u){ union{uint32_t i; float f;} x; x.i = ((uint32_t)u)<<16; return x.f; }
DEV ushort_t f2bf(float f){
  union{float f; uint32_t i;} x; x.f = f;
  uint32_t r = x.i + 0x7fffu + ((x.i>>16)&1u);  // RNE
  return (ushort_t)(r>>16);
}

#define GLOAD16(gp, lp) __builtin_amdgcn_global_load_lds( \
    (const __attribute__((address_space(1))) uint32_t*)(gp), \
    (__attribute__((address_space(3))) uint32_t*)(lp), 16, 0, 0)

#define VMCNT(n) asm volatile("s_waitcnt vmcnt(" #n ")" ::: "memory")
#define CFENCE   asm volatile("" ::: "memory")
#define MFMA16(a,b,c) __builtin_amdgcn_mfma_f32_16x16x32_bf16(a,b,c,0,0,0)

// XCD-locality remap: all NXB N-blocks of one M-row land on the same XCD.
template<int LOG_NXB>
DEV void xcd_remap(int g, int total, int& x, int& y){
  int xcd = g & 7;
  int k = g >> 3;
  int rows_per_xcd = (total >> LOG_NXB) >> 3;
  y = xcd * rows_per_xcd + (k >> LOG_NXB);
  x = k & ((1 << LOG_NXB) - 1);
}

// ---------------- block reduce (sum of two values, 256 threads) ------------
DEV void reduce2(float& a, float& b){
  #pragma unroll
  for (int d = 32; d; d >>= 1){ a += __shfl_down(a, d); b += __shfl_down(b, d); }
  __shared__ float sh[8];
  int w = threadIdx.x >> 6, l = threadIdx.x & 63;
  if (l == 0){ sh[w*2] = a; sh[w*2+1] = b; }
  __syncthreads();
  a = sh[0]+sh[2]+sh[4]+sh[6];
  b = sh[1]+sh[3]+sh[5]+sh[7];
}

// ---------------- mask compaction ------------------------------------------
__global__ __launch_bounds__(256) void k_compact(const int* __restrict__ mask,
                                                 int* __restrict__ idx, int* __restrict__ cnt){
  int b = blockIdx.x, t = threadIdx.x;
  const int* mb = mask + b*2048;
  int keep[8]; int c = 0;
  #pragma unroll
  for (int u = 0; u < 8; ++u){ keep[u] = (mb[t*8+u] != 0); c += keep[u]; }
  __shared__ int s[256];
  s[t] = c; __syncthreads();
  for (int off = 1; off < 256; off <<= 1){
    int v = (t >= off) ? s[t-off] : 0;
    __syncthreads();
    s[t] += v;
    __syncthreads();
  }
  int pos = s[t] - c;
  #pragma unroll
  for (int u = 0; u < 8; ++u) if (keep[u]) idx[b*2048 + pos++] = t*8 + u;
  if (t == 255) cnt[b] = s[255];
}

// ---------------- gather + rownorm features -> bf16 ------------------------
__global__ __launch_bounds__(256) void k_gather_norm(const float* __restrict__ feat,
        const int* __restrict__ idx, const int* __restrict__ cnt, ushort_t* __restrict__ outp){
  int blk = blockIdx.x; int b = blk >> 11, j = blk & 2047;
  if (j >= cnt[b]) return;
  int src = idx[b*2048 + j];
  const float* row = feat + ((size_t)(b*2048 + src))*1024;
  int t = threadIdx.x;
  float4 v = *(const float4*)(row + t*4);
  float s = v.x+v.y+v.z+v.w;
  float q = v.x*v.x+v.y*v.y+v.z*v.z+v.w*v.w;
  reduce2(s, q);
  float mean = s * (1.f/1024.f);
  float rstd = rsqrtf(q*(1.f/1024.f) - mean*mean + 1e-5f);
  ushort4v o;
  o.x = f2bf((v.x-mean)*rstd); o.y = f2bf((v.y-mean)*rstd);
  o.z = f2bf((v.z-mean)*rstd); o.w = f2bf((v.w-mean)*rstd);
  *(ushort4v*)(outp + ((size_t)(b*2048+j))*1024 + t*4) = o;
}

// ---------------- rownorm bf16 -> bf16 (optional skip) ---------------------
__global__ __launch_bounds__(256) void k_rownorm_bf16(const ushort_t* __restrict__ in,
        ushort_t* __restrict__ outp, const int* __restrict__ cnt){
  int blk = blockIdx.x;
  if (cnt){ int b = blk >> 11; if ((blk & 2047) >= cnt[b]) return; }
  int t = threadIdx.x;
  ushort4v u = *(const ushort4v*)(in + (size_t)blk*1024 + t*4);
  float f0 = bf2f(u.x), f1 = bf2f(u.y), f2 = bf2f(u.z), f3 = bf2f(u.w);
  float s = f0+f1+f2+f3, q = f0*f0+f1*f1+f2*f2+f3*f3;
  reduce2(s, q);
  float mean = s * (1.f/1024.f);
  float rstd = rsqrtf(q*(1.f/1024.f) - mean*mean + 1e-5f);
  ushort4v o;
  o.x = f2bf((f0-mean)*rstd); o.y = f2bf((f1-mean)*rstd);
  o.z = f2bf((f2-mean)*rstd); o.w = f2bf((f3-mean)*rstd);
  *(ushort4v*)(outp + (size_t)blk*1024 + t*4) = o;
}

// ---------------- rownorm f32 -> bf16 --------------------------------------
__global__ __launch_bounds__(256) void k_rownorm_f32(const float* __restrict__ in,
                                                     ushort_t* __restrict__ outp){
  int blk = blockIdx.x, t = threadIdx.x;
  float4 v = *(const float4*)(in + (size_t)blk*1024 + t*4);
  float s = v.x+v.y+v.z+v.w;
  float q = v.x*v.x+v.y*v.y+v.z*v.z+v.w*v.w;
  reduce2(s, q);
  float mean = s * (1.f/1024.f);
  float rstd = rsqrtf(q*(1.f/1024.f) - mean*mean + 1e-5f);
  ushort4v o;
  o.x = f2bf((v.x-mean)*rstd); o.y = f2bf((v.y-mean)*rstd);
  o.z = f2bf((v.z-mean)*rstd); o.w = f2bf((v.w-mean)*rstd);
  *(ushort4v*)(outp + (size_t)blk*1024 + t*4) = o;
}

// ---------------- final layernorm (affine) f32 -> f32 ----------------------
__global__ __launch_bounds__(256) void k_final_ln(const float* __restrict__ x,
        const float* __restrict__ g, const float* __restrict__ bb, float* __restrict__ outp){
  int blk = blockIdx.x, t = threadIdx.x;
  float4 v = *(const float4*)(x + (size_t)blk*1024 + t*4);
  float s = v.x+v.y+v.z+v.w;
  float q = v.x*v.x+v.y*v.y+v.z*v.z+v.w*v.w;
  reduce2(s, q);
  float mean = s * (1.f/1024.f);
  float rstd = rsqrtf(q*(1.f/1024.f) - mean*mean + 1e-5f);
  float4 gg = *(const float4*)(g + t*4);
  float4 bv = *(const float4*)(bb + t*4);
  float4 o;
  o.x = (v.x-mean)*rstd*gg.x + bv.x; o.y = (v.y-mean)*rstd*gg.y + bv.y;
  o.z = (v.z-mean)*rstd*gg.z + bv.z; o.w = (v.w-mean)*rstd*gg.w + bv.w;
  *(float4*)(outp + (size_t)blk*1024 + t*4) = o;
}

// ---------------- x init: broadcast latents --------------------------------
__global__ __launch_bounds__(256) void k_init_x(const float* __restrict__ lat, float* __restrict__ x){
  int v = blockIdx.x*256 + threadIdx.x;
  int row = v >> 8, cv = v & 255;
  ((float4*)x)[v] = ((const float4*)lat)[(row & 63)*256 + cv];
}

// ---------------- batched weight fold + transpose --------------------------
DEV void foldT_body(const float* __restrict__ W, const float* __restrict__ g,
                    float scale, ushort_t* __restrict__ Wt, int K, int N,
                    int n0, int k0){
  __shared__ float Ts[64][65];
  int t = threadIdx.x;
  #pragma unroll
  for (int i = 0; i < 4; ++i){
    int flat = i*1024 + t*4; int r = flat >> 6, c = flat & 63;
    float4 v = *(const float4*)(W + (size_t)(k0+r)*N + n0 + c);
    float gg = (g ? g[k0+r] : 1.f) * scale;
    Ts[r][c] = v.x*gg; Ts[r][c+1] = v.y*gg; Ts[r][c+2] = v.z*gg; Ts[r][c+3] = v.w*gg;
  }
  __syncthreads();
  #pragma unroll
  for (int i = 0; i < 4; ++i){
    int flat = i*1024 + t*4; int rn = flat >> 6, ck = flat & 63;
    ushort4v o;
    o.x = f2bf(Ts[ck][rn]);   o.y = f2bf(Ts[ck+1][rn]);
    o.z = f2bf(Ts[ck+2][rn]); o.w = f2bf(Ts[ck+3][rn]);
    *(ushort4v*)(Wt + (size_t)(n0+rn)*K + k0 + ck) = o;
  }
}

struct FDesc { const float* W; const float* g; ushort_t* dst; float scale; int K; int N; };
#define MAXFD 32
struct FoldTArgs { int cnt; FDesc d[MAXFD]; };

__global__ __launch_bounds__(256) void k_foldT_all(FoldTArgs a){
  const FDesc d = a.d[blockIdx.y];
  int nxb = d.N >> 6;
  int n0 = (blockIdx.x % nxb) * 64;
  int k0 = (blockIdx.x / nxb) * 64;
  if (k0 >= d.K) return;
  foldT_body(d.W, d.g, d.scale, d.dst, d.K, d.N, n0, k0);
}

// ---------------- batched bias fold ----------------------------------------
DEV void foldBias_body(const float* __restrict__ W, const float* __restrict__ bvec,
                       float scale, float* __restrict__ bias, int K, int N, int o0){
  int t = threadIdx.x;
  int ol = t & 31, kc = t >> 5;
  int o = o0 + ol;
  int chunk = K >> 3;
  int c0 = kc*chunk, c1 = c0 + chunk;
  float s0 = 0, s1 = 0, s2 = 0, s3 = 0;
  for (int c = c0; c < c1; c += 4){
    s0 += bvec[c+0]*W[(size_t)(c+0)*N + o];
    s1 += bvec[c+1]*W[(size_t)(c+1)*N + o];
    s2 += bvec[c+2]*W[(size_t)(c+2)*N + o];
    s3 += bvec[c+3]*W[(size_t)(c+3)*N + o];
  }
  __shared__ float red[8][32];
  red[kc][ol] = (s0+s1)+(s2+s3);
  __syncthreads();
  if (kc == 0){
    float tot = 0;
    #pragma unroll
    for (int jj = 0; jj < 8; ++jj) tot += red[jj][ol];
    bias[o] = tot * scale;
  }
}

struct BDesc { const float* W; const float* b; float* dst; float scale; int K; int N; };
#define MAXBD 25
struct BiasArgs { int cnt; BDesc d[MAXBD]; };

__global__ __launch_bounds__(256) void k_foldBias_all(BiasArgs a){
  const BDesc d = a.d[blockIdx.y];
  int o0 = blockIdx.x * 32;
  if (o0 >= d.N) return;
  foldBias_body(d.W, d.b, d.scale, d.dst, d.K, d.N, o0);
}

// ---------------- 128x128 2-phase GEMM -------------------------------------
// OUTMODE: 0 = bf16 store, 1 = bf16 relu store, 2 = f32 accumulate (C += v)
template<int OUTMODE, bool SKIP, bool REMAP, int LOG_NXB>
__global__ __launch_bounds__(256, 4) void k_gemm(const ushort_t* __restrict__ A,
        const ushort_t* __restrict__ Bt, const float* __restrict__ bias,
        void* __restrict__ Cp, int M, int N, int K, const int* __restrict__ cnt){
  int bx, by;
  if (REMAP) xcd_remap<LOG_NXB>(blockIdx.x, gridDim.x, bx, by);
  else { bx = blockIdx.x; by = blockIdx.y; }
  const int n0 = bx * 128;
  const int m0 = by * 128;
  if (SKIP){ int b = m0 >> 11; if ((m0 & 2047) >= cnt[b]) return; }
  __shared__ ushort_t sA[2][128*32];
  __shared__ ushort_t sB[2][128*32];
  const int tid = threadIdx.x;
  const int wave = tid >> 6, lane = tid & 63;
  const int lo = lane & 15, hi = lane >> 4;
  const int wr = wave >> 1, wc = wave & 1;

  auto stage = [&](int buf, int k0){
    #pragma unroll
    for (int p = 0; p < 2; ++p){
      int r = p*64 + wave*16 + (lane >> 2);
      int c = lane & 3;
      {
        const ushort_t* gp = A + (size_t)(m0 + r)*K + k0 + c*8;
        char* lp = (char*)(&sA[buf][0]) + p*4096 + wave*1024;
        GLOAD16(gp, lp);
      }
      {
        const ushort_t* gp = Bt + (size_t)(n0 + r)*K + k0 + c*8;
        char* lp = (char*)(&sB[buf][0]) + p*4096 + wave*1024;
        GLOAD16(gp, lp);
      }
    }
  };

  f32x4 acc[4][4] = {};
  stage(0, 0);
  const int nk = K >> 5;
  for (int ks = 0; ks < nk; ++ks){
    __syncthreads();
    if (ks + 1 < nk) stage((ks+1)&1, (ks+1) << 5);
    const int buf = ks & 1;
    short8 af[4], bfr[4];
    #pragma unroll
    for (int mi = 0; mi < 4; ++mi)
      af[mi] = *(const short8*)(&sA[buf][(wr*64 + mi*16 + lo)*32 + hi*8]);
    #pragma unroll
    for (int ni = 0; ni < 4; ++ni)
      bfr[ni] = *(const short8*)(&sB[buf][(wc*64 + ni*16 + lo)*32 + hi*8]);
    #pragma unroll
    for (int mi = 0; mi < 4; ++mi)
      #pragma unroll
      for (int ni = 0; ni < 4; ++ni)
        acc[mi][ni] = MFMA16(af[mi], bfr[ni], acc[mi][ni]);
  }
  #pragma unroll
  for (int ni = 0; ni < 4; ++ni){
    int col = n0 + wc*64 + ni*16 + lo;
    float bv = bias ? bias[col] : 0.f;
    #pragma unroll
    for (int mi = 0; mi < 4; ++mi){
      int rbase = m0 + wr*64 + mi*16 + hi*4;
      #pragma unroll
      for (int rr = 0; rr < 4; ++rr){
        float v = acc[mi][ni][rr] + bv;
        size_t off = (size_t)(rbase + rr)*N + col;
        if (OUTMODE == 0)      ((ushort_t*)Cp)[off] = f2bf(v);
        else if (OUTMODE == 1) ((ushort_t*)Cp)[off] = f2bf(fmaxf(v, 0.f));
        else                   ((float*)Cp)[off] += v;
      }
    }
  }
}

// ======= shared pieces for the 256x256 kernels (8 waves, 512 threads) ======
#define G256_COMMON \
  int bx, by; \
  xcd_remap<LOG_NXB>(blockIdx.x, gridDim.x, bx, by); \
  const int n0 = bx * 256; \
  const int m0 = by * 256; \
  if (SKIP){ int b = m0 >> 11; if ((m0 & 2047) >= cnt[b]) return; } \
  __shared__ __align__(16) ushort_t sA[2][256*64]; \
  __shared__ __align__(16) ushort_t sB[2][256*64]; \
  const int tid = threadIdx.x; \
  const int wave = tid >> 6, lane = tid & 63; \
  const int lo = lane & 15, hi = lane >> 4; \
  const int wm = wave >> 2, wn = wave & 3; \
  const int srow = lane >> 3; \
  const int schunk = (lane & 7) ^ srow; \
  auto stageHalf = [&](ushort_t* dst, const ushort_t* __restrict__ G, int grow0, \
                       int half, int k0){ \
    _Pragma("unroll") \
    for (int p = 0; p < 2; ++p){ \
      int rbase = half*128 + p*64 + wave*8; \
      const ushort_t* gp = G + (size_t)(grow0 + rbase + srow)*K + k0 + schunk*8; \
      char* lp = (char*)dst + (size_t)rbase*128; \
      GLOAD16(gp, lp); \
    } \
  }; \
  auto ldsA = [&](int buf, int row, int kk)->short8{ \
    int ch = ((kk<<2) + hi) ^ (row & 7); \
    return *(const short8*)((const char*)sA + (size_t)buf*32768 + (size_t)row*128 + ch*16); \
  }; \
  auto ldsB = [&](int buf, int row, int kk)->short8{ \
    int ch = ((kk<<2) + hi) ^ (row & 7); \
    return *(const short8*)((const char*)sB + (size_t)buf*32768 + (size_t)row*128 + ch*16); \
  }; \
  f32x4 acc[8][4] = {};

#define G256_EPILOGUE \
  _Pragma("unroll") \
  for (int b2 = 0; b2 < 2; ++b2) \
    _Pragma("unroll") \
    for (int nj = 0; nj < 2; ++nj){ \
      int col = n0 + b2*128 + wn*32 + nj*16 + lo; \
      float bv = bias ? bias[col] : 0.f; \
      _Pragma("unroll") \
      for (int a2 = 0; a2 < 2; ++a2) \
        _Pragma("unroll") \
        for (int mi4 = 0; mi4 < 4; ++mi4){ \
          int rbase = m0 + a2*128 + wm*64 + mi4*16 + hi*4; \
          _Pragma("unroll") \
          for (int rr = 0; rr < 4; ++rr){ \
            float v = acc[a2*4+mi4][b2*2+nj][rr] + bv; \
            Cp[(size_t)(rbase + rr)*N + col] = f2bf(v); \
          } \
        } \
    }

// ---------------- 256x256 8-phase GEMM, counted vmcnt ----------------------
template<bool SKIP, int LOG_NXB>
__global__ __launch_bounds__(512, 2) void k_gemm256p8(const ushort_t* __restrict__ A,
        const ushort_t* __restrict__ Bt, const float* __restrict__ bias,
        ushort_t* __restrict__ Cp, int M, int N, int K, const int* __restrict__ cnt){
  G256_COMMON

  short8 af[4][2], bg[2][2];
#define LOADA(BUF, AH) \
    _Pragma("unroll") for (int mi_ = 0; mi_ < 4; ++mi_) \
      _Pragma("unroll") for (int kk_ = 0; kk_ < 2; ++kk_) \
        af[mi_][kk_] = ldsA(BUF, (AH)*128 + wm*64 + mi_*16 + lo, kk_);
#define LOADB(BUF, BH) \
    _Pragma("unroll") for (int nj_ = 0; nj_ < 2; ++nj_) \
      _Pragma("unroll") for (int kk_ = 0; kk_ < 2; ++kk_) \
        bg[nj_][kk_] = ldsB(BUF, (BH)*128 + wn*32 + nj_*16 + lo, kk_);
#define MMQ(AH, BH) \
    __builtin_amdgcn_s_barrier(); CFENCE; \
    __builtin_amdgcn_s_setprio(1); \
    _Pragma("unroll") for (int mi_ = 0; mi_ < 4; ++mi_) \
      _Pragma("unroll") for (int nj_ = 0; nj_ < 2; ++nj_) \
        _Pragma("unroll") for (int kk_ = 0; kk_ < 2; ++kk_) \
          acc[(AH)*4+mi_][(BH)*2+nj_] = \
            MFMA16(af[mi_][kk_], bg[nj_][kk_], acc[(AH)*4+mi_][(BH)*2+nj_]); \
    __builtin_amdgcn_s_setprio(0); CFENCE; \
    __builtin_amdgcn_s_barrier(); CFENCE;

  stageHalf(&sA[0][0], A,  m0, 0, 0);
  stageHalf(&sB[0][0], Bt, n0, 0, 0);
  stageHalf(&sA[0][0], A,  m0, 1, 0);
  stageHalf(&sB[0][0], Bt, n0, 1, 0);
  stageHalf(&sA[1][0], A,  m0, 0, 64);
  stageHalf(&sB[1][0], Bt, n0, 1, 64);
  VMCNT(4);
  __builtin_amdgcn_s_barrier();
  CFENCE;

  const int NI = K >> 7;
  for (int i = 0; i < NI; ++i){
    const int kt = i << 7;
    const bool lastI = (i == NI-1);
    LOADA(0,0) LOADB(0,0)
    stageHalf(&sA[1][0], A,  m0, 1, kt+64);
    MMQ(0,0)
    LOADB(0,1)
    stageHalf(&sB[1][0], Bt, n0, 0, kt+64);
    MMQ(0,1)
    LOADA(0,1)
    if (!lastI) stageHalf(&sA[0][0], A,  m0, 0, kt+128);
    MMQ(1,1)
    LOADB(0,0)
    if (!lastI) stageHalf(&sB[0][0], Bt, n0, 1, kt+128);
    if (lastI){ VMCNT(0); } else { VMCNT(4); }
    MMQ(1,0)
    LOADA(1,0) LOADB(1,0)
    if (!lastI) stageHalf(&sA[0][0], A,  m0, 1, kt+128);
    MMQ(0,0)
    LOADB(1,1)
    if (!lastI) stageHalf(&sB[0][0], Bt, n0, 0, kt+128);
    MMQ(0,1)
    LOADA(1,1)
    if (!lastI) stageHalf(&sA[1][0], A,  m0, 0, kt+192);
    MMQ(1,1)
    LOADB(1,0)
    if (!lastI){ stageHalf(&sB[1][0], Bt, n0, 1, kt+192); VMCNT(4); }
    MMQ(1,0)
  }
#undef LOADA
#undef LOADB
#undef MMQ

  G256_EPILOGUE
}

// ---------------- flash attention (pipelined): one block per (b,h) ---------
// Double-buffered Ks/Vt; V reg-loads + K gload_lds for tile t+1 issued in
// tile t's pre-barrier region. No vmcnt drains in the loop: the implicit
// wait at the Vt write (uses V(t) regs, issued LAST among t's loads) drains
// the per-wave vmcnt FIFO through K(t)'s gload_lds too.
__global__ __launch_bounds__(256) void k_attn(const ushort_t* __restrict__ qb,
        const ushort_t* __restrict__ kvb, const int* __restrict__ cnt,
        ushort_t* __restrict__ outb){
  const int bh = blockIdx.x;
  const int b = bh >> 4, h = bh & 15;
  const int t = threadIdx.x;
  const int wave = t >> 6, lane = t & 63, lo = lane & 15, hi = lane >> 4;
  __shared__ ushort_t Qs[64*64];        // [q][d], chunk-swizzled
  __shared__ ushort_t Ks[2][64*64];     // [j][d], chunk-swizzled, dbuf
  __shared__ ushort_t Vt[2][64][72];    // [d][j], padded, dbuf
  __shared__ ushort_t Ps[4][16][72];    // per-wave P stripe

  const int count = cnt[b];

  // stage Q (gload_lds, pre-swizzled source chunks)
  #pragma unroll
  for (int p = 0; p < 2; ++p){
    int r = p*32 + wave*8 + (lane >> 3);
    int c = (lane & 7) ^ (r & 7);
    const ushort_t* gp = qb + (size_t)(b*64 + r)*1024 + h*64 + c*8;
    char* lp = (char*)Qs + p*4096 + wave*1024;
    GLOAD16(gp, lp);
  }

  auto stageK = [&](int buf, int tt){
    #pragma unroll
    for (int p = 0; p < 2; ++p){
      int r = p*32 + wave*8 + (lane >> 3);
      int c = (lane & 7) ^ (r & 7);
      const ushort_t* gp = kvb + (size_t)(b*2048 + tt*64 + r)*2048 + h*64 + c*8;
      char* lp = (char*)(&Ks[buf][0]) + p*4096 + wave*1024;
      GLOAD16(gp, lp);
    }
  };
  const int vjj = (t & 31)*2, vc = (t >> 5)*8;
  ushort4v va0, va1, vb0, vb1;
  auto issueV = [&](int tt){
    const ushort_t* g0 = kvb + (size_t)(b*2048 + tt*64 + vjj)*2048 + 1024 + h*64 + vc;
    va0 = *(const ushort4v*)(g0);
    va1 = *(const ushort4v*)(g0 + 4);
    vb0 = *(const ushort4v*)(g0 + 2048);
    vb1 = *(const ushort4v*)(g0 + 2052);
  };
  auto writeV = [&](int buf, int tt){
    bool va  = (tt*64 + vjj)     < count;
    bool vb2 = (tt*64 + vjj + 1) < count;
    #pragma unroll
    for (int u = 0; u < 8; ++u){
      ushort_t ea = (u < 4) ? ((ushort_t*)&va0)[u] : ((ushort_t*)&va1)[u-4];
      ushort_t eb = (u < 4) ? ((ushort_t*)&vb0)[u] : ((ushort_t*)&vb1)[u-4];
      uint32_t word = (va ? (uint32_t)ea : 0u) | ((vb2 ? (uint32_t)eb : 0u) << 16);
      *(uint32_t*)(&Vt[buf][vc+u][vjj]) = word;
    }
  };

  f32x4 oacc[4] = {};
  float m[4], l[4];
  #pragma unroll
  for (int rr = 0; rr < 4; ++rr){ m[rr] = -__builtin_inff(); l[rr] = 0.f; }

  const int ntiles = (count + 63) >> 6;
  if (ntiles > 0){ stageK(0, 0); issueV(0); }

  for (int tt = 0; tt < ntiles; ++tt){
    const int buf = tt & 1;
    writeV(buf, tt);                          // implicit vmcnt wait drains K(tt) too
    if (tt + 1 < ntiles){ stageK(buf^1, tt+1); issueV(tt+1); }
    asm volatile("s_waitcnt lgkmcnt(0)" ::: "memory");
    __builtin_amdgcn_s_barrier();
    CFENCE;

    // S = Q @ K^T
    f32x4 s[4] = {};
    #pragma unroll
    for (int kk = 0; kk < 2; ++kk){
      int rA = wave*16 + lo;
      short8 aq = *(const short8*)(&Qs[rA*64 + (((kk*4 + hi) ^ (rA & 7))*8)]);
      #pragma unroll
      for (int ni = 0; ni < 4; ++ni){
        int rB = ni*16 + lo;
        short8 bk = *(const short8*)(&Ks[buf][rB*64 + (((kk*4 + hi) ^ (rB & 7))*8)]);
        s[ni] = MFMA16(aq, bk, s[ni]);
      }
    }
    #pragma unroll
    for (int ni = 0; ni < 4; ++ni){
      if (tt*64 + ni*16 + lo >= count){
        s[ni][0] = s[ni][1] = s[ni][2] = s[ni][3] = -__builtin_inff();
      }
    }
    // online softmax
    float p[4][4];
    #pragma unroll
    for (int rr = 0; rr < 4; ++rr){
      float mx = fmaxf(fmaxf(s[0][rr], s[1][rr]), fmaxf(s[2][rr], s[3][rr]));
      #pragma unroll
      for (int d = 1; d < 16; d <<= 1) mx = fmaxf(mx, __shfl_xor(mx, d));
      float mnew = fmaxf(m[rr], mx);
      float sc = __expf(m[rr] - mnew);
      float rsum = 0.f;
      #pragma unroll
      for (int ni = 0; ni < 4; ++ni){
        float pv = __expf(s[ni][rr] - mnew);
        p[ni][rr] = pv;
        rsum += pv;
      }
      #pragma unroll
      for (int d = 1; d < 16; d <<= 1) rsum += __shfl_xor(rsum, d);
      l[rr] = l[rr]*sc + rsum;
      m[rr] = mnew;
      #pragma unroll
      for (int ni = 0; ni < 4; ++ni) oacc[ni][rr] *= sc;
    }
    // P -> LDS (C-layout), re-read as A-layout (wave-private stripe)
    #pragma unroll
    for (int ni = 0; ni < 4; ++ni)
      #pragma unroll
      for (int rr = 0; rr < 4; ++rr)
        Ps[wave][hi*4+rr][ni*16+lo] = f2bf(p[ni][rr]);
    asm volatile("s_waitcnt lgkmcnt(0)" ::: "memory");
    #pragma unroll
    for (int kk = 0; kk < 2; ++kk){
      short8 pa = *(const short8*)(&Ps[wave][lo][kk*32 + hi*8]);
      #pragma unroll
      for (int ni = 0; ni < 4; ++ni){
        short8 bv = *(const short8*)(&Vt[buf][ni*16 + lo][kk*32 + hi*8]);
        oacc[ni] = MFMA16(pa, bv, oacc[ni]);
      }
    }
    CFENCE;
    __builtin_amdgcn_s_barrier();   // all waves done reading Ks[buf]/Vt[buf]
    CFENCE;
  }
  #pragma unroll
  for (int rr = 0; rr < 4; ++rr){
    float inv = (l[rr] > 0.f) ? 1.f/l[rr] : 0.f;
    #pragma unroll
    for (int ni = 0; ni < 4; ++ni){
      size_t off = (size_t)(b*64 + wave*16 + hi*4 + rr)*1024 + h*64 + ni*16 + lo;
      outb[off] = f2bf(oacc[ni][rr] * inv);
    }
  }
}

// ---------------------------------------------------------------------------
extern "C" void kernel_launch(void* const* d_in, const int* in_sizes, int n_in,
                              void* d_out, int out_size, void* d_ws, size_t ws_size,
                              hipStream_t stream){
  const float* features = (const float*)d_in[0];
  const int*   mask     = (const int*)  d_in[1];
  const float* latents  = (const float*)d_in[2];
  const float* W_down   = (const float*)d_in[3];
  const float* nin_g    = (const float*)d_in[4];
  const float* nin_b    = (const float*)d_in[5];
  const float* lf_g     = (const float*)d_in[6];
  const float* lf_b     = (const float*)d_in[7];
  const float* ll_g     = (const float*)d_in[8];
  const float* ll_b     = (const float*)d_in[9];
  const float* Wq       = (const float*)d_in[10];
  const float* Wk       = (const float*)d_in[11];
  const float* Wv       = (const float*)d_in[12];
  const float* ffln_g   = (const float*)d_in[13];
  const float* ffln_b   = (const float*)d_in[14];
  const float* ff_w1    = (const float*)d_in[15];
  const float* ff_w2    = (const float*)d_in[16];
  const float* nout_g   = (const float*)d_in[17];
  const float* nout_b   = (const float*)d_in[18];

  char* ws = (char*)d_ws;
  size_t off = 0;
  auto alloc = [&](size_t bytes)->char*{
    char* p = ws + off;
    off += (bytes + 255) & ~(size_t)255;
    return p;
  };
  const size_t SZW  = (size_t)1024*1024*2;      // 2 MB (1024x1024 bf16)
  const size_t SZKV = (size_t)65536*2048*2;     // 256 MB

  ushort_t* FHAT  = (ushort_t*)alloc((size_t)65536*1024*2);   // 128 MB
  ushort_t* WDT   = (ushort_t*)alloc(SZW);
  ushort_t* WQT6  = (ushort_t*)alloc(SZW*6);
  ushort_t* WKVT6 = (ushort_t*)alloc(SZW*2*6);
  ushort_t* W1T6  = (ushort_t*)alloc(SZW*2*6);
  ushort_t* W2T6  = (ushort_t*)alloc(SZW*2*6);
  float* BD   = (float*)alloc(1024*4);
  float* BQ6  = (float*)alloc(1024*4*6);
  float* BKV6 = (float*)alloc(2048*4*6);
  float* B16  = (float*)alloc(2048*4*6);
  float*    X    = (float*)   alloc((size_t)2048*1024*4);
  ushort_t* XHAT = (ushort_t*)alloc((size_t)2048*1024*2);
  ushort_t* QP   = (ushort_t*)alloc((size_t)2048*1024*2);
  ushort_t* OUTB = (ushort_t*)alloc((size_t)2048*1024*2);
  ushort_t* OUTH = (ushort_t*)alloc((size_t)2048*1024*2);
  ushort_t* H1   = (ushort_t*)alloc((size_t)2048*2048*2);
  int* CNT = (int*)alloc(32*4);
  int* IDX = (int*)alloc((size_t)65536*4);
  char* kvbase = ws + off;
  size_t avail = (ws_size > off) ? ws_size - off : 0;
  const bool bigws = avail >= 6*SZKV;
  auto kvslice = [&](int i)->ushort_t*{
    return (ushort_t*)(kvbase + (bigws ? (size_t)i*SZKV : 0));
  };
  ushort_t* FNORM = kvslice(0);
  (void)in_sizes; (void)n_in; (void)out_size;

  const float scale = 0.125f;  // DH^-0.5

  // ---- batched weight folds (all depth-independent) ----
  FoldTArgs fa; int nf = 0;
  auto addF = [&](const float* W, const float* g, float sc, ushort_t* dst, int K, int N){
    fa.d[nf++] = FDesc{W, g, dst, sc, K, N};
  };
  addF(W_down, nin_g, 1.f, WDT, 1024, 1024);
  for (int i = 0; i < 6; ++i){
    const float* Wqi = Wq + (size_t)i*1024*1024;
    const float* Wki = Wk + (size_t)i*1024*1024;
    const float* Wvi = Wv + (size_t)i*1024*1024;
    const float* W1i = ff_w1 + (size_t)i*1024*2048;
    const float* W2i = ff_w2 + (size_t)i*2048*1024;
    addF(Wqi, ll_g + i*1024, scale, WQT6  + i*(SZW/2),        1024, 1024);
    addF(Wki, lf_g + i*1024, 1.f,   WKVT6 + i*SZW,            1024, 1024);
    addF(Wvi, lf_g + i*1024, 1.f,   WKVT6 + i*SZW + (SZW/2),  1024, 1024);
    addF(W1i, ffln_g + i*1024, 1.f, W1T6  + i*SZW,            1024, 2048);
    addF(W2i, nullptr, 1.f,         W2T6  + i*SZW,            2048, 1024);
  }
  fa.cnt = nf;

  BiasArgs ba; int nb = 0;
  auto addB = [&](const float* W, const float* b, float sc, float* dst, int K, int N){
    ba.d[nb++] = BDesc{W, b, dst, sc, K, N};
  };
  addB(W_down, nin_b, 1.f, BD, 1024, 1024);
  for (int i = 0; i < 6; ++i){
    const float* Wqi = Wq + (size_t)i*1024*1024;
    const float* Wki = Wk + (size_t)i*1024*1024;
    const float* Wvi = Wv + (size_t)i*1024*1024;
    const float* W1i = ff_w1 + (size_t)i*1024*2048;
    addB(Wqi, ll_b + i*1024, scale, BQ6  + i*1024,        1024, 1024);
    addB(Wki, lf_b + i*1024, 1.f,   BKV6 + i*2048,        1024, 1024);
    addB(Wvi, lf_b + i*1024, 1.f,   BKV6 + i*2048 + 1024, 1024, 1024);
    addB(W1i, ffln_b + i*1024, 1.f, B16  + i*2048,        1024, 2048);
  }
  ba.cnt = nb;

  // ---- setup ----
  k_compact     <<<32,    256, 0, stream>>>(mask, IDX, CNT);
  k_gather_norm <<<65536, 256, 0, stream>>>(features, IDX, CNT, FNORM);
  k_foldT_all   <<<dim3(512, nf), 256, 0, stream>>>(fa);
  k_foldBias_all<<<dim3(64,  nb), 256, 0, stream>>>(ba);
  k_gemm256p8<true,2><<<1024, 512, 0, stream>>>(FNORM, WDT, BD, FHAT, 65536, 1024, 1024, CNT);
  k_rownorm_bf16<<<65536, 256, 0, stream>>>(FHAT, FHAT, CNT);
  k_init_x      <<<2048,  256, 0, stream>>>(latents, X);

  // ---- KV projections: back-to-back for L3 reuse of FHAT (bigws) ----
  auto launch_kv = [&](int i){
    k_gemm256p8<true,3><<<2048, 512, 0, stream>>>(FHAT, WKVT6 + i*SZW, BKV6 + i*2048,
                                                  kvslice(i), 65536, 2048, 1024, CNT);
  };
  if (bigws) for (int i = 0; i < 6; ++i) launch_kv(i);

  for (int i = 0; i < 6; ++i){
    if (!bigws) launch_kv(i);
    k_rownorm_f32<<<2048, 256, 0, stream>>>(X, XHAT);
    k_gemm<0,false,false,0><<<dim3(8,16),  256, 0, stream>>>(XHAT, WQT6 + i*(SZW/2), BQ6 + i*1024,
                                                             QP, 2048, 1024, 1024, nullptr);
    k_attn<<<512, 256, 0, stream>>>(QP, kvslice(i), CNT, OUTB);
    k_rownorm_bf16<<<2048, 256, 0, stream>>>(OUTB, OUTH, nullptr);
    k_gemm<1,false,false,0><<<dim3(16,16), 256, 0, stream>>>(OUTH, W1T6 + i*SZW, B16 + i*2048,
                                                             H1, 2048, 2048, 1024, nullptr);
    k_gemm<2,false,false,0><<<dim3(8,16),  256, 0, stream>>>(H1, W2T6 + i*SZW, nullptr,
                                                             X, 2048, 1024, 2048, nullptr);
  }
  k_final_ln<<<2048, 256, 0, stream>>>(X, nout_g, nout_b, (float*)d_out);
}

// Round 7
// 2454.396 us; speedup vs baseline: 1.3503x; 1.0106x over previous
//
#include <hip/hip_runtime.h>
#include <stdint.h>

// ---------------------------------------------------------------------------
// PerceiverResampler on MI355X (gfx950)
// B=32, F=2048, DIM=1024, INNER=1024, H=16, DH=64, Q=64, DEPTH=6, MULT=2
//
// Round 7: (1) all 6 KV projections merged into ONE N=12288 GEMM (A read
// once, 48-way A-panel reuse, one dispatch) with non-pow2 XCD remap;
// (2) norm kernels rewritten wave-per-row (shfl-only, no barriers).
// ---------------------------------------------------------------------------

#define DEV static __device__ __forceinline__

typedef __attribute__((ext_vector_type(8))) short short8;
typedef __attribute__((ext_vector_type(4))) float f32x4;
typedef __attribute__((ext_vector_type(4))) unsigned short ushort4v;
typedef unsigned short ushort_t;

DEV float bf2f(ushort_t u){ union{uint32_t i; float f;} x; x.i = ((uint32_t)u)<<16; return x.f; }
DEV ushort_t f2bf(float f){
  union{float f; uint32_t i;} x; x.f = f;
  uint32_t r = x.i + 0x7fffu + ((x.i>>16)&1u);  // RNE
  return (ushort_t)(r>>16);
}

#define GLOAD16(gp, lp) __builtin_amdgcn_global_load_lds( \
    (const __attribute__((address_space(1))) uint32_t*)(gp), \
    (__attribute__((address_space(3))) uint32_t*)(lp), 16, 0, 0)

#define VMCNT(n) asm volatile("s_waitcnt vmcnt(" #n ")" ::: "memory")
#define CFENCE   asm volatile("" ::: "memory")
#define MFMA16(a,b,c) __builtin_amdgcn_mfma_f32_16x16x32_bf16(a,b,c,0,0,0)

// XCD-locality remap (runtime-constant NXB, non-pow2 ok): all NXB N-blocks
// of one M-row land on the same XCD; requires total % (8*NXB) == 0.
template<int NXB>
DEV void xcd_remapN(int g, int total, int& x, int& y){
  int xcd = g & 7;
  int k = g >> 3;
  int rows_per_xcd = (total / NXB) >> 3;
  y = xcd * rows_per_xcd + (k / NXB);
  x = k % NXB;
}

// ---------------- wave reduce (sum of two values over 64 lanes) ------------
DEV void wreduce2(float& a, float& b){
  #pragma unroll
  for (int d = 32; d; d >>= 1){ a += __shfl_xor(a, d); b += __shfl_xor(b, d); }
}

// ---------------- mask compaction ------------------------------------------
__global__ __launch_bounds__(256) void k_compact(const int* __restrict__ mask,
                                                 int* __restrict__ idx, int* __restrict__ cnt){
  int b = blockIdx.x, t = threadIdx.x;
  const int* mb = mask + b*2048;
  int keep[8]; int c = 0;
  #pragma unroll
  for (int u = 0; u < 8; ++u){ keep[u] = (mb[t*8+u] != 0); c += keep[u]; }
  __shared__ int s[256];
  s[t] = c; __syncthreads();
  for (int off = 1; off < 256; off <<= 1){
    int v = (t >= off) ? s[t-off] : 0;
    __syncthreads();
    s[t] += v;
    __syncthreads();
  }
  int pos = s[t] - c;
  #pragma unroll
  for (int u = 0; u < 8; ++u) if (keep[u]) idx[b*2048 + pos++] = t*8 + u;
  if (t == 255) cnt[b] = s[255];
}

// ---------------- gather + rownorm features -> bf16 (wave-per-row) ---------
__global__ __launch_bounds__(256) void k_gather_norm(const float* __restrict__ feat,
        const int* __restrict__ idx, const int* __restrict__ cnt, ushort_t* __restrict__ outp){
  int w = threadIdx.x >> 6, l = threadIdx.x & 63;
  int row = blockIdx.x*4 + w;                 // 16384 blocks x 4 rows
  int b = row >> 11, j = row & 2047;
  if (j >= cnt[b]) return;
  int src = idx[b*2048 + j];
  const float* rp = feat + ((size_t)(b*2048 + src))*1024;
  float4 v[4]; float s = 0.f, q = 0.f;
  #pragma unroll
  for (int i = 0; i < 4; ++i){
    v[i] = *(const float4*)(rp + i*256 + l*4);
    s += v[i].x+v[i].y+v[i].z+v[i].w;
    q += v[i].x*v[i].x+v[i].y*v[i].y+v[i].z*v[i].z+v[i].w*v[i].w;
  }
  wreduce2(s, q);
  float mean = s * (1.f/1024.f);
  float rstd = rsqrtf(q*(1.f/1024.f) - mean*mean + 1e-5f);
  ushort_t* op = outp + (size_t)row*1024;
  #pragma unroll
  for (int i = 0; i < 4; ++i){
    ushort4v o;
    o.x = f2bf((v[i].x-mean)*rstd); o.y = f2bf((v[i].y-mean)*rstd);
    o.z = f2bf((v[i].z-mean)*rstd); o.w = f2bf((v[i].w-mean)*rstd);
    *(ushort4v*)(op + i*256 + l*4) = o;
  }
}

// ---------------- rownorm bf16 -> bf16 (wave-per-row, optional skip) -------
__global__ __launch_bounds__(256) void k_rownorm_bf16(const ushort_t* __restrict__ in,
        ushort_t* __restrict__ outp, const int* __restrict__ cnt){
  int w = threadIdx.x >> 6, l = threadIdx.x & 63;
  int row = blockIdx.x*4 + w;
  if (cnt){ int b = row >> 11; if ((row & 2047) >= cnt[b]) return; }
  const ushort_t* rp = in + (size_t)row*1024;
  float f[4][4]; float s = 0.f, q = 0.f;
  #pragma unroll
  for (int i = 0; i < 4; ++i){
    ushort4v u = *(const ushort4v*)(rp + i*256 + l*4);
    f[i][0] = bf2f(u.x); f[i][1] = bf2f(u.y); f[i][2] = bf2f(u.z); f[i][3] = bf2f(u.w);
    #pragma unroll
    for (int jj = 0; jj < 4; ++jj){ s += f[i][jj]; q += f[i][jj]*f[i][jj]; }
  }
  wreduce2(s, q);
  float mean = s * (1.f/1024.f);
  float rstd = rsqrtf(q*(1.f/1024.f) - mean*mean + 1e-5f);
  ushort_t* op = outp + (size_t)row*1024;
  #pragma unroll
  for (int i = 0; i < 4; ++i){
    ushort4v o;
    o.x = f2bf((f[i][0]-mean)*rstd); o.y = f2bf((f[i][1]-mean)*rstd);
    o.z = f2bf((f[i][2]-mean)*rstd); o.w = f2bf((f[i][3]-mean)*rstd);
    *(ushort4v*)(op + i*256 + l*4) = o;
  }
}

// ---------------- rownorm f32 -> bf16 (wave-per-row) -----------------------
__global__ __launch_bounds__(256) void k_rownorm_f32(const float* __restrict__ in,
                                                     ushort_t* __restrict__ outp){
  int w = threadIdx.x >> 6, l = threadIdx.x & 63;
  int row = blockIdx.x*4 + w;
  const float* rp = in + (size_t)row*1024;
  float4 v[4]; float s = 0.f, q = 0.f;
  #pragma unroll
  for (int i = 0; i < 4; ++i){
    v[i] = *(const float4*)(rp + i*256 + l*4);
    s += v[i].x+v[i].y+v[i].z+v[i].w;
    q += v[i].x*v[i].x+v[i].y*v[i].y+v[i].z*v[i].z+v[i].w*v[i].w;
  }
  wreduce2(s, q);
  float mean = s * (1.f/1024.f);
  float rstd = rsqrtf(q*(1.f/1024.f) - mean*mean + 1e-5f);
  ushort_t* op = outp + (size_t)row*1024;
  #pragma unroll
  for (int i = 0; i < 4; ++i){
    ushort4v o;
    o.x = f2bf((v[i].x-mean)*rstd); o.y = f2bf((v[i].y-mean)*rstd);
    o.z = f2bf((v[i].z-mean)*rstd); o.w = f2bf((v[i].w-mean)*rstd);
    *(ushort4v*)(op + i*256 + l*4) = o;
  }
}

// ---------------- final layernorm (affine) f32 -> f32 (wave-per-row) -------
__global__ __launch_bounds__(256) void k_final_ln(const float* __restrict__ x,
        const float* __restrict__ g, const float* __restrict__ bb, float* __restrict__ outp){
  int w = threadIdx.x >> 6, l = threadIdx.x & 63;
  int row = blockIdx.x*4 + w;
  const float* rp = x + (size_t)row*1024;
  float4 v[4]; float s = 0.f, q = 0.f;
  #pragma unroll
  for (int i = 0; i < 4; ++i){
    v[i] = *(const float4*)(rp + i*256 + l*4);
    s += v[i].x+v[i].y+v[i].z+v[i].w;
    q += v[i].x*v[i].x+v[i].y*v[i].y+v[i].z*v[i].z+v[i].w*v[i].w;
  }
  wreduce2(s, q);
  float mean = s * (1.f/1024.f);
  float rstd = rsqrtf(q*(1.f/1024.f) - mean*mean + 1e-5f);
  float* op = outp + (size_t)row*1024;
  #pragma unroll
  for (int i = 0; i < 4; ++i){
    float4 gg = *(const float4*)(g + i*256 + l*4);
    float4 bv = *(const float4*)(bb + i*256 + l*4);
    float4 o;
    o.x = (v[i].x-mean)*rstd*gg.x + bv.x; o.y = (v[i].y-mean)*rstd*gg.y + bv.y;
    o.z = (v[i].z-mean)*rstd*gg.z + bv.z; o.w = (v[i].w-mean)*rstd*gg.w + bv.w;
    *(float4*)(op + i*256 + l*4) = o;
  }
}

// ---------------- x init: broadcast latents --------------------------------
__global__ __launch_bounds__(256) void k_init_x(const float* __restrict__ lat, float* __restrict__ x){
  int v = blockIdx.x*256 + threadIdx.x;
  int row = v >> 8, cv = v & 255;
  ((float4*)x)[v] = ((const float4*)lat)[(row & 63)*256 + cv];
}

// ---------------- batched weight fold + transpose --------------------------
DEV void foldT_body(const float* __restrict__ W, const float* __restrict__ g,
                    float scale, ushort_t* __restrict__ Wt, int K, int N,
                    int n0, int k0){
  __shared__ float Ts[64][65];
  int t = threadIdx.x;
  #pragma unroll
  for (int i = 0; i < 4; ++i){
    int flat = i*1024 + t*4; int r = flat >> 6, c = flat & 63;
    float4 v = *(const float4*)(W + (size_t)(k0+r)*N + n0 + c);
    float gg = (g ? g[k0+r] : 1.f) * scale;
    Ts[r][c] = v.x*gg; Ts[r][c+1] = v.y*gg; Ts[r][c+2] = v.z*gg; Ts[r][c+3] = v.w*gg;
  }
  __syncthreads();
  #pragma unroll
  for (int i = 0; i < 4; ++i){
    int flat = i*1024 + t*4; int rn = flat >> 6, ck = flat & 63;
    ushort4v o;
    o.x = f2bf(Ts[ck][rn]);   o.y = f2bf(Ts[ck+1][rn]);
    o.z = f2bf(Ts[ck+2][rn]); o.w = f2bf(Ts[ck+3][rn]);
    *(ushort4v*)(Wt + (size_t)(n0+rn)*K + k0 + ck) = o;
  }
}

struct FDesc { const float* W; const float* g; ushort_t* dst; float scale; int K; int N; };
#define MAXFD 32
struct FoldTArgs { int cnt; FDesc d[MAXFD]; };

__global__ __launch_bounds__(256) void k_foldT_all(FoldTArgs a){
  const FDesc d = a.d[blockIdx.y];
  int nxb = d.N >> 6;
  int n0 = (blockIdx.x % nxb) * 64;
  int k0 = (blockIdx.x / nxb) * 64;
  if (k0 >= d.K) return;
  foldT_body(d.W, d.g, d.scale, d.dst, d.K, d.N, n0, k0);
}

// ---------------- batched bias fold ----------------------------------------
DEV void foldBias_body(const float* __restrict__ W, const float* __restrict__ bvec,
                       float scale, float* __restrict__ bias, int K, int N, int o0){
  int t = threadIdx.x;
  int ol = t & 31, kc = t >> 5;
  int o = o0 + ol;
  int chunk = K >> 3;
  int c0 = kc*chunk, c1 = c0 + chunk;
  float s0 = 0, s1 = 0, s2 = 0, s3 = 0;
  for (int c = c0; c < c1; c += 4){
    s0 += bvec[c+0]*W[(size_t)(c+0)*N + o];
    s1 += bvec[c+1]*W[(size_t)(c+1)*N + o];
    s2 += bvec[c+2]*W[(size_t)(c+2)*N + o];
    s3 += bvec[c+3]*W[(size_t)(c+3)*N + o];
  }
  __shared__ float red[8][32];
  red[kc][ol] = (s0+s1)+(s2+s3);
  __syncthreads();
  if (kc == 0){
    float tot = 0;
    #pragma unroll
    for (int jj = 0; jj < 8; ++jj) tot += red[jj][ol];
    bias[o] = tot * scale;
  }
}

struct BDesc { const float* W; const float* b; float* dst; float scale; int K; int N; };
#define MAXBD 25
struct BiasArgs { int cnt; BDesc d[MAXBD]; };

__global__ __launch_bounds__(256) void k_foldBias_all(BiasArgs a){
  const BDesc d = a.d[blockIdx.y];
  int o0 = blockIdx.x * 32;
  if (o0 >= d.N) return;
  foldBias_body(d.W, d.b, d.scale, d.dst, d.K, d.N, o0);
}

// ---------------- 128x128 2-phase GEMM -------------------------------------
// OUTMODE: 0 = bf16 store, 1 = bf16 relu store, 2 = f32 accumulate (C += v)
template<int OUTMODE, bool SKIP>
__global__ __launch_bounds__(256, 4) void k_gemm(const ushort_t* __restrict__ A,
        const ushort_t* __restrict__ Bt, const float* __restrict__ bias,
        void* __restrict__ Cp, int M, int N, int K, const int* __restrict__ cnt){
  const int n0 = blockIdx.x * 128;
  const int m0 = blockIdx.y * 128;
  if (SKIP){ int b = m0 >> 11; if ((m0 & 2047) >= cnt[b]) return; }
  __shared__ ushort_t sA[2][128*32];
  __shared__ ushort_t sB[2][128*32];
  const int tid = threadIdx.x;
  const int wave = tid >> 6, lane = tid & 63;
  const int lo = lane & 15, hi = lane >> 4;
  const int wr = wave >> 1, wc = wave & 1;

  auto stage = [&](int buf, int k0){
    #pragma unroll
    for (int p = 0; p < 2; ++p){
      int r = p*64 + wave*16 + (lane >> 2);
      int c = lane & 3;
      {
        const ushort_t* gp = A + (size_t)(m0 + r)*K + k0 + c*8;
        char* lp = (char*)(&sA[buf][0]) + p*4096 + wave*1024;
        GLOAD16(gp, lp);
      }
      {
        const ushort_t* gp = Bt + (size_t)(n0 + r)*K + k0 + c*8;
        char* lp = (char*)(&sB[buf][0]) + p*4096 + wave*1024;
        GLOAD16(gp, lp);
      }
    }
  };

  f32x4 acc[4][4] = {};
  stage(0, 0);
  const int nk = K >> 5;
  for (int ks = 0; ks < nk; ++ks){
    __syncthreads();
    if (ks + 1 < nk) stage((ks+1)&1, (ks+1) << 5);
    const int buf = ks & 1;
    short8 af[4], bfr[4];
    #pragma unroll
    for (int mi = 0; mi < 4; ++mi)
      af[mi] = *(const short8*)(&sA[buf][(wr*64 + mi*16 + lo)*32 + hi*8]);
    #pragma unroll
    for (int ni = 0; ni < 4; ++ni)
      bfr[ni] = *(const short8*)(&sB[buf][(wc*64 + ni*16 + lo)*32 + hi*8]);
    #pragma unroll
    for (int mi = 0; mi < 4; ++mi)
      #pragma unroll
      for (int ni = 0; ni < 4; ++ni)
        acc[mi][ni] = MFMA16(af[mi], bfr[ni], acc[mi][ni]);
  }
  #pragma unroll
  for (int ni = 0; ni < 4; ++ni){
    int col = n0 + wc*64 + ni*16 + lo;
    float bv = bias ? bias[col] : 0.f;
    #pragma unroll
    for (int mi = 0; mi < 4; ++mi){
      int rbase = m0 + wr*64 + mi*16 + hi*4;
      #pragma unroll
      for (int rr = 0; rr < 4; ++rr){
        float v = acc[mi][ni][rr] + bv;
        size_t off = (size_t)(rbase + rr)*N + col;
        if (OUTMODE == 0)      ((ushort_t*)Cp)[off] = f2bf(v);
        else if (OUTMODE == 1) ((ushort_t*)Cp)[off] = f2bf(fmaxf(v, 0.f));
        else                   ((float*)Cp)[off] += v;
      }
    }
  }
}

// ======= 256x256 8-phase GEMM (8 waves, 512 threads) ======
template<bool SKIP, int NXB>
__global__ __launch_bounds__(512, 2) void k_gemm256p8(const ushort_t* __restrict__ A,
        const ushort_t* __restrict__ Bt, const float* __restrict__ bias,
        ushort_t* __restrict__ Cp, int M, int N, int K, const int* __restrict__ cnt){
  int bx, by;
  xcd_remapN<NXB>(blockIdx.x, gridDim.x, bx, by);
  const int n0 = bx * 256;
  const int m0 = by * 256;
  if (SKIP){ int b = m0 >> 11; if ((m0 & 2047) >= cnt[b]) return; }
  __shared__ __align__(16) ushort_t sA[2][256*64];
  __shared__ __align__(16) ushort_t sB[2][256*64];
  const int tid = threadIdx.x;
  const int wave = tid >> 6, lane = tid & 63;
  const int lo = lane & 15, hi = lane >> 4;
  const int wm = wave >> 2, wn = wave & 3;
  const int srow = lane >> 3;
  const int schunk = (lane & 7) ^ srow;
  auto stageHalf = [&](ushort_t* dst, const ushort_t* __restrict__ G, int grow0,
                       int half, int k0){
    #pragma unroll
    for (int p = 0; p < 2; ++p){
      int rbase = half*128 + p*64 + wave*8;
      const ushort_t* gp = G + (size_t)(grow0 + rbase + srow)*K + k0 + schunk*8;
      char* lp = (char*)dst + (size_t)rbase*128;
      GLOAD16(gp, lp);
    }
  };
  auto ldsA = [&](int buf, int row, int kk)->short8{
    int ch = ((kk<<2) + hi) ^ (row & 7);
    return *(const short8*)((const char*)sA + (size_t)buf*32768 + (size_t)row*128 + ch*16);
  };
  auto ldsB = [&](int buf, int row, int kk)->short8{
    int ch = ((kk<<2) + hi) ^ (row & 7);
    return *(const short8*)((const char*)sB + (size_t)buf*32768 + (size_t)row*128 + ch*16);
  };
  f32x4 acc[8][4] = {};

  short8 af[4][2], bg[2][2];
#define LOADA(BUF, AH) \
    _Pragma("unroll") for (int mi_ = 0; mi_ < 4; ++mi_) \
      _Pragma("unroll") for (int kk_ = 0; kk_ < 2; ++kk_) \
        af[mi_][kk_] = ldsA(BUF, (AH)*128 + wm*64 + mi_*16 + lo, kk_);
#define LOADB(BUF, BH) \
    _Pragma("unroll") for (int nj_ = 0; nj_ < 2; ++nj_) \
      _Pragma("unroll") for (int kk_ = 0; kk_ < 2; ++kk_) \
        bg[nj_][kk_] = ldsB(BUF, (BH)*128 + wn*32 + nj_*16 + lo, kk_);
#define MMQ(AH, BH) \
    __builtin_amdgcn_s_barrier(); CFENCE; \
    __builtin_amdgcn_s_setprio(1); \
    _Pragma("unroll") for (int mi_ = 0; mi_ < 4; ++mi_) \
      _Pragma("unroll") for (int nj_ = 0; nj_ < 2; ++nj_) \
        _Pragma("unroll") for (int kk_ = 0; kk_ < 2; ++kk_) \
          acc[(AH)*4+mi_][(BH)*2+nj_] = \
            MFMA16(af[mi_][kk_], bg[nj_][kk_], acc[(AH)*4+mi_][(BH)*2+nj_]); \
    __builtin_amdgcn_s_setprio(0); CFENCE; \
    __builtin_amdgcn_s_barrier(); CFENCE;

  stageHalf(&sA[0][0], A,  m0, 0, 0);
  stageHalf(&sB[0][0], Bt, n0, 0, 0);
  stageHalf(&sA[0][0], A,  m0, 1, 0);
  stageHalf(&sB[0][0], Bt, n0, 1, 0);
  stageHalf(&sA[1][0], A,  m0, 0, 64);
  stageHalf(&sB[1][0], Bt, n0, 1, 64);
  VMCNT(4);
  __builtin_amdgcn_s_barrier();
  CFENCE;

  const int NI = K >> 7;
  for (int i = 0; i < NI; ++i){
    const int kt = i << 7;
    const bool lastI = (i == NI-1);
    LOADA(0,0) LOADB(0,0)
    stageHalf(&sA[1][0], A,  m0, 1, kt+64);
    MMQ(0,0)
    LOADB(0,1)
    stageHalf(&sB[1][0], Bt, n0, 0, kt+64);
    MMQ(0,1)
    LOADA(0,1)
    if (!lastI) stageHalf(&sA[0][0], A,  m0, 0, kt+128);
    MMQ(1,1)
    LOADB(0,0)
    if (!lastI) stageHalf(&sB[0][0], Bt, n0, 1, kt+128);
    if (lastI){ VMCNT(0); } else { VMCNT(4); }
    MMQ(1,0)
    LOADA(1,0) LOADB(1,0)
    if (!lastI) stageHalf(&sA[0][0], A,  m0, 1, kt+128);
    MMQ(0,0)
    LOADB(1,1)
    if (!lastI) stageHalf(&sB[0][0], Bt, n0, 0, kt+128);
    MMQ(0,1)
    LOADA(1,1)
    if (!lastI) stageHalf(&sA[1][0], A,  m0, 0, kt+192);
    MMQ(1,1)
    LOADB(1,0)
    if (!lastI){ stageHalf(&sB[1][0], Bt, n0, 1, kt+192); VMCNT(4); }
    MMQ(1,0)
  }
#undef LOADA
#undef LOADB
#undef MMQ

  #pragma unroll
  for (int b2 = 0; b2 < 2; ++b2)
    #pragma unroll
    for (int nj = 0; nj < 2; ++nj){
      int col = n0 + b2*128 + wn*32 + nj*16 + lo;
      float bv = bias ? bias[col] : 0.f;
      #pragma unroll
      for (int a2 = 0; a2 < 2; ++a2)
        #pragma unroll
        for (int mi4 = 0; mi4 < 4; ++mi4){
          int rbase = m0 + a2*128 + wm*64 + mi4*16 + hi*4;
          #pragma unroll
          for (int rr = 0; rr < 4; ++rr){
            float v = acc[a2*4+mi4][b2*2+nj][rr] + bv;
            Cp[(size_t)(rbase + rr)*N + col] = f2bf(v);
          }
        }
    }
}

// ---------------- flash attention (pipelined): one block per (b,h) ---------
// kvb points at this depth's K columns; V at +1024. Row stride = kstride.
__global__ __launch_bounds__(256) void k_attn(const ushort_t* __restrict__ qb,
        const ushort_t* __restrict__ kvb, int kstride, const int* __restrict__ cnt,
        ushort_t* __restrict__ outb){
  const int bh = blockIdx.x;
  const int b = bh >> 4, h = bh & 15;
  const int t = threadIdx.x;
  const int wave = t >> 6, lane = t & 63, lo = lane & 15, hi = lane >> 4;
  __shared__ ushort_t Qs[64*64];        // [q][d], chunk-swizzled
  __shared__ ushort_t Ks[2][64*64];     // [j][d], chunk-swizzled, dbuf
  __shared__ ushort_t Vt[2][64][72];    // [d][j], padded, dbuf
  __shared__ ushort_t Ps[4][16][72];    // per-wave P stripe

  const int count = cnt[b];

  #pragma unroll
  for (int p = 0; p < 2; ++p){
    int r = p*32 + wave*8 + (lane >> 3);
    int c = (lane & 7) ^ (r & 7);
    const ushort_t* gp = qb + (size_t)(b*64 + r)*1024 + h*64 + c*8;
    char* lp = (char*)Qs + p*4096 + wave*1024;
    GLOAD16(gp, lp);
  }

  auto stageK = [&](int buf, int tt){
    #pragma unroll
    for (int p = 0; p < 2; ++p){
      int r = p*32 + wave*8 + (lane >> 3);
      int c = (lane & 7) ^ (r & 7);
      const ushort_t* gp = kvb + (size_t)(b*2048 + tt*64 + r)*kstride + h*64 + c*8;
      char* lp = (char*)(&Ks[buf][0]) + p*4096 + wave*1024;
      GLOAD16(gp, lp);
    }
  };
  const int vjj = (t & 31)*2, vc = (t >> 5)*8;
  ushort4v va0, va1, vb0, vb1;
  auto issueV = [&](int tt){
    const ushort_t* g0 = kvb + (size_t)(b*2048 + tt*64 + vjj)*kstride + 1024 + h*64 + vc;
    va0 = *(const ushort4v*)(g0);
    va1 = *(const ushort4v*)(g0 + 4);
    vb0 = *(const ushort4v*)(g0 + kstride);
    vb1 = *(const ushort4v*)(g0 + kstride + 4);
  };
  auto writeV = [&](int buf, int tt){
    bool va  = (tt*64 + vjj)     < count;
    bool vb2 = (tt*64 + vjj + 1) < count;
    #pragma unroll
    for (int u = 0; u < 8; ++u){
      ushort_t ea = (u < 4) ? ((ushort_t*)&va0)[u] : ((ushort_t*)&va1)[u-4];
      ushort_t eb = (u < 4) ? ((ushort_t*)&vb0)[u] : ((ushort_t*)&vb1)[u-4];
      uint32_t word = (va ? (uint32_t)ea : 0u) | ((vb2 ? (uint32_t)eb : 0u) << 16);
      *(uint32_t*)(&Vt[buf][vc+u][vjj]) = word;
    }
  };

  f32x4 oacc[4] = {};
  float m[4], l[4];
  #pragma unroll
  for (int rr = 0; rr < 4; ++rr){ m[rr] = -__builtin_inff(); l[rr] = 0.f; }

  const int ntiles = (count + 63) >> 6;
  if (ntiles > 0){ stageK(0, 0); issueV(0); }

  for (int tt = 0; tt < ntiles; ++tt){
    const int buf = tt & 1;
    writeV(buf, tt);                          // implicit vmcnt wait drains K(tt) too
    if (tt + 1 < ntiles){ stageK(buf^1, tt+1); issueV(tt+1); }
    asm volatile("s_waitcnt lgkmcnt(0)" ::: "memory");
    __builtin_amdgcn_s_barrier();
    CFENCE;

    // S = Q @ K^T
    f32x4 s[4] = {};
    #pragma unroll
    for (int kk = 0; kk < 2; ++kk){
      int rA = wave*16 + lo;
      short8 aq = *(const short8*)(&Qs[rA*64 + (((kk*4 + hi) ^ (rA & 7))*8)]);
      #pragma unroll
      for (int ni = 0; ni < 4; ++ni){
        int rB = ni*16 + lo;
        short8 bk = *(const short8*)(&Ks[buf][rB*64 + (((kk*4 + hi) ^ (rB & 7))*8)]);
        s[ni] = MFMA16(aq, bk, s[ni]);
      }
    }
    #pragma unroll
    for (int ni = 0; ni < 4; ++ni){
      if (tt*64 + ni*16 + lo >= count){
        s[ni][0] = s[ni][1] = s[ni][2] = s[ni][3] = -__builtin_inff();
      }
    }
    // online softmax
    float p[4][4];
    #pragma unroll
    for (int rr = 0; rr < 4; ++rr){
      float mx = fmaxf(fmaxf(s[0][rr], s[1][rr]), fmaxf(s[2][rr], s[3][rr]));
      #pragma unroll
      for (int d = 1; d < 16; d <<= 1) mx = fmaxf(mx, __shfl_xor(mx, d));
      float mnew = fmaxf(m[rr], mx);
      float sc = __expf(m[rr] - mnew);
      float rsum = 0.f;
      #pragma unroll
      for (int ni = 0; ni < 4; ++ni){
        float pv = __expf(s[ni][rr] - mnew);
        p[ni][rr] = pv;
        rsum += pv;
      }
      #pragma unroll
      for (int d = 1; d < 16; d <<= 1) rsum += __shfl_xor(rsum, d);
      l[rr] = l[rr]*sc + rsum;
      m[rr] = mnew;
      #pragma unroll
      for (int ni = 0; ni < 4; ++ni) oacc[ni][rr] *= sc;
    }
    // P -> LDS (C-layout), re-read as A-layout (wave-private stripe)
    #pragma unroll
    for (int ni = 0; ni < 4; ++ni)
      #pragma unroll
      for (int rr = 0; rr < 4; ++rr)
        Ps[wave][hi*4+rr][ni*16+lo] = f2bf(p[ni][rr]);
    asm volatile("s_waitcnt lgkmcnt(0)" ::: "memory");
    #pragma unroll
    for (int kk = 0; kk < 2; ++kk){
      short8 pa = *(const short8*)(&Ps[wave][lo][kk*32 + hi*8]);
      #pragma unroll
      for (int ni = 0; ni < 4; ++ni){
        short8 bv = *(const short8*)(&Vt[buf][ni*16 + lo][kk*32 + hi*8]);
        oacc[ni] = MFMA16(pa, bv, oacc[ni]);
      }
    }
    CFENCE;
    __builtin_amdgcn_s_barrier();   // all waves done reading Ks[buf]/Vt[buf]
    CFENCE;
  }
  #pragma unroll
  for (int rr = 0; rr < 4; ++rr){
    float inv = (l[rr] > 0.f) ? 1.f/l[rr] : 0.f;
    #pragma unroll
    for (int ni = 0; ni < 4; ++ni){
      size_t off = (size_t)(b*64 + wave*16 + hi*4 + rr)*1024 + h*64 + ni*16 + lo;
      outb[off] = f2bf(oacc[ni][rr] * inv);
    }
  }
}

// ---------------------------------------------------------------------------
extern "C" void kernel_launch(void* const* d_in, const int* in_sizes, int n_in,
                              void* d_out, int out_size, void* d_ws, size_t ws_size,
                              hipStream_t stream){
  const float* features = (const float*)d_in[0];
  const int*   mask     = (const int*)  d_in[1];
  const float* latents  = (const float*)d_in[2];
  const float* W_down   = (const float*)d_in[3];
  const float* nin_g    = (const float*)d_in[4];
  const float* nin_b    = (const float*)d_in[5];
  const float* lf_g     = (const float*)d_in[6];
  const float* lf_b     = (const float*)d_in[7];
  const float* ll_g     = (const float*)d_in[8];
  const float* ll_b     = (const float*)d_in[9];
  const float* Wq       = (const float*)d_in[10];
  const float* Wk       = (const float*)d_in[11];
  const float* Wv       = (const float*)d_in[12];
  const float* ffln_g   = (const float*)d_in[13];
  const float* ffln_b   = (const float*)d_in[14];
  const float* ff_w1    = (const float*)d_in[15];
  const float* ff_w2    = (const float*)d_in[16];
  const float* nout_g   = (const float*)d_in[17];
  const float* nout_b   = (const float*)d_in[18];

  char* ws = (char*)d_ws;
  size_t off = 0;
  auto alloc = [&](size_t bytes)->char*{
    char* p = ws + off;
    off += (bytes + 255) & ~(size_t)255;
    return p;
  };
  const size_t SZW    = (size_t)1024*1024*2;      // 2 MB (1024x1024 bf16)
  const size_t SZKV1  = (size_t)65536*2048*2;     // 256 MB  (per-depth)
  const size_t SZKV12 = (size_t)65536*12288*2;    // 1.61 GB (merged 6-depth)

  ushort_t* FHAT  = (ushort_t*)alloc((size_t)65536*1024*2);   // 128 MB
  ushort_t* WDT   = (ushort_t*)alloc(SZW);
  ushort_t* WQT6  = (ushort_t*)alloc(SZW*6);
  ushort_t* WKVT6 = (ushort_t*)alloc(SZW*2*6);    // contiguous [12288][1024]
  ushort_t* W1T6  = (ushort_t*)alloc(SZW*2*6);
  ushort_t* W2T6  = (ushort_t*)alloc(SZW*2*6);
  float* BD   = (float*)alloc(1024*4);
  float* BQ6  = (float*)alloc(1024*4*6);
  float* BKV6 = (float*)alloc(2048*4*6);          // contiguous [12288]
  float* B16  = (float*)alloc(2048*4*6);
  float*    X    = (float*)   alloc((size_t)2048*1024*4);
  ushort_t* XHAT = (ushort_t*)alloc((size_t)2048*1024*2);
  ushort_t* QP   = (ushort_t*)alloc((size_t)2048*1024*2);
  ushort_t* OUTB = (ushort_t*)alloc((size_t)2048*1024*2);
  ushort_t* OUTH = (ushort_t*)alloc((size_t)2048*1024*2);
  ushort_t* H1   = (ushort_t*)alloc((size_t)2048*2048*2);
  int* CNT = (int*)alloc(32*4);
  int* IDX = (int*)alloc((size_t)65536*4);
  char* kvbase = ws + off;
  size_t avail = (ws_size > off) ? ws_size - off : 0;
  const bool merged = avail >= SZKV12;
  ushort_t* KVBUF = (ushort_t*)kvbase;
  ushort_t* FNORM = KVBUF;   // transient alias (dead before KV GEMM writes)
  (void)in_sizes; (void)n_in; (void)out_size;

  const float scale = 0.125f;  // DH^-0.5

  // ---- batched weight folds (all depth-independent) ----
  FoldTArgs fa; int nf = 0;
  auto addF = [&](const float* W, const float* g, float sc, ushort_t* dst, int K, int N){
    fa.d[nf++] = FDesc{W, g, dst, sc, K, N};
  };
  addF(W_down, nin_g, 1.f, WDT, 1024, 1024);
  for (int i = 0; i < 6; ++i){
    const float* Wqi = Wq + (size_t)i*1024*1024;
    const float* Wki = Wk + (size_t)i*1024*1024;
    const float* Wvi = Wv + (size_t)i*1024*1024;
    const float* W1i = ff_w1 + (size_t)i*1024*2048;
    const float* W2i = ff_w2 + (size_t)i*2048*1024;
    addF(Wqi, ll_g + i*1024, scale, WQT6  + i*(SZW/2),        1024, 1024);
    addF(Wki, lf_g + i*1024, 1.f,   WKVT6 + i*SZW,            1024, 1024);
    addF(Wvi, lf_g + i*1024, 1.f,   WKVT6 + i*SZW + (SZW/2),  1024, 1024);
    addF(W1i, ffln_g + i*1024, 1.f, W1T6  + i*SZW,            1024, 2048);
    addF(W2i, nullptr, 1.f,         W2T6  + i*SZW,            2048, 1024);
  }
  fa.cnt = nf;

  BiasArgs ba; int nb = 0;
  auto addB = [&](const float* W, const float* b, float sc, float* dst, int K, int N){
    ba.d[nb++] = BDesc{W, b, dst, sc, K, N};
  };
  addB(W_down, nin_b, 1.f, BD, 1024, 1024);
  for (int i = 0; i < 6; ++i){
    const float* Wqi = Wq + (size_t)i*1024*1024;
    const float* Wki = Wk + (size_t)i*1024*1024;
    const float* Wvi = Wv + (size_t)i*1024*1024;
    const float* W1i = ff_w1 + (size_t)i*1024*2048;
    addB(Wqi, ll_b + i*1024, scale, BQ6  + i*1024,        1024, 1024);
    addB(Wki, lf_b + i*1024, 1.f,   BKV6 + i*2048,        1024, 1024);
    addB(Wvi, lf_b + i*1024, 1.f,   BKV6 + i*2048 + 1024, 1024, 1024);
    addB(W1i, ffln_b + i*1024, 1.f, B16  + i*2048,        1024, 2048);
  }
  ba.cnt = nb;

  // ---- setup ----
  k_compact     <<<32,    256, 0, stream>>>(mask, IDX, CNT);
  k_gather_norm <<<16384, 256, 0, stream>>>(features, IDX, CNT, FNORM);
  k_foldT_all   <<<dim3(512, nf), 256, 0, stream>>>(fa);
  k_foldBias_all<<<dim3(64,  nb), 256, 0, stream>>>(ba);
  k_gemm256p8<true,4><<<1024, 512, 0, stream>>>(FNORM, WDT, BD, FHAT, 65536, 1024, 1024, CNT);
  k_rownorm_bf16<<<16384, 256, 0, stream>>>(FHAT, FHAT, CNT);
  k_init_x      <<<2048,  256, 0, stream>>>(latents, X);

  // ---- KV projections ----
  if (merged){
    // one GEMM, N = 6 depths x (K|V) x 1024 = 12288; A read once
    k_gemm256p8<true,48><<<12288, 512, 0, stream>>>(FHAT, WKVT6, BKV6, KVBUF,
                                                    65536, 12288, 1024, CNT);
  }

  for (int i = 0; i < 6; ++i){
    if (!merged)
      k_gemm256p8<true,8><<<2048, 512, 0, stream>>>(FHAT, WKVT6 + i*SZW, BKV6 + i*2048,
                                                    KVBUF, 65536, 2048, 1024, CNT);
    k_rownorm_f32<<<512, 256, 0, stream>>>(X, XHAT);
    k_gemm<0,false><<<dim3(8,16),  256, 0, stream>>>(XHAT, WQT6 + i*(SZW/2), BQ6 + i*1024,
                                                     QP, 2048, 1024, 1024, nullptr);
    if (merged)
      k_attn<<<512, 256, 0, stream>>>(QP, KVBUF + (size_t)i*2048, 12288, CNT, OUTB);
    else
      k_attn<<<512, 256, 0, stream>>>(QP, KVBUF, 2048, CNT, OUTB);
    k_rownorm_bf16<<<512, 256, 0, stream>>>(OUTB, OUTH, nullptr);
    k_gemm<1,false><<<dim3(16,16), 256, 0, stream>>>(OUTH, W1T6 + i*SZW, B16 + i*2048,
                                                     H1, 2048, 2048, 1024, nullptr);
    k_gemm<2,false><<<dim3(8,16),  256, 0, stream>>>(H1, W2T6 + i*SZW, nullptr,
                                                     X, 2048, 1024, 2048, nullptr);
  }
  k_final_ln<<<512, 256, 0, stream>>>(X, nout_g, nout_b, (float*)d_out);
}

// Round 8
// 2021.373 us; speedup vs baseline: 1.6395x; 1.2142x over previous
//
#include <hip/hip_runtime.h>
#include <stdint.h>

// ---------------------------------------------------------------------------
// PerceiverResampler on MI355X (gfx950)
// B=32, F=2048, DIM=1024, INNER=1024, H=16, DH=64, Q=64, DEPTH=6, MULT=2
//
// Round 8: KV projections switched to i8 MFMA (16x16x64, 2x bf16 rate,
// half LDS/staging traffic). A = LN'd fhat quantized per-row (fused into
// rownorm), B = folded weights quantized per-col; i32 accumulate; dequant
// + bias in epilogue. KV output stays bf16 -> attention unchanged.
// ---------------------------------------------------------------------------

#define DEV static __device__ __forceinline__

typedef __attribute__((ext_vector_type(8))) short short8;
typedef __attribute__((ext_vector_type(4))) float f32x4;
typedef __attribute__((ext_vector_type(4))) int int4v;
typedef __attribute__((ext_vector_type(4))) unsigned short ushort4v;
typedef unsigned short ushort_t;

DEV float bf2f(ushort_t u){ union{uint32_t i; float f;} x; x.i = ((uint32_t)u)<<16; return x.f; }
DEV ushort_t f2bf(float f){
  union{float f; uint32_t i;} x; x.f = f;
  uint32_t r = x.i + 0x7fffu + ((x.i>>16)&1u);  // RNE
  return (ushort_t)(r>>16);
}

#define GLOAD16(gp, lp) __builtin_amdgcn_global_load_lds( \
    (const __attribute__((address_space(1))) uint32_t*)(gp), \
    (__attribute__((address_space(3))) uint32_t*)(lp), 16, 0, 0)

#define VMCNT(n) asm volatile("s_waitcnt vmcnt(" #n ")" ::: "memory")
#define CFENCE   asm volatile("" ::: "memory")
#define MFMA16(a,b,c) __builtin_amdgcn_mfma_f32_16x16x32_bf16(a,b,c,0,0,0)
#define MFMAI8(a,b,c) __builtin_amdgcn_mfma_i32_16x16x64_i8(a,b,c,0,0,0)

// XCD-locality remap: all NXB N-blocks of one M-row land on the same XCD.
template<int NXB>
DEV void xcd_remapN(int g, int total, int& x, int& y){
  int xcd = g & 7;
  int k = g >> 3;
  int rows_per_xcd = (total / NXB) >> 3;
  y = xcd * rows_per_xcd + (k / NXB);
  x = k % NXB;
}

DEV void wreduce2(float& a, float& b){
  #pragma unroll
  for (int d = 32; d; d >>= 1){ a += __shfl_xor(a, d); b += __shfl_xor(b, d); }
}

// ---------------- mask compaction ------------------------------------------
__global__ __launch_bounds__(256) void k_compact(const int* __restrict__ mask,
                                                 int* __restrict__ idx, int* __restrict__ cnt){
  int b = blockIdx.x, t = threadIdx.x;
  const int* mb = mask + b*2048;
  int keep[8]; int c = 0;
  #pragma unroll
  for (int u = 0; u < 8; ++u){ keep[u] = (mb[t*8+u] != 0); c += keep[u]; }
  __shared__ int s[256];
  s[t] = c; __syncthreads();
  for (int off = 1; off < 256; off <<= 1){
    int v = (t >= off) ? s[t-off] : 0;
    __syncthreads();
    s[t] += v;
    __syncthreads();
  }
  int pos = s[t] - c;
  #pragma unroll
  for (int u = 0; u < 8; ++u) if (keep[u]) idx[b*2048 + pos++] = t*8 + u;
  if (t == 255) cnt[b] = s[255];
}

// ---------------- gather + rownorm features -> bf16 (wave-per-row) ---------
__global__ __launch_bounds__(256) void k_gather_norm(const float* __restrict__ feat,
        const int* __restrict__ idx, const int* __restrict__ cnt, ushort_t* __restrict__ outp){
  int w = threadIdx.x >> 6, l = threadIdx.x & 63;
  int row = blockIdx.x*4 + w;
  int b = row >> 11, j = row & 2047;
  if (j >= cnt[b]) return;
  int src = idx[b*2048 + j];
  const float* rp = feat + ((size_t)(b*2048 + src))*1024;
  float4 v[4]; float s = 0.f, q = 0.f;
  #pragma unroll
  for (int i = 0; i < 4; ++i){
    v[i] = *(const float4*)(rp + i*256 + l*4);
    s += v[i].x+v[i].y+v[i].z+v[i].w;
    q += v[i].x*v[i].x+v[i].y*v[i].y+v[i].z*v[i].z+v[i].w*v[i].w;
  }
  wreduce2(s, q);
  float mean = s * (1.f/1024.f);
  float rstd = rsqrtf(q*(1.f/1024.f) - mean*mean + 1e-5f);
  ushort_t* op = outp + (size_t)row*1024;
  #pragma unroll
  for (int i = 0; i < 4; ++i){
    ushort4v o;
    o.x = f2bf((v[i].x-mean)*rstd); o.y = f2bf((v[i].y-mean)*rstd);
    o.z = f2bf((v[i].z-mean)*rstd); o.w = f2bf((v[i].w-mean)*rstd);
    *(ushort4v*)(op + i*256 + l*4) = o;
  }
}

// ---------------- rownorm bf16 -> bf16 (wave-per-row) ----------------------
__global__ __launch_bounds__(256) void k_rownorm_bf16(const ushort_t* __restrict__ in,
        ushort_t* __restrict__ outp, const int* __restrict__ cnt){
  int w = threadIdx.x >> 6, l = threadIdx.x & 63;
  int row = blockIdx.x*4 + w;
  if (cnt){ int b = row >> 11; if ((row & 2047) >= cnt[b]) return; }
  const ushort_t* rp = in + (size_t)row*1024;
  float f[4][4]; float s = 0.f, q = 0.f;
  #pragma unroll
  for (int i = 0; i < 4; ++i){
    ushort4v u = *(const ushort4v*)(rp + i*256 + l*4);
    f[i][0] = bf2f(u.x); f[i][1] = bf2f(u.y); f[i][2] = bf2f(u.z); f[i][3] = bf2f(u.w);
    #pragma unroll
    for (int jj = 0; jj < 4; ++jj){ s += f[i][jj]; q += f[i][jj]*f[i][jj]; }
  }
  wreduce2(s, q);
  float mean = s * (1.f/1024.f);
  float rstd = rsqrtf(q*(1.f/1024.f) - mean*mean + 1e-5f);
  ushort_t* op = outp + (size_t)row*1024;
  #pragma unroll
  for (int i = 0; i < 4; ++i){
    ushort4v o;
    o.x = f2bf((f[i][0]-mean)*rstd); o.y = f2bf((f[i][1]-mean)*rstd);
    o.z = f2bf((f[i][2]-mean)*rstd); o.w = f2bf((f[i][3]-mean)*rstd);
    *(ushort4v*)(op + i*256 + l*4) = o;
  }
}

// ---------------- rownorm bf16 -> i8 + per-row scale (wave-per-row) --------
// lane handles 16 contiguous elems; LN then symmetric int8 quantization.
__global__ __launch_bounds__(256) void k_rownorm_i8(const ushort_t* __restrict__ in,
        int8_t* __restrict__ outp, float* __restrict__ sca, const int* __restrict__ cnt){
  int w = threadIdx.x >> 6, l = threadIdx.x & 63;
  int row = blockIdx.x*4 + w;
  int b = row >> 11; if ((row & 2047) >= cnt[b]) return;
  const ushort_t* rp = in + (size_t)row*1024 + l*16;
  float f[16]; float s = 0.f, q = 0.f;
  #pragma unroll
  for (int i = 0; i < 4; ++i){
    ushort4v u = *(const ushort4v*)(rp + i*4);
    f[i*4+0] = bf2f(u.x); f[i*4+1] = bf2f(u.y);
    f[i*4+2] = bf2f(u.z); f[i*4+3] = bf2f(u.w);
  }
  #pragma unroll
  for (int jj = 0; jj < 16; ++jj){ s += f[jj]; q += f[jj]*f[jj]; }
  wreduce2(s, q);
  float mean = s * (1.f/1024.f);
  float rstd = rsqrtf(q*(1.f/1024.f) - mean*mean + 1e-5f);
  float amax = 0.f;
  #pragma unroll
  for (int jj = 0; jj < 16; ++jj) amax = fmaxf(amax, fabsf(f[jj]-mean));
  #pragma unroll
  for (int d = 32; d; d >>= 1) amax = fmaxf(amax, __shfl_xor(amax, d));
  amax *= rstd;
  float inv = (amax > 0.f) ? 127.f/amax : 0.f;
  if (l == 0) sca[row] = amax * (1.f/127.f);
  uint32_t wds[4];
  #pragma unroll
  for (int i = 0; i < 4; ++i){
    uint32_t wd = 0;
    #pragma unroll
    for (int c = 0; c < 4; ++c){
      int qv = (int)rintf((f[i*4+c]-mean)*rstd*inv);
      wd |= ((uint32_t)(uint8_t)(int8_t)qv) << (c*8);
    }
    wds[i] = wd;
  }
  int4v pk; pk[0]=(int)wds[0]; pk[1]=(int)wds[1]; pk[2]=(int)wds[2]; pk[3]=(int)wds[3];
  *(int4v*)(outp + (size_t)row*1024 + l*16) = pk;
}

// ---------------- weight rows bf16 -> i8 + per-row scale -------------------
__global__ __launch_bounds__(256) void k_quantW(const ushort_t* __restrict__ in,
        int8_t* __restrict__ outp, float* __restrict__ sca){
  int w = threadIdx.x >> 6, l = threadIdx.x & 63;
  int row = blockIdx.x*4 + w;
  const ushort_t* rp = in + (size_t)row*1024 + l*16;
  float f[16];
  #pragma unroll
  for (int i = 0; i < 4; ++i){
    ushort4v u = *(const ushort4v*)(rp + i*4);
    f[i*4+0] = bf2f(u.x); f[i*4+1] = bf2f(u.y);
    f[i*4+2] = bf2f(u.z); f[i*4+3] = bf2f(u.w);
  }
  float amax = 0.f;
  #pragma unroll
  for (int jj = 0; jj < 16; ++jj) amax = fmaxf(amax, fabsf(f[jj]));
  #pragma unroll
  for (int d = 32; d; d >>= 1) amax = fmaxf(amax, __shfl_xor(amax, d));
  float inv = (amax > 0.f) ? 127.f/amax : 0.f;
  if (l == 0) sca[row] = amax * (1.f/127.f);
  uint32_t wds[4];
  #pragma unroll
  for (int i = 0; i < 4; ++i){
    uint32_t wd = 0;
    #pragma unroll
    for (int c = 0; c < 4; ++c){
      int qv = (int)rintf(f[i*4+c]*inv);
      wd |= ((uint32_t)(uint8_t)(int8_t)qv) << (c*8);
    }
    wds[i] = wd;
  }
  int4v pk; pk[0]=(int)wds[0]; pk[1]=(int)wds[1]; pk[2]=(int)wds[2]; pk[3]=(int)wds[3];
  *(int4v*)(outp + (size_t)row*1024 + l*16) = pk;
}

// ---------------- rownorm f32 -> bf16 (wave-per-row) -----------------------
__global__ __launch_bounds__(256) void k_rownorm_f32(const float* __restrict__ in,
                                                     ushort_t* __restrict__ outp){
  int w = threadIdx.x >> 6, l = threadIdx.x & 63;
  int row = blockIdx.x*4 + w;
  const float* rp = in + (size_t)row*1024;
  float4 v[4]; float s = 0.f, q = 0.f;
  #pragma unroll
  for (int i = 0; i < 4; ++i){
    v[i] = *(const float4*)(rp + i*256 + l*4);
    s += v[i].x+v[i].y+v[i].z+v[i].w;
    q += v[i].x*v[i].x+v[i].y*v[i].y+v[i].z*v[i].z+v[i].w*v[i].w;
  }
  wreduce2(s, q);
  float mean = s * (1.f/1024.f);
  float rstd = rsqrtf(q*(1.f/1024.f) - mean*mean + 1e-5f);
  ushort_t* op = outp + (size_t)row*1024;
  #pragma unroll
  for (int i = 0; i < 4; ++i){
    ushort4v o;
    o.x = f2bf((v[i].x-mean)*rstd); o.y = f2bf((v[i].y-mean)*rstd);
    o.z = f2bf((v[i].z-mean)*rstd); o.w = f2bf((v[i].w-mean)*rstd);
    *(ushort4v*)(op + i*256 + l*4) = o;
  }
}

// ---------------- final layernorm (affine) f32 -> f32 ----------------------
__global__ __launch_bounds__(256) void k_final_ln(const float* __restrict__ x,
        const float* __restrict__ g, const float* __restrict__ bb, float* __restrict__ outp){
  int w = threadIdx.x >> 6, l = threadIdx.x & 63;
  int row = blockIdx.x*4 + w;
  const float* rp = x + (size_t)row*1024;
  float4 v[4]; float s = 0.f, q = 0.f;
  #pragma unroll
  for (int i = 0; i < 4; ++i){
    v[i] = *(const float4*)(rp + i*256 + l*4);
    s += v[i].x+v[i].y+v[i].z+v[i].w;
    q += v[i].x*v[i].x+v[i].y*v[i].y+v[i].z*v[i].z+v[i].w*v[i].w;
  }
  wreduce2(s, q);
  float mean = s * (1.f/1024.f);
  float rstd = rsqrtf(q*(1.f/1024.f) - mean*mean + 1e-5f);
  float* op = outp + (size_t)row*1024;
  #pragma unroll
  for (int i = 0; i < 4; ++i){
    float4 gg = *(const float4*)(g + i*256 + l*4);
    float4 bv = *(const float4*)(bb + i*256 + l*4);
    float4 o;
    o.x = (v[i].x-mean)*rstd*gg.x + bv.x; o.y = (v[i].y-mean)*rstd*gg.y + bv.y;
    o.z = (v[i].z-mean)*rstd*gg.z + bv.z; o.w = (v[i].w-mean)*rstd*gg.w + bv.w;
    *(float4*)(op + i*256 + l*4) = o;
  }
}

// ---------------- x init ----------------------------------------------------
__global__ __launch_bounds__(256) void k_init_x(const float* __restrict__ lat, float* __restrict__ x){
  int v = blockIdx.x*256 + threadIdx.x;
  int row = v >> 8, cv = v & 255;
  ((float4*)x)[v] = ((const float4*)lat)[(row & 63)*256 + cv];
}

// ---------------- batched weight fold + transpose --------------------------
DEV void foldT_body(const float* __restrict__ W, const float* __restrict__ g,
                    float scale, ushort_t* __restrict__ Wt, int K, int N,
                    int n0, int k0){
  __shared__ float Ts[64][65];
  int t = threadIdx.x;
  #pragma unroll
  for (int i = 0; i < 4; ++i){
    int flat = i*1024 + t*4; int r = flat >> 6, c = flat & 63;
    float4 v = *(const float4*)(W + (size_t)(k0+r)*N + n0 + c);
    float gg = (g ? g[k0+r] : 1.f) * scale;
    Ts[r][c] = v.x*gg; Ts[r][c+1] = v.y*gg; Ts[r][c+2] = v.z*gg; Ts[r][c+3] = v.w*gg;
  }
  __syncthreads();
  #pragma unroll
  for (int i = 0; i < 4; ++i){
    int flat = i*1024 + t*4; int rn = flat >> 6, ck = flat & 63;
    ushort4v o;
    o.x = f2bf(Ts[ck][rn]);   o.y = f2bf(Ts[ck+1][rn]);
    o.z = f2bf(Ts[ck+2][rn]); o.w = f2bf(Ts[ck+3][rn]);
    *(ushort4v*)(Wt + (size_t)(n0+rn)*K + k0 + ck) = o;
  }
}

struct FDesc { const float* W; const float* g; ushort_t* dst; float scale; int K; int N; };
#define MAXFD 32
struct FoldTArgs { int cnt; FDesc d[MAXFD]; };

__global__ __launch_bounds__(256) void k_foldT_all(FoldTArgs a){
  const FDesc d = a.d[blockIdx.y];
  int nxb = d.N >> 6;
  int n0 = (blockIdx.x % nxb) * 64;
  int k0 = (blockIdx.x / nxb) * 64;
  if (k0 >= d.K) return;
  foldT_body(d.W, d.g, d.scale, d.dst, d.K, d.N, n0, k0);
}

// ---------------- batched bias fold ----------------------------------------
DEV void foldBias_body(const float* __restrict__ W, const float* __restrict__ bvec,
                       float scale, float* __restrict__ bias, int K, int N, int o0){
  int t = threadIdx.x;
  int ol = t & 31, kc = t >> 5;
  int o = o0 + ol;
  int chunk = K >> 3;
  int c0 = kc*chunk, c1 = c0 + chunk;
  float s0 = 0, s1 = 0, s2 = 0, s3 = 0;
  for (int c = c0; c < c1; c += 4){
    s0 += bvec[c+0]*W[(size_t)(c+0)*N + o];
    s1 += bvec[c+1]*W[(size_t)(c+1)*N + o];
    s2 += bvec[c+2]*W[(size_t)(c+2)*N + o];
    s3 += bvec[c+3]*W[(size_t)(c+3)*N + o];
  }
  __shared__ float red[8][32];
  red[kc][ol] = (s0+s1)+(s2+s3);
  __syncthreads();
  if (kc == 0){
    float tot = 0;
    #pragma unroll
    for (int jj = 0; jj < 8; ++jj) tot += red[jj][ol];
    bias[o] = tot * scale;
  }
}

struct BDesc { const float* W; const float* b; float* dst; float scale; int K; int N; };
#define MAXBD 25
struct BiasArgs { int cnt; BDesc d[MAXBD]; };

__global__ __launch_bounds__(256) void k_foldBias_all(BiasArgs a){
  const BDesc d = a.d[blockIdx.y];
  int o0 = blockIdx.x * 32;
  if (o0 >= d.N) return;
  foldBias_body(d.W, d.b, d.scale, d.dst, d.K, d.N, o0);
}

// ---------------- 128x128 2-phase GEMM (small shapes) ----------------------
template<int OUTMODE, bool SKIP>
__global__ __launch_bounds__(256, 4) void k_gemm(const ushort_t* __restrict__ A,
        const ushort_t* __restrict__ Bt, const float* __restrict__ bias,
        void* __restrict__ Cp, int M, int N, int K, const int* __restrict__ cnt){
  const int n0 = blockIdx.x * 128;
  const int m0 = blockIdx.y * 128;
  if (SKIP){ int b = m0 >> 11; if ((m0 & 2047) >= cnt[b]) return; }
  __shared__ ushort_t sA[2][128*32];
  __shared__ ushort_t sB[2][128*32];
  const int tid = threadIdx.x;
  const int wave = tid >> 6, lane = tid & 63;
  const int lo = lane & 15, hi = lane >> 4;
  const int wr = wave >> 1, wc = wave & 1;

  auto stage = [&](int buf, int k0){
    #pragma unroll
    for (int p = 0; p < 2; ++p){
      int r = p*64 + wave*16 + (lane >> 2);
      int c = lane & 3;
      {
        const ushort_t* gp = A + (size_t)(m0 + r)*K + k0 + c*8;
        char* lp = (char*)(&sA[buf][0]) + p*4096 + wave*1024;
        GLOAD16(gp, lp);
      }
      {
        const ushort_t* gp = Bt + (size_t)(n0 + r)*K + k0 + c*8;
        char* lp = (char*)(&sB[buf][0]) + p*4096 + wave*1024;
        GLOAD16(gp, lp);
      }
    }
  };

  f32x4 acc[4][4] = {};
  stage(0, 0);
  const int nk = K >> 5;
  for (int ks = 0; ks < nk; ++ks){
    __syncthreads();
    if (ks + 1 < nk) stage((ks+1)&1, (ks+1) << 5);
    const int buf = ks & 1;
    short8 af[4], bfr[4];
    #pragma unroll
    for (int mi = 0; mi < 4; ++mi)
      af[mi] = *(const short8*)(&sA[buf][(wr*64 + mi*16 + lo)*32 + hi*8]);
    #pragma unroll
    for (int ni = 0; ni < 4; ++ni)
      bfr[ni] = *(const short8*)(&sB[buf][(wc*64 + ni*16 + lo)*32 + hi*8]);
    #pragma unroll
    for (int mi = 0; mi < 4; ++mi)
      #pragma unroll
      for (int ni = 0; ni < 4; ++ni)
        acc[mi][ni] = MFMA16(af[mi], bfr[ni], acc[mi][ni]);
  }
  #pragma unroll
  for (int ni = 0; ni < 4; ++ni){
    int col = n0 + wc*64 + ni*16 + lo;
    float bv = bias ? bias[col] : 0.f;
    #pragma unroll
    for (int mi = 0; mi < 4; ++mi){
      int rbase = m0 + wr*64 + mi*16 + hi*4;
      #pragma unroll
      for (int rr = 0; rr < 4; ++rr){
        float v = acc[mi][ni][rr] + bv;
        size_t off = (size_t)(rbase + rr)*N + col;
        if (OUTMODE == 0)      ((ushort_t*)Cp)[off] = f2bf(v);
        else if (OUTMODE == 1) ((ushort_t*)Cp)[off] = f2bf(fmaxf(v, 0.f));
        else                   ((float*)Cp)[off] += v;
      }
    }
  }
}

// ---------------- 256x256 8-phase bf16 GEMM (down-proj) --------------------
template<bool SKIP, int NXB>
__global__ __launch_bounds__(512, 2) void k_gemm256p8(const ushort_t* __restrict__ A,
        const ushort_t* __restrict__ Bt, const float* __restrict__ bias,
        ushort_t* __restrict__ Cp, int M, int N, int K, const int* __restrict__ cnt){
  int bx, by;
  xcd_remapN<NXB>(blockIdx.x, gridDim.x, bx, by);
  const int n0 = bx * 256;
  const int m0 = by * 256;
  if (SKIP){ int b = m0 >> 11; if ((m0 & 2047) >= cnt[b]) return; }
  __shared__ __align__(16) ushort_t sA[2][256*64];
  __shared__ __align__(16) ushort_t sB[2][256*64];
  const int tid = threadIdx.x;
  const int wave = tid >> 6, lane = tid & 63;
  const int lo = lane & 15, hi = lane >> 4;
  const int wm = wave >> 2, wn = wave & 3;
  const int srow = lane >> 3;
  const int schunk = (lane & 7) ^ srow;
  auto stageHalf = [&](ushort_t* dst, const ushort_t* __restrict__ G, int grow0,
                       int half, int k0){
    #pragma unroll
    for (int p = 0; p < 2; ++p){
      int rbase = half*128 + p*64 + wave*8;
      const ushort_t* gp = G + (size_t)(grow0 + rbase + srow)*K + k0 + schunk*8;
      char* lp = (char*)dst + (size_t)rbase*128;
      GLOAD16(gp, lp);
    }
  };
  auto ldsA = [&](int buf, int row, int kk)->short8{
    int ch = ((kk<<2) + hi) ^ (row & 7);
    return *(const short8*)((const char*)sA + (size_t)buf*32768 + (size_t)row*128 + ch*16);
  };
  auto ldsB = [&](int buf, int row, int kk)->short8{
    int ch = ((kk<<2) + hi) ^ (row & 7);
    return *(const short8*)((const char*)sB + (size_t)buf*32768 + (size_t)row*128 + ch*16);
  };
  f32x4 acc[8][4] = {};

  short8 af[4][2], bg[2][2];
#define LOADA(BUF, AH) \
    _Pragma("unroll") for (int mi_ = 0; mi_ < 4; ++mi_) \
      _Pragma("unroll") for (int kk_ = 0; kk_ < 2; ++kk_) \
        af[mi_][kk_] = ldsA(BUF, (AH)*128 + wm*64 + mi_*16 + lo, kk_);
#define LOADB(BUF, BH) \
    _Pragma("unroll") for (int nj_ = 0; nj_ < 2; ++nj_) \
      _Pragma("unroll") for (int kk_ = 0; kk_ < 2; ++kk_) \
        bg[nj_][kk_] = ldsB(BUF, (BH)*128 + wn*32 + nj_*16 + lo, kk_);
#define MMQ(AH, BH) \
    __builtin_amdgcn_s_barrier(); CFENCE; \
    __builtin_amdgcn_s_setprio(1); \
    _Pragma("unroll") for (int mi_ = 0; mi_ < 4; ++mi_) \
      _Pragma("unroll") for (int nj_ = 0; nj_ < 2; ++nj_) \
        _Pragma("unroll") for (int kk_ = 0; kk_ < 2; ++kk_) \
          acc[(AH)*4+mi_][(BH)*2+nj_] = \
            MFMA16(af[mi_][kk_], bg[nj_][kk_], acc[(AH)*4+mi_][(BH)*2+nj_]); \
    __builtin_amdgcn_s_setprio(0); CFENCE; \
    __builtin_amdgcn_s_barrier(); CFENCE;

  stageHalf(&sA[0][0], A,  m0, 0, 0);
  stageHalf(&sB[0][0], Bt, n0, 0, 0);
  stageHalf(&sA[0][0], A,  m0, 1, 0);
  stageHalf(&sB[0][0], Bt, n0, 1, 0);
  stageHalf(&sA[1][0], A,  m0, 0, 64);
  stageHalf(&sB[1][0], Bt, n0, 1, 64);
  VMCNT(4);
  __builtin_amdgcn_s_barrier();
  CFENCE;

  const int NI = K >> 7;
  for (int i = 0; i < NI; ++i){
    const int kt = i << 7;
    const bool lastI = (i == NI-1);
    LOADA(0,0) LOADB(0,0)
    stageHalf(&sA[1][0], A,  m0, 1, kt+64);
    MMQ(0,0)
    LOADB(0,1)
    stageHalf(&sB[1][0], Bt, n0, 0, kt+64);
    MMQ(0,1)
    LOADA(0,1)
    if (!lastI) stageHalf(&sA[0][0], A,  m0, 0, kt+128);
    MMQ(1,1)
    LOADB(0,0)
    if (!lastI) stageHalf(&sB[0][0], Bt, n0, 1, kt+128);
    if (lastI){ VMCNT(0); } else { VMCNT(4); }
    MMQ(1,0)
    LOADA(1,0) LOADB(1,0)
    if (!lastI) stageHalf(&sA[0][0], A,  m0, 1, kt+128);
    MMQ(0,0)
    LOADB(1,1)
    if (!lastI) stageHalf(&sB[0][0], Bt, n0, 0, kt+128);
    MMQ(0,1)
    LOADA(1,1)
    if (!lastI) stageHalf(&sA[1][0], A,  m0, 0, kt+192);
    MMQ(1,1)
    LOADB(1,0)
    if (!lastI){ stageHalf(&sB[1][0], Bt, n0, 1, kt+192); VMCNT(4); }
    MMQ(1,0)
  }
#undef LOADA
#undef LOADB
#undef MMQ

  #pragma unroll
  for (int b2 = 0; b2 < 2; ++b2)
    #pragma unroll
    for (int nj = 0; nj < 2; ++nj){
      int col = n0 + b2*128 + wn*32 + nj*16 + lo;
      float bv = bias ? bias[col] : 0.f;
      #pragma unroll
      for (int a2 = 0; a2 < 2; ++a2)
        #pragma unroll
        for (int mi4 = 0; mi4 < 4; ++mi4){
          int rbase = m0 + a2*128 + wm*64 + mi4*16 + hi*4;
          #pragma unroll
          for (int rr = 0; rr < 4; ++rr){
            float v = acc[a2*4+mi4][b2*2+nj][rr] + bv;
            Cp[(size_t)(rbase + rr)*N + col] = f2bf(v);
          }
        }
    }
}

// ---------------- 256x256 8-phase i8 GEMM (KV projections) -----------------
// A[M][1024] i8 (per-row scale sA), Bt[N][1024] i8 (per-row scale sB).
// C = (i32 dot) * sA[m] * sB[n] + bias[n], stored bf16. Kb = K in bytes.
// Byte-layout identical to bf16 kernel: rows of 128B K-windows, 16B chunks,
// chunk-XOR swizzle; MFMA 16x16x64 i8 consumes 16B/lane (chunk = kk*4+hi).
template<bool SKIP, int NXB>
__global__ __launch_bounds__(512, 2) void k_gemm256i8(const int8_t* __restrict__ A,
        const int8_t* __restrict__ Bt, const float* __restrict__ sAr,
        const float* __restrict__ sBr, const float* __restrict__ bias,
        ushort_t* __restrict__ Cp, int M, int N, int Kb, const int* __restrict__ cnt){
  int bx, by;
  xcd_remapN<NXB>(blockIdx.x, gridDim.x, bx, by);
  const int n0 = bx * 256;
  const int m0 = by * 256;
  if (SKIP){ int b = m0 >> 11; if ((m0 & 2047) >= cnt[b]) return; }
  __shared__ __align__(16) char sAl[2][256*128];
  __shared__ __align__(16) char sBl[2][256*128];
  const int tid = threadIdx.x;
  const int wave = tid >> 6, lane = tid & 63;
  const int lo = lane & 15, hi = lane >> 4;
  const int wm = wave >> 2, wn = wave & 3;
  const int srow = lane >> 3;
  const int schunk = (lane & 7) ^ srow;
  auto stageHalf = [&](char* dst, const int8_t* __restrict__ G, int grow0,
                       int half, int k0){            // k0 in BYTES
    #pragma unroll
    for (int p = 0; p < 2; ++p){
      int rbase = half*128 + p*64 + wave*8;
      const int8_t* gp = G + (size_t)(grow0 + rbase + srow)*Kb + k0 + schunk*16;
      char* lp = dst + (size_t)rbase*128;
      GLOAD16(gp, lp);
    }
  };
  auto ldsA = [&](int buf, int row, int kk)->int4v{
    int ch = ((kk<<2) + hi) ^ (row & 7);
    return *(const int4v*)((const char*)sAl + (size_t)buf*32768 + (size_t)row*128 + ch*16);
  };
  auto ldsB = [&](int buf, int row, int kk)->int4v{
    int ch = ((kk<<2) + hi) ^ (row & 7);
    return *(const int4v*)((const char*)sBl + (size_t)buf*32768 + (size_t)row*128 + ch*16);
  };
  int4v acc[8][4] = {};

  int4v af[4][2], bg[2][2];
#define LOADA(BUF, AH) \
    _Pragma("unroll") for (int mi_ = 0; mi_ < 4; ++mi_) \
      _Pragma("unroll") for (int kk_ = 0; kk_ < 2; ++kk_) \
        af[mi_][kk_] = ldsA(BUF, (AH)*128 + wm*64 + mi_*16 + lo, kk_);
#define LOADB(BUF, BH) \
    _Pragma("unroll") for (int nj_ = 0; nj_ < 2; ++nj_) \
      _Pragma("unroll") for (int kk_ = 0; kk_ < 2; ++kk_) \
        bg[nj_][kk_] = ldsB(BUF, (BH)*128 + wn*32 + nj_*16 + lo, kk_);
#define MMQ(AH, BH) \
    __builtin_amdgcn_s_barrier(); CFENCE; \
    __builtin_amdgcn_s_setprio(1); \
    _Pragma("unroll") for (int mi_ = 0; mi_ < 4; ++mi_) \
      _Pragma("unroll") for (int nj_ = 0; nj_ < 2; ++nj_) \
        _Pragma("unroll") for (int kk_ = 0; kk_ < 2; ++kk_) \
          acc[(AH)*4+mi_][(BH)*2+nj_] = \
            MFMAI8(af[mi_][kk_], bg[nj_][kk_], acc[(AH)*4+mi_][(BH)*2+nj_]); \
    __builtin_amdgcn_s_setprio(0); CFENCE; \
    __builtin_amdgcn_s_barrier(); CFENCE;

  stageHalf(&sAl[0][0], A,  m0, 0, 0);
  stageHalf(&sBl[0][0], Bt, n0, 0, 0);
  stageHalf(&sAl[0][0], A,  m0, 1, 0);
  stageHalf(&sBl[0][0], Bt, n0, 1, 0);
  stageHalf(&sAl[1][0], A,  m0, 0, 128);
  stageHalf(&sBl[1][0], Bt, n0, 1, 128);
  VMCNT(4);
  __builtin_amdgcn_s_barrier();
  CFENCE;

  const int NI = Kb >> 8;            // 2 K-tiles (128B each) per iteration
  for (int i = 0; i < NI; ++i){
    const int kt = i << 8;
    const bool lastI = (i == NI-1);
    LOADA(0,0) LOADB(0,0)
    stageHalf(&sAl[1][0], A,  m0, 1, kt+128);
    MMQ(0,0)
    LOADB(0,1)
    stageHalf(&sBl[1][0], Bt, n0, 0, kt+128);
    MMQ(0,1)
    LOADA(0,1)
    if (!lastI) stageHalf(&sAl[0][0], A,  m0, 0, kt+256);
    MMQ(1,1)
    LOADB(0,0)
    if (!lastI) stageHalf(&sBl[0][0], Bt, n0, 1, kt+256);
    if (lastI){ VMCNT(0); } else { VMCNT(4); }
    MMQ(1,0)
    LOADA(1,0) LOADB(1,0)
    if (!lastI) stageHalf(&sAl[0][0], A,  m0, 1, kt+256);
    MMQ(0,0)
    LOADB(1,1)
    if (!lastI) stageHalf(&sBl[0][0], Bt, n0, 0, kt+256);
    MMQ(0,1)
    LOADA(1,1)
    if (!lastI) stageHalf(&sAl[1][0], A,  m0, 0, kt+384);
    MMQ(1,1)
    LOADB(1,0)
    if (!lastI){ stageHalf(&sBl[1][0], Bt, n0, 1, kt+384); VMCNT(4); }
    MMQ(1,0)
  }
#undef LOADA
#undef LOADB
#undef MMQ

  #pragma unroll
  for (int b2 = 0; b2 < 2; ++b2)
    #pragma unroll
    for (int nj = 0; nj < 2; ++nj){
      int col = n0 + b2*128 + wn*32 + nj*16 + lo;
      float bv = bias ? bias[col] : 0.f;
      float sb = sBr[col];
      #pragma unroll
      for (int a2 = 0; a2 < 2; ++a2)
        #pragma unroll
        for (int mi4 = 0; mi4 < 4; ++mi4){
          int rbase = m0 + a2*128 + wm*64 + mi4*16 + hi*4;
          #pragma unroll
          for (int rr = 0; rr < 4; ++rr){
            int row = rbase + rr;
            float v = (float)acc[a2*4+mi4][b2*2+nj][rr] * (sAr[row]*sb) + bv;
            Cp[(size_t)row*N + col] = f2bf(v);
          }
        }
    }
}

// ---------------- flash attention (pipelined): one block per (b,h) ---------
__global__ __launch_bounds__(256) void k_attn(const ushort_t* __restrict__ qb,
        const ushort_t* __restrict__ kvb, int kstride, const int* __restrict__ cnt,
        ushort_t* __restrict__ outb){
  const int bh = blockIdx.x;
  const int b = bh >> 4, h = bh & 15;
  const int t = threadIdx.x;
  const int wave = t >> 6, lane = t & 63, lo = lane & 15, hi = lane >> 4;
  __shared__ ushort_t Qs[64*64];
  __shared__ ushort_t Ks[2][64*64];
  __shared__ ushort_t Vt[2][64][72];
  __shared__ ushort_t Ps[4][16][72];

  const int count = cnt[b];

  #pragma unroll
  for (int p = 0; p < 2; ++p){
    int r = p*32 + wave*8 + (lane >> 3);
    int c = (lane & 7) ^ (r & 7);
    const ushort_t* gp = qb + (size_t)(b*64 + r)*1024 + h*64 + c*8;
    char* lp = (char*)Qs + p*4096 + wave*1024;
    GLOAD16(gp, lp);
  }

  auto stageK = [&](int buf, int tt){
    #pragma unroll
    for (int p = 0; p < 2; ++p){
      int r = p*32 + wave*8 + (lane >> 3);
      int c = (lane & 7) ^ (r & 7);
      const ushort_t* gp = kvb + (size_t)(b*2048 + tt*64 + r)*kstride + h*64 + c*8;
      char* lp = (char*)(&Ks[buf][0]) + p*4096 + wave*1024;
      GLOAD16(gp, lp);
    }
  };
  const int vjj = (t & 31)*2, vc = (t >> 5)*8;
  ushort4v va0, va1, vb0, vb1;
  auto issueV = [&](int tt){
    const ushort_t* g0 = kvb + (size_t)(b*2048 + tt*64 + vjj)*kstride + 1024 + h*64 + vc;
    va0 = *(const ushort4v*)(g0);
    va1 = *(const ushort4v*)(g0 + 4);
    vb0 = *(const ushort4v*)(g0 + kstride);
    vb1 = *(const ushort4v*)(g0 + kstride + 4);
  };
  auto writeV = [&](int buf, int tt){
    bool va  = (tt*64 + vjj)     < count;
    bool vb2 = (tt*64 + vjj + 1) < count;
    #pragma unroll
    for (int u = 0; u < 8; ++u){
      ushort_t ea = (u < 4) ? ((ushort_t*)&va0)[u] : ((ushort_t*)&va1)[u-4];
      ushort_t eb = (u < 4) ? ((ushort_t*)&vb0)[u] : ((ushort_t*)&vb1)[u-4];
      uint32_t word = (va ? (uint32_t)ea : 0u) | ((vb2 ? (uint32_t)eb : 0u) << 16);
      *(uint32_t*)(&Vt[buf][vc+u][vjj]) = word;
    }
  };

  f32x4 oacc[4] = {};
  float m[4], l[4];
  #pragma unroll
  for (int rr = 0; rr < 4; ++rr){ m[rr] = -__builtin_inff(); l[rr] = 0.f; }

  const int ntiles = (count + 63) >> 6;
  if (ntiles > 0){ stageK(0, 0); issueV(0); }

  for (int tt = 0; tt < ntiles; ++tt){
    const int buf = tt & 1;
    writeV(buf, tt);
    if (tt + 1 < ntiles){ stageK(buf^1, tt+1); issueV(tt+1); }
    asm volatile("s_waitcnt lgkmcnt(0)" ::: "memory");
    __builtin_amdgcn_s_barrier();
    CFENCE;

    f32x4 s[4] = {};
    #pragma unroll
    for (int kk = 0; kk < 2; ++kk){
      int rA = wave*16 + lo;
      short8 aq = *(const short8*)(&Qs[rA*64 + (((kk*4 + hi) ^ (rA & 7))*8)]);
      #pragma unroll
      for (int ni = 0; ni < 4; ++ni){
        int rB = ni*16 + lo;
        short8 bk = *(const short8*)(&Ks[buf][rB*64 + (((kk*4 + hi) ^ (rB & 7))*8)]);
        s[ni] = MFMA16(aq, bk, s[ni]);
      }
    }
    #pragma unroll
    for (int ni = 0; ni < 4; ++ni){
      if (tt*64 + ni*16 + lo >= count){
        s[ni][0] = s[ni][1] = s[ni][2] = s[ni][3] = -__builtin_inff();
      }
    }
    float p[4][4];
    #pragma unroll
    for (int rr = 0; rr < 4; ++rr){
      float mx = fmaxf(fmaxf(s[0][rr], s[1][rr]), fmaxf(s[2][rr], s[3][rr]));
      #pragma unroll
      for (int d = 1; d < 16; d <<= 1) mx = fmaxf(mx, __shfl_xor(mx, d));
      float mnew = fmaxf(m[rr], mx);
      float sc = __expf(m[rr] - mnew);
      float rsum = 0.f;
      #pragma unroll
      for (int ni = 0; ni < 4; ++ni){
        float pv = __expf(s[ni][rr] - mnew);
        p[ni][rr] = pv;
        rsum += pv;
      }
      #pragma unroll
      for (int d = 1; d < 16; d <<= 1) rsum += __shfl_xor(rsum, d);
      l[rr] = l[rr]*sc + rsum;
      m[rr] = mnew;
      #pragma unroll
      for (int ni = 0; ni < 4; ++ni) oacc[ni][rr] *= sc;
    }
    #pragma unroll
    for (int ni = 0; ni < 4; ++ni)
      #pragma unroll
      for (int rr = 0; rr < 4; ++rr)
        Ps[wave][hi*4+rr][ni*16+lo] = f2bf(p[ni][rr]);
    asm volatile("s_waitcnt lgkmcnt(0)" ::: "memory");
    #pragma unroll
    for (int kk = 0; kk < 2; ++kk){
      short8 pa = *(const short8*)(&Ps[wave][lo][kk*32 + hi*8]);
      #pragma unroll
      for (int ni = 0; ni < 4; ++ni){
        short8 bv = *(const short8*)(&Vt[buf][ni*16 + lo][kk*32 + hi*8]);
        oacc[ni] = MFMA16(pa, bv, oacc[ni]);
      }
    }
    CFENCE;
    __builtin_amdgcn_s_barrier();
    CFENCE;
  }
  #pragma unroll
  for (int rr = 0; rr < 4; ++rr){
    float inv = (l[rr] > 0.f) ? 1.f/l[rr] : 0.f;
    #pragma unroll
    for (int ni = 0; ni < 4; ++ni){
      size_t off = (size_t)(b*64 + wave*16 + hi*4 + rr)*1024 + h*64 + ni*16 + lo;
      outb[off] = f2bf(oacc[ni][rr] * inv);
    }
  }
}

// ---------------------------------------------------------------------------
extern "C" void kernel_launch(void* const* d_in, const int* in_sizes, int n_in,
                              void* d_out, int out_size, void* d_ws, size_t ws_size,
                              hipStream_t stream){
  const float* features = (const float*)d_in[0];
  const int*   mask     = (const int*)  d_in[1];
  const float* latents  = (const float*)d_in[2];
  const float* W_down   = (const float*)d_in[3];
  const float* nin_g    = (const float*)d_in[4];
  const float* nin_b    = (const float*)d_in[5];
  const float* lf_g     = (const float*)d_in[6];
  const float* lf_b     = (const float*)d_in[7];
  const float* ll_g     = (const float*)d_in[8];
  const float* ll_b     = (const float*)d_in[9];
  const float* Wq       = (const float*)d_in[10];
  const float* Wk       = (const float*)d_in[11];
  const float* Wv       = (const float*)d_in[12];
  const float* ffln_g   = (const float*)d_in[13];
  const float* ffln_b   = (const float*)d_in[14];
  const float* ff_w1    = (const float*)d_in[15];
  const float* ff_w2    = (const float*)d_in[16];
  const float* nout_g   = (const float*)d_in[17];
  const float* nout_b   = (const float*)d_in[18];

  char* ws = (char*)d_ws;
  size_t off = 0;
  auto alloc = [&](size_t bytes)->char*{
    char* p = ws + off;
    off += (bytes + 255) & ~(size_t)255;
    return p;
  };
  const size_t SZW = (size_t)1024*1024*2;       // 2 MB (1024x1024 bf16)

  ushort_t* FHAT  = (ushort_t*)alloc((size_t)65536*1024*2);   // raw down-proj out
  int8_t*   I8A   = (int8_t*)  alloc((size_t)65536*1024);     // LN'd fhat, i8
  float*    SA    = (float*)   alloc((size_t)65536*4);
  int8_t*   I8B   = (int8_t*)  alloc((size_t)12288*1024);     // KV weights, i8
  float*    SB    = (float*)   alloc((size_t)12288*4);
  ushort_t* WDT   = (ushort_t*)alloc(SZW);
  ushort_t* WQT6  = (ushort_t*)alloc(SZW*6);
  ushort_t* WKVT6 = (ushort_t*)alloc(SZW*2*6);  // [12288][1024] bf16 (pre-quant)
  ushort_t* W1T6  = (ushort_t*)alloc(SZW*2*6);
  ushort_t* W2T6  = (ushort_t*)alloc(SZW*2*6);
  float* BD   = (float*)alloc(1024*4);
  float* BQ6  = (float*)alloc(1024*4*6);
  float* BKV6 = (float*)alloc(2048*4*6);
  float* B16  = (float*)alloc(2048*4*6);
  float*    X    = (float*)   alloc((size_t)2048*1024*4);
  ushort_t* XHAT = (ushort_t*)alloc((size_t)2048*1024*2);
  ushort_t* QP   = (ushort_t*)alloc((size_t)2048*1024*2);
  ushort_t* OUTB = (ushort_t*)alloc((size_t)2048*1024*2);
  ushort_t* OUTH = (ushort_t*)alloc((size_t)2048*1024*2);
  ushort_t* H1   = (ushort_t*)alloc((size_t)2048*2048*2);
  int* CNT = (int*)alloc(32*4);
  int* IDX = (int*)alloc((size_t)65536*4);
  ushort_t* KVBUF = (ushort_t*)alloc((size_t)65536*2048*2);   // 256 MB
  ushort_t* FNORM = KVBUF;   // transient alias (dead before KV GEMM writes)
  (void)in_sizes; (void)n_in; (void)out_size; (void)ws_size;

  const float scale = 0.125f;  // DH^-0.5

  // ---- batched weight folds (all depth-independent) ----
  FoldTArgs fa; int nf = 0;
  auto addF = [&](const float* W, const float* g, float sc, ushort_t* dst, int K, int N){
    fa.d[nf++] = FDesc{W, g, dst, sc, K, N};
  };
  addF(W_down, nin_g, 1.f, WDT, 1024, 1024);
  for (int i = 0; i < 6; ++i){
    const float* Wqi = Wq + (size_t)i*1024*1024;
    const float* Wki = Wk + (size_t)i*1024*1024;
    const float* Wvi = Wv + (size_t)i*1024*1024;
    const float* W1i = ff_w1 + (size_t)i*1024*2048;
    const float* W2i = ff_w2 + (size_t)i*2048*1024;
    addF(Wqi, ll_g + i*1024, scale, WQT6  + i*(SZW/2),        1024, 1024);
    addF(Wki, lf_g + i*1024, 1.f,   WKVT6 + i*SZW,            1024, 1024);
    addF(Wvi, lf_g + i*1024, 1.f,   WKVT6 + i*SZW + (SZW/2),  1024, 1024);
    addF(W1i, ffln_g + i*1024, 1.f, W1T6  + i*SZW,            1024, 2048);
    addF(W2i, nullptr, 1.f,         W2T6  + i*SZW,            2048, 1024);
  }
  fa.cnt = nf;

  BiasArgs ba; int nb = 0;
  auto addB = [&](const float* W, const float* b, float sc, float* dst, int K, int N){
    ba.d[nb++] = BDesc{W, b, dst, sc, K, N};
  };
  addB(W_down, nin_b, 1.f, BD, 1024, 1024);
  for (int i = 0; i < 6; ++i){
    const float* Wqi = Wq + (size_t)i*1024*1024;
    const float* Wki = Wk + (size_t)i*1024*1024;
    const float* Wvi = Wv + (size_t)i*1024*1024;
    const float* W1i = ff_w1 + (size_t)i*1024*2048;
    addB(Wqi, ll_b + i*1024, scale, BQ6  + i*1024,        1024, 1024);
    addB(Wki, lf_b + i*1024, 1.f,   BKV6 + i*2048,        1024, 1024);
    addB(Wvi, lf_b + i*1024, 1.f,   BKV6 + i*2048 + 1024, 1024, 1024);
    addB(W1i, ffln_b + i*1024, 1.f, B16  + i*2048,        1024, 2048);
  }
  ba.cnt = nb;

  // ---- setup ----
  k_compact     <<<32,    256, 0, stream>>>(mask, IDX, CNT);
  k_gather_norm <<<16384, 256, 0, stream>>>(features, IDX, CNT, FNORM);
  k_foldT_all   <<<dim3(512, nf), 256, 0, stream>>>(fa);
  k_foldBias_all<<<dim3(64,  nb), 256, 0, stream>>>(ba);
  k_quantW      <<<3072,  256, 0, stream>>>(WKVT6, I8B, SB);
  k_gemm256p8<true,4><<<1024, 512, 0, stream>>>(FNORM, WDT, BD, FHAT, 65536, 1024, 1024, CNT);
  k_rownorm_i8  <<<16384, 256, 0, stream>>>(FHAT, I8A, SA, CNT);
  k_init_x      <<<2048,  256, 0, stream>>>(latents, X);

  for (int i = 0; i < 6; ++i){
    k_gemm256i8<true,8><<<2048, 512, 0, stream>>>(I8A, I8B + (size_t)i*2048*1024,
                                                  SA, SB + i*2048, BKV6 + i*2048,
                                                  KVBUF, 65536, 2048, 1024, CNT);
    k_rownorm_f32<<<512, 256, 0, stream>>>(X, XHAT);
    k_gemm<0,false><<<dim3(8,16),  256, 0, stream>>>(XHAT, WQT6 + i*(SZW/2), BQ6 + i*1024,
                                                     QP, 2048, 1024, 1024, nullptr);
    k_attn<<<512, 256, 0, stream>>>(QP, KVBUF, 2048, CNT, OUTB);
    k_rownorm_bf16<<<512, 256, 0, stream>>>(OUTB, OUTH, nullptr);
    k_gemm<1,false><<<dim3(16,16), 256, 0, stream>>>(OUTH, W1T6 + i*SZW, B16 + i*2048,
                                                     H1, 2048, 2048, 1024, nullptr);
    k_gemm<2,false><<<dim3(8,16),  256, 0, stream>>>(H1, W2T6 + i*SZW, nullptr,
                                                     X, 2048, 1024, 2048, nullptr);
  }
  k_final_ln<<<512, 256, 0, stream>>>(X, nout_g, nout_b, (float*)d_out);
}

// Round 9
// 1783.351 us; speedup vs baseline: 1.8584x; 1.1335x over previous
//
#include <hip/hip_runtime.h>
#include <stdint.h>

// ---------------------------------------------------------------------------
// PerceiverResampler on MI355X (gfx950)
// B=32, F=2048, DIM=1024, INNER=1024, H=16, DH=64, Q=64, DEPTH=6, MULT=2
//
// Round 9: i8 everywhere it pays. KV (256x256 8-phase i8, validated R8) plus
// Q / FF1 / FF2 on a 128x128 2-phase i8 GEMM (half the K-loop iterations of
// bf16). Activations quantized per-row inside the existing norm passes;
// weights quantized once in setup. Attention + down-proj stay bf16.
// ---------------------------------------------------------------------------

#define DEV static __device__ __forceinline__

typedef __attribute__((ext_vector_type(8))) short short8;
typedef __attribute__((ext_vector_type(4))) float f32x4;
typedef __attribute__((ext_vector_type(4))) int int4v;
typedef __attribute__((ext_vector_type(4))) unsigned short ushort4v;
typedef unsigned short ushort_t;

DEV float bf2f(ushort_t u){ union{uint32_t i; float f;} x; x.i = ((uint32_t)u)<<16; return x.f; }
DEV ushort_t f2bf(float f){
  union{float f; uint32_t i;} x; x.f = f;
  uint32_t r = x.i + 0x7fffu + ((x.i>>16)&1u);  // RNE
  return (ushort_t)(r>>16);
}

#define GLOAD16(gp, lp) __builtin_amdgcn_global_load_lds( \
    (const __attribute__((address_space(1))) uint32_t*)(gp), \
    (__attribute__((address_space(3))) uint32_t*)(lp), 16, 0, 0)

#define VMCNT(n) asm volatile("s_waitcnt vmcnt(" #n ")" ::: "memory")
#define CFENCE   asm volatile("" ::: "memory")
#define MFMA16(a,b,c) __builtin_amdgcn_mfma_f32_16x16x32_bf16(a,b,c,0,0,0)
#define MFMAI8(a,b,c) __builtin_amdgcn_mfma_i32_16x16x64_i8(a,b,c,0,0,0)

template<int NXB>
DEV void xcd_remapN(int g, int total, int& x, int& y){
  int xcd = g & 7;
  int k = g >> 3;
  int rows_per_xcd = (total / NXB) >> 3;
  y = xcd * rows_per_xcd + (k / NXB);
  x = k % NXB;
}

DEV void wreduce2(float& a, float& b){
  #pragma unroll
  for (int d = 32; d; d >>= 1){ a += __shfl_xor(a, d); b += __shfl_xor(b, d); }
}

// ---------------- mask compaction ------------------------------------------
__global__ __launch_bounds__(256) void k_compact(const int* __restrict__ mask,
                                                 int* __restrict__ idx, int* __restrict__ cnt){
  int b = blockIdx.x, t = threadIdx.x;
  const int* mb = mask + b*2048;
  int keep[8]; int c = 0;
  #pragma unroll
  for (int u = 0; u < 8; ++u){ keep[u] = (mb[t*8+u] != 0); c += keep[u]; }
  __shared__ int s[256];
  s[t] = c; __syncthreads();
  for (int off = 1; off < 256; off <<= 1){
    int v = (t >= off) ? s[t-off] : 0;
    __syncthreads();
    s[t] += v;
    __syncthreads();
  }
  int pos = s[t] - c;
  #pragma unroll
  for (int u = 0; u < 8; ++u) if (keep[u]) idx[b*2048 + pos++] = t*8 + u;
  if (t == 255) cnt[b] = s[255];
}

// ---------------- gather + rownorm features -> bf16 (wave-per-row) ---------
__global__ __launch_bounds__(256) void k_gather_norm(const float* __restrict__ feat,
        const int* __restrict__ idx, const int* __restrict__ cnt, ushort_t* __restrict__ outp){
  int w = threadIdx.x >> 6, l = threadIdx.x & 63;
  int row = blockIdx.x*4 + w;
  int b = row >> 11, j = row & 2047;
  if (j >= cnt[b]) return;
  int src = idx[b*2048 + j];
  const float* rp = feat + ((size_t)(b*2048 + src))*1024;
  float4 v[4]; float s = 0.f, q = 0.f;
  #pragma unroll
  for (int i = 0; i < 4; ++i){
    v[i] = *(const float4*)(rp + i*256 + l*4);
    s += v[i].x+v[i].y+v[i].z+v[i].w;
    q += v[i].x*v[i].x+v[i].y*v[i].y+v[i].z*v[i].z+v[i].w*v[i].w;
  }
  wreduce2(s, q);
  float mean = s * (1.f/1024.f);
  float rstd = rsqrtf(q*(1.f/1024.f) - mean*mean + 1e-5f);
  ushort_t* op = outp + (size_t)row*1024;
  #pragma unroll
  for (int i = 0; i < 4; ++i){
    ushort4v o;
    o.x = f2bf((v[i].x-mean)*rstd); o.y = f2bf((v[i].y-mean)*rstd);
    o.z = f2bf((v[i].z-mean)*rstd); o.w = f2bf((v[i].w-mean)*rstd);
    *(ushort4v*)(op + i*256 + l*4) = o;
  }
}

// ---------------- rownorm bf16 -> i8 + per-row scale (cnt nullable) --------
__global__ __launch_bounds__(256) void k_rownorm_i8(const ushort_t* __restrict__ in,
        int8_t* __restrict__ outp, float* __restrict__ sca, const int* __restrict__ cnt){
  int w = threadIdx.x >> 6, l = threadIdx.x & 63;
  int row = blockIdx.x*4 + w;
  if (cnt){ int b = row >> 11; if ((row & 2047) >= cnt[b]) return; }
  const ushort_t* rp = in + (size_t)row*1024 + l*16;
  float f[16]; float s = 0.f, q = 0.f;
  #pragma unroll
  for (int i = 0; i < 4; ++i){
    ushort4v u = *(const ushort4v*)(rp + i*4);
    f[i*4+0] = bf2f(u.x); f[i*4+1] = bf2f(u.y);
    f[i*4+2] = bf2f(u.z); f[i*4+3] = bf2f(u.w);
  }
  #pragma unroll
  for (int jj = 0; jj < 16; ++jj){ s += f[jj]; q += f[jj]*f[jj]; }
  wreduce2(s, q);
  float mean = s * (1.f/1024.f);
  float rstd = rsqrtf(q*(1.f/1024.f) - mean*mean + 1e-5f);
  float amax = 0.f;
  #pragma unroll
  for (int jj = 0; jj < 16; ++jj) amax = fmaxf(amax, fabsf(f[jj]-mean));
  #pragma unroll
  for (int d = 32; d; d >>= 1) amax = fmaxf(amax, __shfl_xor(amax, d));
  amax *= rstd;
  float inv = (amax > 0.f) ? 127.f/amax : 0.f;
  if (l == 0) sca[row] = amax * (1.f/127.f);
  uint32_t wds[4];
  #pragma unroll
  for (int i = 0; i < 4; ++i){
    uint32_t wd = 0;
    #pragma unroll
    for (int c = 0; c < 4; ++c){
      int qv = (int)rintf((f[i*4+c]-mean)*rstd*inv);
      wd |= ((uint32_t)(uint8_t)(int8_t)qv) << (c*8);
    }
    wds[i] = wd;
  }
  int4v pk; pk[0]=(int)wds[0]; pk[1]=(int)wds[1]; pk[2]=(int)wds[2]; pk[3]=(int)wds[3];
  *(int4v*)(outp + (size_t)row*1024 + l*16) = pk;
}

// ---------------- rownorm f32 -> i8 + per-row scale ------------------------
__global__ __launch_bounds__(256) void k_rownorm_f32_i8(const float* __restrict__ in,
        int8_t* __restrict__ outp, float* __restrict__ sca){
  int w = threadIdx.x >> 6, l = threadIdx.x & 63;
  int row = blockIdx.x*4 + w;
  const float* rp = in + (size_t)row*1024 + l*16;
  float f[16]; float s = 0.f, q = 0.f;
  #pragma unroll
  for (int i = 0; i < 4; ++i){
    float4 v = *(const float4*)(rp + i*4);
    f[i*4+0] = v.x; f[i*4+1] = v.y; f[i*4+2] = v.z; f[i*4+3] = v.w;
  }
  #pragma unroll
  for (int jj = 0; jj < 16; ++jj){ s += f[jj]; q += f[jj]*f[jj]; }
  wreduce2(s, q);
  float mean = s * (1.f/1024.f);
  float rstd = rsqrtf(q*(1.f/1024.f) - mean*mean + 1e-5f);
  float amax = 0.f;
  #pragma unroll
  for (int jj = 0; jj < 16; ++jj) amax = fmaxf(amax, fabsf(f[jj]-mean));
  #pragma unroll
  for (int d = 32; d; d >>= 1) amax = fmaxf(amax, __shfl_xor(amax, d));
  amax *= rstd;
  float inv = (amax > 0.f) ? 127.f/amax : 0.f;
  if (l == 0) sca[row] = amax * (1.f/127.f);
  uint32_t wds[4];
  #pragma unroll
  for (int i = 0; i < 4; ++i){
    uint32_t wd = 0;
    #pragma unroll
    for (int c = 0; c < 4; ++c){
      int qv = (int)rintf((f[i*4+c]-mean)*rstd*inv);
      wd |= ((uint32_t)(uint8_t)(int8_t)qv) << (c*8);
    }
    wds[i] = wd;
  }
  int4v pk; pk[0]=(int)wds[0]; pk[1]=(int)wds[1]; pk[2]=(int)wds[2]; pk[3]=(int)wds[3];
  *(int4v*)(outp + (size_t)row*1024 + l*16) = pk;
}

// ---------------- bf16 rows -> i8 + per-row scale (no norm) ----------------
// PER = K/64 elements per lane (16 -> K=1024, 32 -> K=2048).
template<int PER>
__global__ __launch_bounds__(256) void k_quant_rows(const ushort_t* __restrict__ in,
        int8_t* __restrict__ outp, float* __restrict__ sca){
  const int K = PER*64;
  int w = threadIdx.x >> 6, l = threadIdx.x & 63;
  int row = blockIdx.x*4 + w;
  const ushort_t* rp = in + (size_t)row*K + l*PER;
  float f[PER];
  #pragma unroll
  for (int i = 0; i < PER/4; ++i){
    ushort4v u = *(const ushort4v*)(rp + i*4);
    f[i*4+0] = bf2f(u.x); f[i*4+1] = bf2f(u.y);
    f[i*4+2] = bf2f(u.z); f[i*4+3] = bf2f(u.w);
  }
  float amax = 0.f;
  #pragma unroll
  for (int jj = 0; jj < PER; ++jj) amax = fmaxf(amax, fabsf(f[jj]));
  #pragma unroll
  for (int d = 32; d; d >>= 1) amax = fmaxf(amax, __shfl_xor(amax, d));
  float inv = (amax > 0.f) ? 127.f/amax : 0.f;
  if (l == 0) sca[row] = amax * (1.f/127.f);
  #pragma unroll
  for (int vq = 0; vq < PER/16; ++vq){
    int4v pk;
    #pragma unroll
    for (int i = 0; i < 4; ++i){
      uint32_t wd = 0;
      #pragma unroll
      for (int c = 0; c < 4; ++c){
        int qv = (int)rintf(f[vq*16 + i*4 + c]*inv);
        wd |= ((uint32_t)(uint8_t)(int8_t)qv) << (c*8);
      }
      pk[i] = (int)wd;
    }
    *(int4v*)(outp + (size_t)row*K + l*PER + vq*16) = pk;
  }
}

// ---------------- final layernorm (affine) f32 -> f32 ----------------------
__global__ __launch_bounds__(256) void k_final_ln(const float* __restrict__ x,
        const float* __restrict__ g, const float* __restrict__ bb, float* __restrict__ outp){
  int w = threadIdx.x >> 6, l = threadIdx.x & 63;
  int row = blockIdx.x*4 + w;
  const float* rp = x + (size_t)row*1024;
  float4 v[4]; float s = 0.f, q = 0.f;
  #pragma unroll
  for (int i = 0; i < 4; ++i){
    v[i] = *(const float4*)(rp + i*256 + l*4);
    s += v[i].x+v[i].y+v[i].z+v[i].w;
    q += v[i].x*v[i].x+v[i].y*v[i].y+v[i].z*v[i].z+v[i].w*v[i].w;
  }
  wreduce2(s, q);
  float mean = s * (1.f/1024.f);
  float rstd = rsqrtf(q*(1.f/1024.f) - mean*mean + 1e-5f);
  float* op = outp + (size_t)row*1024;
  #pragma unroll
  for (int i = 0; i < 4; ++i){
    float4 gg = *(const float4*)(g + i*256 + l*4);
    float4 bv = *(const float4*)(bb + i*256 + l*4);
    float4 o;
    o.x = (v[i].x-mean)*rstd*gg.x + bv.x; o.y = (v[i].y-mean)*rstd*gg.y + bv.y;
    o.z = (v[i].z-mean)*rstd*gg.z + bv.z; o.w = (v[i].w-mean)*rstd*gg.w + bv.w;
    *(float4*)(op + i*256 + l*4) = o;
  }
}

// ---------------- x init ----------------------------------------------------
__global__ __launch_bounds__(256) void k_init_x(const float* __restrict__ lat, float* __restrict__ x){
  int v = blockIdx.x*256 + threadIdx.x;
  int row = v >> 8, cv = v & 255;
  ((float4*)x)[v] = ((const float4*)lat)[(row & 63)*256 + cv];
}

// ---------------- batched weight fold + transpose --------------------------
DEV void foldT_body(const float* __restrict__ W, const float* __restrict__ g,
                    float scale, ushort_t* __restrict__ Wt, int K, int N,
                    int n0, int k0){
  __shared__ float Ts[64][65];
  int t = threadIdx.x;
  #pragma unroll
  for (int i = 0; i < 4; ++i){
    int flat = i*1024 + t*4; int r = flat >> 6, c = flat & 63;
    float4 v = *(const float4*)(W + (size_t)(k0+r)*N + n0 + c);
    float gg = (g ? g[k0+r] : 1.f) * scale;
    Ts[r][c] = v.x*gg; Ts[r][c+1] = v.y*gg; Ts[r][c+2] = v.z*gg; Ts[r][c+3] = v.w*gg;
  }
  __syncthreads();
  #pragma unroll
  for (int i = 0; i < 4; ++i){
    int flat = i*1024 + t*4; int rn = flat >> 6, ck = flat & 63;
    ushort4v o;
    o.x = f2bf(Ts[ck][rn]);   o.y = f2bf(Ts[ck+1][rn]);
    o.z = f2bf(Ts[ck+2][rn]); o.w = f2bf(Ts[ck+3][rn]);
    *(ushort4v*)(Wt + (size_t)(n0+rn)*K + k0 + ck) = o;
  }
}

struct FDesc { const float* W; const float* g; ushort_t* dst; float scale; int K; int N; };
#define MAXFD 32
struct FoldTArgs { int cnt; FDesc d[MAXFD]; };

__global__ __launch_bounds__(256) void k_foldT_all(FoldTArgs a){
  const FDesc d = a.d[blockIdx.y];
  int nxb = d.N >> 6;
  int n0 = (blockIdx.x % nxb) * 64;
  int k0 = (blockIdx.x / nxb) * 64;
  if (k0 >= d.K) return;
  foldT_body(d.W, d.g, d.scale, d.dst, d.K, d.N, n0, k0);
}

// ---------------- batched bias fold ----------------------------------------
DEV void foldBias_body(const float* __restrict__ W, const float* __restrict__ bvec,
                       float scale, float* __restrict__ bias, int K, int N, int o0){
  int t = threadIdx.x;
  int ol = t & 31, kc = t >> 5;
  int o = o0 + ol;
  int chunk = K >> 3;
  int c0 = kc*chunk, c1 = c0 + chunk;
  float s0 = 0, s1 = 0, s2 = 0, s3 = 0;
  for (int c = c0; c < c1; c += 4){
    s0 += bvec[c+0]*W[(size_t)(c+0)*N + o];
    s1 += bvec[c+1]*W[(size_t)(c+1)*N + o];
    s2 += bvec[c+2]*W[(size_t)(c+2)*N + o];
    s3 += bvec[c+3]*W[(size_t)(c+3)*N + o];
  }
  __shared__ float red[8][32];
  red[kc][ol] = (s0+s1)+(s2+s3);
  __syncthreads();
  if (kc == 0){
    float tot = 0;
    #pragma unroll
    for (int jj = 0; jj < 8; ++jj) tot += red[jj][ol];
    bias[o] = tot * scale;
  }
}

struct BDesc { const float* W; const float* b; float* dst; float scale; int K; int N; };
#define MAXBD 25
struct BiasArgs { int cnt; BDesc d[MAXBD]; };

__global__ __launch_bounds__(256) void k_foldBias_all(BiasArgs a){
  const BDesc d = a.d[blockIdx.y];
  int o0 = blockIdx.x * 32;
  if (o0 >= d.N) return;
  foldBias_body(d.W, d.b, d.scale, d.dst, d.K, d.N, o0);
}

// ---------------- 128x128 2-phase i8 GEMM (small shapes) -------------------
// Byte-layout mirrors the validated bf16 128x128 kernel: 64B K-windows,
// 16B lane chunks; each window = one mfma_i32_16x16x64_i8 (K=64 i8).
// OUTMODE: 0 = bf16 store, 1 = bf16 relu store, 2 = f32 accumulate.
template<int OUTMODE>
__global__ __launch_bounds__(256, 4) void k_gemm128i8(const int8_t* __restrict__ A,
        const int8_t* __restrict__ Bt, const float* __restrict__ sAr,
        const float* __restrict__ sBr, const float* __restrict__ bias,
        void* __restrict__ Cp, int M, int N, int Kb){
  const int n0 = blockIdx.x * 128;
  const int m0 = blockIdx.y * 128;
  __shared__ __align__(16) char sA[2][128*64];
  __shared__ __align__(16) char sB[2][128*64];
  const int tid = threadIdx.x;
  const int wave = tid >> 6, lane = tid & 63;
  const int lo = lane & 15, hi = lane >> 4;
  const int wr = wave >> 1, wc = wave & 1;

  auto stage = [&](int buf, int k0){            // k0 in BYTES
    #pragma unroll
    for (int p = 0; p < 2; ++p){
      int r = p*64 + wave*16 + (lane >> 2);
      int c = lane & 3;
      {
        const int8_t* gp = A + (size_t)(m0 + r)*Kb + k0 + c*16;
        char* lp = (char*)(&sA[buf][0]) + p*4096 + wave*1024;
        GLOAD16(gp, lp);
      }
      {
        const int8_t* gp = Bt + (size_t)(n0 + r)*Kb + k0 + c*16;
        char* lp = (char*)(&sB[buf][0]) + p*4096 + wave*1024;
        GLOAD16(gp, lp);
      }
    }
  };

  int4v acc[4][4] = {};
  stage(0, 0);
  const int nk = Kb >> 6;
  for (int ks = 0; ks < nk; ++ks){
    __syncthreads();
    if (ks + 1 < nk) stage((ks+1)&1, (ks+1) << 6);
    const int buf = ks & 1;
    int4v af[4], bfr[4];
    #pragma unroll
    for (int mi = 0; mi < 4; ++mi)
      af[mi] = *(const int4v*)(&sA[buf][(wr*64 + mi*16 + lo)*64 + hi*16]);
    #pragma unroll
    for (int ni = 0; ni < 4; ++ni)
      bfr[ni] = *(const int4v*)(&sB[buf][(wc*64 + ni*16 + lo)*64 + hi*16]);
    #pragma unroll
    for (int mi = 0; mi < 4; ++mi)
      #pragma unroll
      for (int ni = 0; ni < 4; ++ni)
        acc[mi][ni] = MFMAI8(af[mi], bfr[ni], acc[mi][ni]);
  }
  #pragma unroll
  for (int ni = 0; ni < 4; ++ni){
    int col = n0 + wc*64 + ni*16 + lo;
    float bv = bias ? bias[col] : 0.f;
    float sb = sBr[col];
    #pragma unroll
    for (int mi = 0; mi < 4; ++mi){
      int rbase = m0 + wr*64 + mi*16 + hi*4;
      #pragma unroll
      for (int rr = 0; rr < 4; ++rr){
        int row = rbase + rr;
        float v = (float)acc[mi][ni][rr] * (sAr[row]*sb) + bv;
        size_t off = (size_t)row*N + col;
        if (OUTMODE == 0)      ((ushort_t*)Cp)[off] = f2bf(v);
        else if (OUTMODE == 1) ((ushort_t*)Cp)[off] = f2bf(fmaxf(v, 0.f));
        else                   ((float*)Cp)[off] += v;
      }
    }
  }
}

// ---------------- 256x256 8-phase bf16 GEMM (down-proj) --------------------
template<bool SKIP, int NXB>
__global__ __launch_bounds__(512, 2) void k_gemm256p8(const ushort_t* __restrict__ A,
        const ushort_t* __restrict__ Bt, const float* __restrict__ bias,
        ushort_t* __restrict__ Cp, int M, int N, int K, const int* __restrict__ cnt){
  int bx, by;
  xcd_remapN<NXB>(blockIdx.x, gridDim.x, bx, by);
  const int n0 = bx * 256;
  const int m0 = by * 256;
  if (SKIP){ int b = m0 >> 11; if ((m0 & 2047) >= cnt[b]) return; }
  __shared__ __align__(16) ushort_t sA[2][256*64];
  __shared__ __align__(16) ushort_t sB[2][256*64];
  const int tid = threadIdx.x;
  const int wave = tid >> 6, lane = tid & 63;
  const int lo = lane & 15, hi = lane >> 4;
  const int wm = wave >> 2, wn = wave & 3;
  const int srow = lane >> 3;
  const int schunk = (lane & 7) ^ srow;
  auto stageHalf = [&](ushort_t* dst, const ushort_t* __restrict__ G, int grow0,
                       int half, int k0){
    #pragma unroll
    for (int p = 0; p < 2; ++p){
      int rbase = half*128 + p*64 + wave*8;
      const ushort_t* gp = G + (size_t)(grow0 + rbase + srow)*K + k0 + schunk*8;
      char* lp = (char*)dst + (size_t)rbase*128;
      GLOAD16(gp, lp);
    }
  };
  auto ldsA = [&](int buf, int row, int kk)->short8{
    int ch = ((kk<<2) + hi) ^ (row & 7);
    return *(const short8*)((const char*)sA + (size_t)buf*32768 + (size_t)row*128 + ch*16);
  };
  auto ldsB = [&](int buf, int row, int kk)->short8{
    int ch = ((kk<<2) + hi) ^ (row & 7);
    return *(const short8*)((const char*)sB + (size_t)buf*32768 + (size_t)row*128 + ch*16);
  };
  f32x4 acc[8][4] = {};

  short8 af[4][2], bg[2][2];
#define LOADA(BUF, AH) \
    _Pragma("unroll") for (int mi_ = 0; mi_ < 4; ++mi_) \
      _Pragma("unroll") for (int kk_ = 0; kk_ < 2; ++kk_) \
        af[mi_][kk_] = ldsA(BUF, (AH)*128 + wm*64 + mi_*16 + lo, kk_);
#define LOADB(BUF, BH) \
    _Pragma("unroll") for (int nj_ = 0; nj_ < 2; ++nj_) \
      _Pragma("unroll") for (int kk_ = 0; kk_ < 2; ++kk_) \
        bg[nj_][kk_] = ldsB(BUF, (BH)*128 + wn*32 + nj_*16 + lo, kk_);
#define MMQ(AH, BH) \
    __builtin_amdgcn_s_barrier(); CFENCE; \
    __builtin_amdgcn_s_setprio(1); \
    _Pragma("unroll") for (int mi_ = 0; mi_ < 4; ++mi_) \
      _Pragma("unroll") for (int nj_ = 0; nj_ < 2; ++nj_) \
        _Pragma("unroll") for (int kk_ = 0; kk_ < 2; ++kk_) \
          acc[(AH)*4+mi_][(BH)*2+nj_] = \
            MFMA16(af[mi_][kk_], bg[nj_][kk_], acc[(AH)*4+mi_][(BH)*2+nj_]); \
    __builtin_amdgcn_s_setprio(0); CFENCE; \
    __builtin_amdgcn_s_barrier(); CFENCE;

  stageHalf(&sA[0][0], A,  m0, 0, 0);
  stageHalf(&sB[0][0], Bt, n0, 0, 0);
  stageHalf(&sA[0][0], A,  m0, 1, 0);
  stageHalf(&sB[0][0], Bt, n0, 1, 0);
  stageHalf(&sA[1][0], A,  m0, 0, 64);
  stageHalf(&sB[1][0], Bt, n0, 1, 64);
  VMCNT(4);
  __builtin_amdgcn_s_barrier();
  CFENCE;

  const int NI = K >> 7;
  for (int i = 0; i < NI; ++i){
    const int kt = i << 7;
    const bool lastI = (i == NI-1);
    LOADA(0,0) LOADB(0,0)
    stageHalf(&sA[1][0], A,  m0, 1, kt+64);
    MMQ(0,0)
    LOADB(0,1)
    stageHalf(&sB[1][0], Bt, n0, 0, kt+64);
    MMQ(0,1)
    LOADA(0,1)
    if (!lastI) stageHalf(&sA[0][0], A,  m0, 0, kt+128);
    MMQ(1,1)
    LOADB(0,0)
    if (!lastI) stageHalf(&sB[0][0], Bt, n0, 1, kt+128);
    if (lastI){ VMCNT(0); } else { VMCNT(4); }
    MMQ(1,0)
    LOADA(1,0) LOADB(1,0)
    if (!lastI) stageHalf(&sA[0][0], A,  m0, 1, kt+128);
    MMQ(0,0)
    LOADB(1,1)
    if (!lastI) stageHalf(&sB[0][0], Bt, n0, 0, kt+128);
    MMQ(0,1)
    LOADA(1,1)
    if (!lastI) stageHalf(&sA[1][0], A,  m0, 0, kt+192);
    MMQ(1,1)
    LOADB(1,0)
    if (!lastI){ stageHalf(&sB[1][0], Bt, n0, 1, kt+192); VMCNT(4); }
    MMQ(1,0)
  }
#undef LOADA
#undef LOADB
#undef MMQ

  #pragma unroll
  for (int b2 = 0; b2 < 2; ++b2)
    #pragma unroll
    for (int nj = 0; nj < 2; ++nj){
      int col = n0 + b2*128 + wn*32 + nj*16 + lo;
      float bv = bias ? bias[col] : 0.f;
      #pragma unroll
      for (int a2 = 0; a2 < 2; ++a2)
        #pragma unroll
        for (int mi4 = 0; mi4 < 4; ++mi4){
          int rbase = m0 + a2*128 + wm*64 + mi4*16 + hi*4;
          #pragma unroll
          for (int rr = 0; rr < 4; ++rr){
            float v = acc[a2*4+mi4][b2*2+nj][rr] + bv;
            Cp[(size_t)(rbase + rr)*N + col] = f2bf(v);
          }
        }
    }
}

// ---------------- 256x256 8-phase i8 GEMM (KV projections) -----------------
template<bool SKIP, int NXB>
__global__ __launch_bounds__(512, 2) void k_gemm256i8(const int8_t* __restrict__ A,
        const int8_t* __restrict__ Bt, const float* __restrict__ sAr,
        const float* __restrict__ sBr, const float* __restrict__ bias,
        ushort_t* __restrict__ Cp, int M, int N, int Kb, const int* __restrict__ cnt){
  int bx, by;
  xcd_remapN<NXB>(blockIdx.x, gridDim.x, bx, by);
  const int n0 = bx * 256;
  const int m0 = by * 256;
  if (SKIP){ int b = m0 >> 11; if ((m0 & 2047) >= cnt[b]) return; }
  __shared__ __align__(16) char sAl[2][256*128];
  __shared__ __align__(16) char sBl[2][256*128];
  const int tid = threadIdx.x;
  const int wave = tid >> 6, lane = tid & 63;
  const int lo = lane & 15, hi = lane >> 4;
  const int wm = wave >> 2, wn = wave & 3;
  const int srow = lane >> 3;
  const int schunk = (lane & 7) ^ srow;
  auto stageHalf = [&](char* dst, const int8_t* __restrict__ G, int grow0,
                       int half, int k0){            // k0 in BYTES
    #pragma unroll
    for (int p = 0; p < 2; ++p){
      int rbase = half*128 + p*64 + wave*8;
      const int8_t* gp = G + (size_t)(grow0 + rbase + srow)*Kb + k0 + schunk*16;
      char* lp = dst + (size_t)rbase*128;
      GLOAD16(gp, lp);
    }
  };
  auto ldsA = [&](int buf, int row, int kk)->int4v{
    int ch = ((kk<<2) + hi) ^ (row & 7);
    return *(const int4v*)((const char*)sAl + (size_t)buf*32768 + (size_t)row*128 + ch*16);
  };
  auto ldsB = [&](int buf, int row, int kk)->int4v{
    int ch = ((kk<<2) + hi) ^ (row & 7);
    return *(const int4v*)((const char*)sBl + (size_t)buf*32768 + (size_t)row*128 + ch*16);
  };
  int4v acc[8][4] = {};

  int4v af[4][2], bg[2][2];
#define LOADA(BUF, AH) \
    _Pragma("unroll") for (int mi_ = 0; mi_ < 4; ++mi_) \
      _Pragma("unroll") for (int kk_ = 0; kk_ < 2; ++kk_) \
        af[mi_][kk_] = ldsA(BUF, (AH)*128 + wm*64 + mi_*16 + lo, kk_);
#define LOADB(BUF, BH) \
    _Pragma("unroll") for (int nj_ = 0; nj_ < 2; ++nj_) \
      _Pragma("unroll") for (int kk_ = 0; kk_ < 2; ++kk_) \
        bg[nj_][kk_] = ldsB(BUF, (BH)*128 + wn*32 + nj_*16 + lo, kk_);
#define MMQ(AH, BH) \
    __builtin_amdgcn_s_barrier(); CFENCE; \
    __builtin_amdgcn_s_setprio(1); \
    _Pragma("unroll") for (int mi_ = 0; mi_ < 4; ++mi_) \
      _Pragma("unroll") for (int nj_ = 0; nj_ < 2; ++nj_) \
        _Pragma("unroll") for (int kk_ = 0; kk_ < 2; ++kk_) \
          acc[(AH)*4+mi_][(BH)*2+nj_] = \
            MFMAI8(af[mi_][kk_], bg[nj_][kk_], acc[(AH)*4+mi_][(BH)*2+nj_]); \
    __builtin_amdgcn_s_setprio(0); CFENCE; \
    __builtin_amdgcn_s_barrier(); CFENCE;

  stageHalf(&sAl[0][0], A,  m0, 0, 0);
  stageHalf(&sBl[0][0], Bt, n0, 0, 0);
  stageHalf(&sAl[0][0], A,  m0, 1, 0);
  stageHalf(&sBl[0][0], Bt, n0, 1, 0);
  stageHalf(&sAl[1][0], A,  m0, 0, 128);
  stageHalf(&sBl[1][0], Bt, n0, 1, 128);
  VMCNT(4);
  __builtin_amdgcn_s_barrier();
  CFENCE;

  const int NI = Kb >> 8;
  for (int i = 0; i < NI; ++i){
    const int kt = i << 8;
    const bool lastI = (i == NI-1);
    LOADA(0,0) LOADB(0,0)
    stageHalf(&sAl[1][0], A,  m0, 1, kt+128);
    MMQ(0,0)
    LOADB(0,1)
    stageHalf(&sBl[1][0], Bt, n0, 0, kt+128);
    MMQ(0,1)
    LOADA(0,1)
    if (!lastI) stageHalf(&sAl[0][0], A,  m0, 0, kt+256);
    MMQ(1,1)
    LOADB(0,0)
    if (!lastI) stageHalf(&sBl[0][0], Bt, n0, 1, kt+256);
    if (lastI){ VMCNT(0); } else { VMCNT(4); }
    MMQ(1,0)
    LOADA(1,0) LOADB(1,0)
    if (!lastI) stageHalf(&sAl[0][0], A,  m0, 1, kt+256);
    MMQ(0,0)
    LOADB(1,1)
    if (!lastI) stageHalf(&sBl[0][0], Bt, n0, 0, kt+256);
    MMQ(0,1)
    LOADA(1,1)
    if (!lastI) stageHalf(&sAl[1][0], A,  m0, 0, kt+384);
    MMQ(1,1)
    LOADB(1,0)
    if (!lastI){ stageHalf(&sBl[1][0], Bt, n0, 1, kt+384); VMCNT(4); }
    MMQ(1,0)
  }
#undef LOADA
#undef LOADB
#undef MMQ

  #pragma unroll
  for (int b2 = 0; b2 < 2; ++b2)
    #pragma unroll
    for (int nj = 0; nj < 2; ++nj){
      int col = n0 + b2*128 + wn*32 + nj*16 + lo;
      float bv = bias ? bias[col] : 0.f;
      float sb = sBr[col];
      #pragma unroll
      for (int a2 = 0; a2 < 2; ++a2)
        #pragma unroll
        for (int mi4 = 0; mi4 < 4; ++mi4){
          int rbase = m0 + a2*128 + wm*64 + mi4*16 + hi*4;
          #pragma unroll
          for (int rr = 0; rr < 4; ++rr){
            int row = rbase + rr;
            float v = (float)acc[a2*4+mi4][b2*2+nj][rr] * (sAr[row]*sb) + bv;
            Cp[(size_t)row*N + col] = f2bf(v);
          }
        }
    }
}

// ---------------- flash attention (pipelined): one block per (b,h) ---------
__global__ __launch_bounds__(256) void k_attn(const ushort_t* __restrict__ qb,
        const ushort_t* __restrict__ kvb, int kstride, const int* __restrict__ cnt,
        ushort_t* __restrict__ outb){
  const int bh = blockIdx.x;
  const int b = bh >> 4, h = bh & 15;
  const int t = threadIdx.x;
  const int wave = t >> 6, lane = t & 63, lo = lane & 15, hi = lane >> 4;
  __shared__ ushort_t Qs[64*64];
  __shared__ ushort_t Ks[2][64*64];
  __shared__ ushort_t Vt[2][64][72];
  __shared__ ushort_t Ps[4][16][72];

  const int count = cnt[b];

  #pragma unroll
  for (int p = 0; p < 2; ++p){
    int r = p*32 + wave*8 + (lane >> 3);
    int c = (lane & 7) ^ (r & 7);
    const ushort_t* gp = qb + (size_t)(b*64 + r)*1024 + h*64 + c*8;
    char* lp = (char*)Qs + p*4096 + wave*1024;
    GLOAD16(gp, lp);
  }

  auto stageK = [&](int buf, int tt){
    #pragma unroll
    for (int p = 0; p < 2; ++p){
      int r = p*32 + wave*8 + (lane >> 3);
      int c = (lane & 7) ^ (r & 7);
      const ushort_t* gp = kvb + (size_t)(b*2048 + tt*64 + r)*kstride + h*64 + c*8;
      char* lp = (char*)(&Ks[buf][0]) + p*4096 + wave*1024;
      GLOAD16(gp, lp);
    }
  };
  const int vjj = (t & 31)*2, vc = (t >> 5)*8;
  ushort4v va0, va1, vb0, vb1;
  auto issueV = [&](int tt){
    const ushort_t* g0 = kvb + (size_t)(b*2048 + tt*64 + vjj)*kstride + 1024 + h*64 + vc;
    va0 = *(const ushort4v*)(g0);
    va1 = *(const ushort4v*)(g0 + 4);
    vb0 = *(const ushort4v*)(g0 + kstride);
    vb1 = *(const ushort4v*)(g0 + kstride + 4);
  };
  auto writeV = [&](int buf, int tt){
    bool va  = (tt*64 + vjj)     < count;
    bool vb2 = (tt*64 + vjj + 1) < count;
    #pragma unroll
    for (int u = 0; u < 8; ++u){
      ushort_t ea = (u < 4) ? ((ushort_t*)&va0)[u] : ((ushort_t*)&va1)[u-4];
      ushort_t eb = (u < 4) ? ((ushort_t*)&vb0)[u] : ((ushort_t*)&vb1)[u-4];
      uint32_t word = (va ? (uint32_t)ea : 0u) | ((vb2 ? (uint32_t)eb : 0u) << 16);
      *(uint32_t*)(&Vt[buf][vc+u][vjj]) = word;
    }
  };

  f32x4 oacc[4] = {};
  float m[4], l[4];
  #pragma unroll
  for (int rr = 0; rr < 4; ++rr){ m[rr] = -__builtin_inff(); l[rr] = 0.f; }

  const int ntiles = (count + 63) >> 6;
  if (ntiles > 0){ stageK(0, 0); issueV(0); }

  for (int tt = 0; tt < ntiles; ++tt){
    const int buf = tt & 1;
    writeV(buf, tt);
    if (tt + 1 < ntiles){ stageK(buf^1, tt+1); issueV(tt+1); }
    asm volatile("s_waitcnt lgkmcnt(0)" ::: "memory");
    __builtin_amdgcn_s_barrier();
    CFENCE;

    f32x4 s[4] = {};
    #pragma unroll
    for (int kk = 0; kk < 2; ++kk){
      int rA = wave*16 + lo;
      short8 aq = *(const short8*)(&Qs[rA*64 + (((kk*4 + hi) ^ (rA & 7))*8)]);
      #pragma unroll
      for (int ni = 0; ni < 4; ++ni){
        int rB = ni*16 + lo;
        short8 bk = *(const short8*)(&Ks[buf][rB*64 + (((kk*4 + hi) ^ (rB & 7))*8)]);
        s[ni] = MFMA16(aq, bk, s[ni]);
      }
    }
    #pragma unroll
    for (int ni = 0; ni < 4; ++ni){
      if (tt*64 + ni*16 + lo >= count){
        s[ni][0] = s[ni][1] = s[ni][2] = s[ni][3] = -__builtin_inff();
      }
    }
    float p[4][4];
    #pragma unroll
    for (int rr = 0; rr < 4; ++rr){
      float mx = fmaxf(fmaxf(s[0][rr], s[1][rr]), fmaxf(s[2][rr], s[3][rr]));
      #pragma unroll
      for (int d = 1; d < 16; d <<= 1) mx = fmaxf(mx, __shfl_xor(mx, d));
      float mnew = fmaxf(m[rr], mx);
      float sc = __expf(m[rr] - mnew);
      float rsum = 0.f;
      #pragma unroll
      for (int ni = 0; ni < 4; ++ni){
        float pv = __expf(s[ni][rr] - mnew);
        p[ni][rr] = pv;
        rsum += pv;
      }
      #pragma unroll
      for (int d = 1; d < 16; d <<= 1) rsum += __shfl_xor(rsum, d);
      l[rr] = l[rr]*sc + rsum;
      m[rr] = mnew;
      #pragma unroll
      for (int ni = 0; ni < 4; ++ni) oacc[ni][rr] *= sc;
    }
    #pragma unroll
    for (int ni = 0; ni < 4; ++ni)
      #pragma unroll
      for (int rr = 0; rr < 4; ++rr)
        Ps[wave][hi*4+rr][ni*16+lo] = f2bf(p[ni][rr]);
    asm volatile("s_waitcnt lgkmcnt(0)" ::: "memory");
    #pragma unroll
    for (int kk = 0; kk < 2; ++kk){
      short8 pa = *(const short8*)(&Ps[wave][lo][kk*32 + hi*8]);
      #pragma unroll
      for (int ni = 0; ni < 4; ++ni){
        short8 bv = *(const short8*)(&Vt[buf][ni*16 + lo][kk*32 + hi*8]);
        oacc[ni] = MFMA16(pa, bv, oacc[ni]);
      }
    }
    CFENCE;
    __builtin_amdgcn_s_barrier();
    CFENCE;
  }
  #pragma unroll
  for (int rr = 0; rr < 4; ++rr){
    float inv = (l[rr] > 0.f) ? 1.f/l[rr] : 0.f;
    #pragma unroll
    for (int ni = 0; ni < 4; ++ni){
      size_t off = (size_t)(b*64 + wave*16 + hi*4 + rr)*1024 + h*64 + ni*16 + lo;
      outb[off] = f2bf(oacc[ni][rr] * inv);
    }
  }
}

// ---------------------------------------------------------------------------
extern "C" void kernel_launch(void* const* d_in, const int* in_sizes, int n_in,
                              void* d_out, int out_size, void* d_ws, size_t ws_size,
                              hipStream_t stream){
  const float* features = (const float*)d_in[0];
  const int*   mask     = (const int*)  d_in[1];
  const float* latents  = (const float*)d_in[2];
  const float* W_down   = (const float*)d_in[3];
  const float* nin_g    = (const float*)d_in[4];
  const float* nin_b    = (const float*)d_in[5];
  const float* lf_g     = (const float*)d_in[6];
  const float* lf_b     = (const float*)d_in[7];
  const float* ll_g     = (const float*)d_in[8];
  const float* ll_b     = (const float*)d_in[9];
  const float* Wq       = (const float*)d_in[10];
  const float* Wk       = (const float*)d_in[11];
  const float* Wv       = (const float*)d_in[12];
  const float* ffln_g   = (const float*)d_in[13];
  const float* ffln_b   = (const float*)d_in[14];
  const float* ff_w1    = (const float*)d_in[15];
  const float* ff_w2    = (const float*)d_in[16];
  const float* nout_g   = (const float*)d_in[17];
  const float* nout_b   = (const float*)d_in[18];

  char* ws = (char*)d_ws;
  size_t off = 0;
  auto alloc = [&](size_t bytes)->char*{
    char* p = ws + off;
    off += (bytes + 255) & ~(size_t)255;
    return p;
  };
  const size_t SZW = (size_t)1024*1024*2;       // 2 MB (1024x1024 bf16)

  ushort_t* FHAT  = (ushort_t*)alloc((size_t)65536*1024*2);   // down-proj out
  int8_t*   I8A   = (int8_t*)  alloc((size_t)65536*1024);     // LN'd fhat, i8
  float*    SA    = (float*)   alloc((size_t)65536*4);
  int8_t*   I8KV  = (int8_t*)  alloc((size_t)12288*1024);     // KV weights i8
  float*    SKV   = (float*)   alloc((size_t)12288*4);
  int8_t*   I8Q   = (int8_t*)  alloc((size_t)6144*1024);      // Q weights i8
  float*    SQW   = (float*)   alloc((size_t)6144*4);
  int8_t*   I8W1  = (int8_t*)  alloc((size_t)12288*1024);     // FF1 weights i8
  float*    SW1   = (float*)   alloc((size_t)12288*4);
  int8_t*   I8W2  = (int8_t*)  alloc((size_t)6144*2048);      // FF2 weights i8 (K=2048)
  float*    SW2   = (float*)   alloc((size_t)6144*4);
  ushort_t* WDT   = (ushort_t*)alloc(SZW);
  ushort_t* WQT6  = (ushort_t*)alloc(SZW*6);
  ushort_t* WKVT6 = (ushort_t*)alloc(SZW*2*6);
  ushort_t* W1T6  = (ushort_t*)alloc(SZW*2*6);
  ushort_t* W2T6  = (ushort_t*)alloc(SZW*2*6);
  float* BD   = (float*)alloc(1024*4);
  float* BQ6  = (float*)alloc(1024*4*6);
  float* BKV6 = (float*)alloc(2048*4*6);
  float* B16  = (float*)alloc(2048*4*6);
  float*    X    = (float*)   alloc((size_t)2048*1024*4);
  int8_t*   I8X  = (int8_t*)  alloc((size_t)2048*1024);
  float*    SX   = (float*)   alloc((size_t)2048*4);
  ushort_t* QP   = (ushort_t*)alloc((size_t)2048*1024*2);
  ushort_t* OUTB = (ushort_t*)alloc((size_t)2048*1024*2);
  int8_t*   I8O  = (int8_t*)  alloc((size_t)2048*1024);
  float*    SO   = (float*)   alloc((size_t)2048*4);
  ushort_t* H1   = (ushort_t*)alloc((size_t)2048*2048*2);
  int8_t*   I8H  = (int8_t*)  alloc((size_t)2048*2048);
  float*    SH   = (float*)   alloc((size_t)2048*4);
  int* CNT = (int*)alloc(32*4);
  int* IDX = (int*)alloc((size_t)65536*4);
  ushort_t* KVBUF = (ushort_t*)alloc((size_t)65536*2048*2);   // 256 MB
  ushort_t* FNORM = KVBUF;   // transient alias (dead before KV GEMM writes)
  (void)in_sizes; (void)n_in; (void)out_size; (void)ws_size;

  const float scale = 0.125f;  // DH^-0.5

  // ---- batched weight folds (all depth-independent) ----
  FoldTArgs fa; int nf = 0;
  auto addF = [&](const float* W, const float* g, float sc, ushort_t* dst, int K, int N){
    fa.d[nf++] = FDesc{W, g, dst, sc, K, N};
  };
  addF(W_down, nin_g, 1.f, WDT, 1024, 1024);
  for (int i = 0; i < 6; ++i){
    const float* Wqi = Wq + (size_t)i*1024*1024;
    const float* Wki = Wk + (size_t)i*1024*1024;
    const float* Wvi = Wv + (size_t)i*1024*1024;
    const float* W1i = ff_w1 + (size_t)i*1024*2048;
    const float* W2i = ff_w2 + (size_t)i*2048*1024;
    addF(Wqi, ll_g + i*1024, scale, WQT6  + i*(SZW/2),        1024, 1024);
    addF(Wki, lf_g + i*1024, 1.f,   WKVT6 + i*SZW,            1024, 1024);
    addF(Wvi, lf_g + i*1024, 1.f,   WKVT6 + i*SZW + (SZW/2),  1024, 1024);
    addF(W1i, ffln_g + i*1024, 1.f, W1T6  + i*SZW,            1024, 2048);
    addF(W2i, nullptr, 1.f,         W2T6  + i*SZW,            2048, 1024);
  }
  fa.cnt = nf;

  BiasArgs ba; int nb = 0;
  auto addB = [&](const float* W, const float* b, float sc, float* dst, int K, int N){
    ba.d[nb++] = BDesc{W, b, dst, sc, K, N};
  };
  addB(W_down, nin_b, 1.f, BD, 1024, 1024);
  for (int i = 0; i < 6; ++i){
    const float* Wqi = Wq + (size_t)i*1024*1024;
    const float* Wki = Wk + (size_t)i*1024*1024;
    const float* Wvi = Wv + (size_t)i*1024*1024;
    const float* W1i = ff_w1 + (size_t)i*1024*2048;
    addB(Wqi, ll_b + i*1024, scale, BQ6  + i*1024,        1024, 1024);
    addB(Wki, lf_b + i*1024, 1.f,   BKV6 + i*2048,        1024, 1024);
    addB(Wvi, lf_b + i*1024, 1.f,   BKV6 + i*2048 + 1024, 1024, 1024);
    addB(W1i, ffln_b + i*1024, 1.f, B16  + i*2048,        1024, 2048);
  }
  ba.cnt = nb;

  // ---- setup ----
  k_compact     <<<32,    256, 0, stream>>>(mask, IDX, CNT);
  k_gather_norm <<<16384, 256, 0, stream>>>(features, IDX, CNT, FNORM);
  k_foldT_all   <<<dim3(512, nf), 256, 0, stream>>>(fa);
  k_foldBias_all<<<dim3(64,  nb), 256, 0, stream>>>(ba);
  k_quant_rows<16><<<3072, 256, 0, stream>>>(WKVT6, I8KV, SKV);  // 12288 rows K=1024
  k_quant_rows<16><<<1536, 256, 0, stream>>>(WQT6,  I8Q,  SQW);  //  6144 rows K=1024
  k_quant_rows<16><<<3072, 256, 0, stream>>>(W1T6,  I8W1, SW1);  // 12288 rows K=1024
  k_quant_rows<32><<<1536, 256, 0, stream>>>(W2T6,  I8W2, SW2);  //  6144 rows K=2048
  k_gemm256p8<true,4><<<1024, 512, 0, stream>>>(FNORM, WDT, BD, FHAT, 65536, 1024, 1024, CNT);
  k_rownorm_i8  <<<16384, 256, 0, stream>>>(FHAT, I8A, SA, CNT);
  k_init_x      <<<2048,  256, 0, stream>>>(latents, X);

  for (int i = 0; i < 6; ++i){
    k_gemm256i8<true,8><<<2048, 512, 0, stream>>>(I8A, I8KV + (size_t)i*2048*1024,
                                                  SA, SKV + i*2048, BKV6 + i*2048,
                                                  KVBUF, 65536, 2048, 1024, CNT);
    k_rownorm_f32_i8<<<512, 256, 0, stream>>>(X, I8X, SX);
    k_gemm128i8<0><<<dim3(8,16), 256, 0, stream>>>(I8X, I8Q + (size_t)i*1024*1024,
                                                   SX, SQW + i*1024, BQ6 + i*1024,
                                                   QP, 2048, 1024, 1024);
    k_attn<<<512, 256, 0, stream>>>(QP, KVBUF, 2048, CNT, OUTB);
    k_rownorm_i8<<<512, 256, 0, stream>>>(OUTB, I8O, SO, nullptr);
    k_gemm128i8<1><<<dim3(16,16), 256, 0, stream>>>(I8O, I8W1 + (size_t)i*2048*1024,
                                                    SO, SW1 + i*2048, B16 + i*2048,
                                                    H1, 2048, 2048, 1024);
    k_quant_rows<32><<<512, 256, 0, stream>>>(H1, I8H, SH);
    k_gemm128i8<2><<<dim3(8,16), 256, 0, stream>>>(I8H, I8W2 + (size_t)i*1024*2048,
                                                   SH, SW2 + i*1024, nullptr,
                                                   X, 2048, 1024, 2048);
  }
  k_final_ln<<<512, 256, 0, stream>>>(X, nout_g, nout_b, (float*)d_out);
}

// Round 10
// 1640.976 us; speedup vs baseline: 2.0196x; 1.0868x over previous
//
#include <hip/hip_runtime.h>
#include <stdint.h>

// ---------------------------------------------------------------------------
// PerceiverResampler on MI355X (gfx950)
// B=32, F=2048, DIM=1024, INNER=1024, H=16, DH=64, Q=64, DEPTH=6, MULT=2
//
// Round 10: small GEMMs (Q/FF1/FF2) on 64-row i8 tiles -> 512 blocks (2/CU)
// instead of 128-256 (0.5-1/CU); latency-bound K-loops now interleave across
// two blocks per CU. Math bit-identical to R9 (i32 exact accumulate).
// ---------------------------------------------------------------------------

#define DEV static __device__ __forceinline__

typedef __attribute__((ext_vector_type(8))) short short8;
typedef __attribute__((ext_vector_type(4))) float f32x4;
typedef __attribute__((ext_vector_type(4))) int int4v;
typedef __attribute__((ext_vector_type(4))) unsigned short ushort4v;
typedef unsigned short ushort_t;

DEV float bf2f(ushort_t u){ union{uint32_t i; float f;} x; x.i = ((uint32_t)u)<<16; return x.f; }
DEV ushort_t f2bf(float f){
  union{float f; uint32_t i;} x; x.f = f;
  uint32_t r = x.i + 0x7fffu + ((x.i>>16)&1u);  // RNE
  return (ushort_t)(r>>16);
}

#define GLOAD16(gp, lp) __builtin_amdgcn_global_load_lds( \
    (const __attribute__((address_space(1))) uint32_t*)(gp), \
    (__attribute__((address_space(3))) uint32_t*)(lp), 16, 0, 0)

#define VMCNT(n) asm volatile("s_waitcnt vmcnt(" #n ")" ::: "memory")
#define CFENCE   asm volatile("" ::: "memory")
#define MFMA16(a,b,c) __builtin_amdgcn_mfma_f32_16x16x32_bf16(a,b,c,0,0,0)
#define MFMAI8(a,b,c) __builtin_amdgcn_mfma_i32_16x16x64_i8(a,b,c,0,0,0)

template<int NXB>
DEV void xcd_remapN(int g, int total, int& x, int& y){
  int xcd = g & 7;
  int k = g >> 3;
  int rows_per_xcd = (total / NXB) >> 3;
  y = xcd * rows_per_xcd + (k / NXB);
  x = k % NXB;
}

DEV void wreduce2(float& a, float& b){
  #pragma unroll
  for (int d = 32; d; d >>= 1){ a += __shfl_xor(a, d); b += __shfl_xor(b, d); }
}

// ---------------- mask compaction ------------------------------------------
__global__ __launch_bounds__(256) void k_compact(const int* __restrict__ mask,
                                                 int* __restrict__ idx, int* __restrict__ cnt){
  int b = blockIdx.x, t = threadIdx.x;
  const int* mb = mask + b*2048;
  int keep[8]; int c = 0;
  #pragma unroll
  for (int u = 0; u < 8; ++u){ keep[u] = (mb[t*8+u] != 0); c += keep[u]; }
  __shared__ int s[256];
  s[t] = c; __syncthreads();
  for (int off = 1; off < 256; off <<= 1){
    int v = (t >= off) ? s[t-off] : 0;
    __syncthreads();
    s[t] += v;
    __syncthreads();
  }
  int pos = s[t] - c;
  #pragma unroll
  for (int u = 0; u < 8; ++u) if (keep[u]) idx[b*2048 + pos++] = t*8 + u;
  if (t == 255) cnt[b] = s[255];
}

// ---------------- gather + rownorm features -> bf16 (wave-per-row) ---------
__global__ __launch_bounds__(256) void k_gather_norm(const float* __restrict__ feat,
        const int* __restrict__ idx, const int* __restrict__ cnt, ushort_t* __restrict__ outp){
  int w = threadIdx.x >> 6, l = threadIdx.x & 63;
  int row = blockIdx.x*4 + w;
  int b = row >> 11, j = row & 2047;
  if (j >= cnt[b]) return;
  int src = idx[b*2048 + j];
  const float* rp = feat + ((size_t)(b*2048 + src))*1024;
  float4 v[4]; float s = 0.f, q = 0.f;
  #pragma unroll
  for (int i = 0; i < 4; ++i){
    v[i] = *(const float4*)(rp + i*256 + l*4);
    s += v[i].x+v[i].y+v[i].z+v[i].w;
    q += v[i].x*v[i].x+v[i].y*v[i].y+v[i].z*v[i].z+v[i].w*v[i].w;
  }
  wreduce2(s, q);
  float mean = s * (1.f/1024.f);
  float rstd = rsqrtf(q*(1.f/1024.f) - mean*mean + 1e-5f);
  ushort_t* op = outp + (size_t)row*1024;
  #pragma unroll
  for (int i = 0; i < 4; ++i){
    ushort4v o;
    o.x = f2bf((v[i].x-mean)*rstd); o.y = f2bf((v[i].y-mean)*rstd);
    o.z = f2bf((v[i].z-mean)*rstd); o.w = f2bf((v[i].w-mean)*rstd);
    *(ushort4v*)(op + i*256 + l*4) = o;
  }
}

// ---------------- rownorm bf16 -> i8 + per-row scale (cnt nullable) --------
__global__ __launch_bounds__(256) void k_rownorm_i8(const ushort_t* __restrict__ in,
        int8_t* __restrict__ outp, float* __restrict__ sca, const int* __restrict__ cnt){
  int w = threadIdx.x >> 6, l = threadIdx.x & 63;
  int row = blockIdx.x*4 + w;
  if (cnt){ int b = row >> 11; if ((row & 2047) >= cnt[b]) return; }
  const ushort_t* rp = in + (size_t)row*1024 + l*16;
  float f[16]; float s = 0.f, q = 0.f;
  #pragma unroll
  for (int i = 0; i < 4; ++i){
    ushort4v u = *(const ushort4v*)(rp + i*4);
    f[i*4+0] = bf2f(u.x); f[i*4+1] = bf2f(u.y);
    f[i*4+2] = bf2f(u.z); f[i*4+3] = bf2f(u.w);
  }
  #pragma unroll
  for (int jj = 0; jj < 16; ++jj){ s += f[jj]; q += f[jj]*f[jj]; }
  wreduce2(s, q);
  float mean = s * (1.f/1024.f);
  float rstd = rsqrtf(q*(1.f/1024.f) - mean*mean + 1e-5f);
  float amax = 0.f;
  #pragma unroll
  for (int jj = 0; jj < 16; ++jj) amax = fmaxf(amax, fabsf(f[jj]-mean));
  #pragma unroll
  for (int d = 32; d; d >>= 1) amax = fmaxf(amax, __shfl_xor(amax, d));
  amax *= rstd;
  float inv = (amax > 0.f) ? 127.f/amax : 0.f;
  if (l == 0) sca[row] = amax * (1.f/127.f);
  uint32_t wds[4];
  #pragma unroll
  for (int i = 0; i < 4; ++i){
    uint32_t wd = 0;
    #pragma unroll
    for (int c = 0; c < 4; ++c){
      int qv = (int)rintf((f[i*4+c]-mean)*rstd*inv);
      wd |= ((uint32_t)(uint8_t)(int8_t)qv) << (c*8);
    }
    wds[i] = wd;
  }
  int4v pk; pk[0]=(int)wds[0]; pk[1]=(int)wds[1]; pk[2]=(int)wds[2]; pk[3]=(int)wds[3];
  *(int4v*)(outp + (size_t)row*1024 + l*16) = pk;
}

// ---------------- rownorm f32 -> i8 + per-row scale ------------------------
__global__ __launch_bounds__(256) void k_rownorm_f32_i8(const float* __restrict__ in,
        int8_t* __restrict__ outp, float* __restrict__ sca){
  int w = threadIdx.x >> 6, l = threadIdx.x & 63;
  int row = blockIdx.x*4 + w;
  const float* rp = in + (size_t)row*1024 + l*16;
  float f[16]; float s = 0.f, q = 0.f;
  #pragma unroll
  for (int i = 0; i < 4; ++i){
    float4 v = *(const float4*)(rp + i*4);
    f[i*4+0] = v.x; f[i*4+1] = v.y; f[i*4+2] = v.z; f[i*4+3] = v.w;
  }
  #pragma unroll
  for (int jj = 0; jj < 16; ++jj){ s += f[jj]; q += f[jj]*f[jj]; }
  wreduce2(s, q);
  float mean = s * (1.f/1024.f);
  float rstd = rsqrtf(q*(1.f/1024.f) - mean*mean + 1e-5f);
  float amax = 0.f;
  #pragma unroll
  for (int jj = 0; jj < 16; ++jj) amax = fmaxf(amax, fabsf(f[jj]-mean));
  #pragma unroll
  for (int d = 32; d; d >>= 1) amax = fmaxf(amax, __shfl_xor(amax, d));
  amax *= rstd;
  float inv = (amax > 0.f) ? 127.f/amax : 0.f;
  if (l == 0) sca[row] = amax * (1.f/127.f);
  uint32_t wds[4];
  #pragma unroll
  for (int i = 0; i < 4; ++i){
    uint32_t wd = 0;
    #pragma unroll
    for (int c = 0; c < 4; ++c){
      int qv = (int)rintf((f[i*4+c]-mean)*rstd*inv);
      wd |= ((uint32_t)(uint8_t)(int8_t)qv) << (c*8);
    }
    wds[i] = wd;
  }
  int4v pk; pk[0]=(int)wds[0]; pk[1]=(int)wds[1]; pk[2]=(int)wds[2]; pk[3]=(int)wds[3];
  *(int4v*)(outp + (size_t)row*1024 + l*16) = pk;
}

// ---------------- bf16 rows -> i8 + per-row scale (no norm) ----------------
template<int PER>
__global__ __launch_bounds__(256) void k_quant_rows(const ushort_t* __restrict__ in,
        int8_t* __restrict__ outp, float* __restrict__ sca){
  const int K = PER*64;
  int w = threadIdx.x >> 6, l = threadIdx.x & 63;
  int row = blockIdx.x*4 + w;
  const ushort_t* rp = in + (size_t)row*K + l*PER;
  float f[PER];
  #pragma unroll
  for (int i = 0; i < PER/4; ++i){
    ushort4v u = *(const ushort4v*)(rp + i*4);
    f[i*4+0] = bf2f(u.x); f[i*4+1] = bf2f(u.y);
    f[i*4+2] = bf2f(u.z); f[i*4+3] = bf2f(u.w);
  }
  float amax = 0.f;
  #pragma unroll
  for (int jj = 0; jj < PER; ++jj) amax = fmaxf(amax, fabsf(f[jj]));
  #pragma unroll
  for (int d = 32; d; d >>= 1) amax = fmaxf(amax, __shfl_xor(amax, d));
  float inv = (amax > 0.f) ? 127.f/amax : 0.f;
  if (l == 0) sca[row] = amax * (1.f/127.f);
  #pragma unroll
  for (int vq = 0; vq < PER/16; ++vq){
    int4v pk;
    #pragma unroll
    for (int i = 0; i < 4; ++i){
      uint32_t wd = 0;
      #pragma unroll
      for (int c = 0; c < 4; ++c){
        int qv = (int)rintf(f[vq*16 + i*4 + c]*inv);
        wd |= ((uint32_t)(uint8_t)(int8_t)qv) << (c*8);
      }
      pk[i] = (int)wd;
    }
    *(int4v*)(outp + (size_t)row*K + l*PER + vq*16) = pk;
  }
}

// ---------------- final layernorm (affine) f32 -> f32 ----------------------
__global__ __launch_bounds__(256) void k_final_ln(const float* __restrict__ x,
        const float* __restrict__ g, const float* __restrict__ bb, float* __restrict__ outp){
  int w = threadIdx.x >> 6, l = threadIdx.x & 63;
  int row = blockIdx.x*4 + w;
  const float* rp = x + (size_t)row*1024;
  float4 v[4]; float s = 0.f, q = 0.f;
  #pragma unroll
  for (int i = 0; i < 4; ++i){
    v[i] = *(const float4*)(rp + i*256 + l*4);
    s += v[i].x+v[i].y+v[i].z+v[i].w;
    q += v[i].x*v[i].x+v[i].y*v[i].y+v[i].z*v[i].z+v[i].w*v[i].w;
  }
  wreduce2(s, q);
  float mean = s * (1.f/1024.f);
  float rstd = rsqrtf(q*(1.f/1024.f) - mean*mean + 1e-5f);
  float* op = outp + (size_t)row*1024;
  #pragma unroll
  for (int i = 0; i < 4; ++i){
    float4 gg = *(const float4*)(g + i*256 + l*4);
    float4 bv = *(const float4*)(bb + i*256 + l*4);
    float4 o;
    o.x = (v[i].x-mean)*rstd*gg.x + bv.x; o.y = (v[i].y-mean)*rstd*gg.y + bv.y;
    o.z = (v[i].z-mean)*rstd*gg.z + bv.z; o.w = (v[i].w-mean)*rstd*gg.w + bv.w;
    *(float4*)(op + i*256 + l*4) = o;
  }
}

// ---------------- x init ----------------------------------------------------
__global__ __launch_bounds__(256) void k_init_x(const float* __restrict__ lat, float* __restrict__ x){
  int v = blockIdx.x*256 + threadIdx.x;
  int row = v >> 8, cv = v & 255;
  ((float4*)x)[v] = ((const float4*)lat)[(row & 63)*256 + cv];
}

// ---------------- batched weight fold + transpose --------------------------
DEV void foldT_body(const float* __restrict__ W, const float* __restrict__ g,
                    float scale, ushort_t* __restrict__ Wt, int K, int N,
                    int n0, int k0){
  __shared__ float Ts[64][65];
  int t = threadIdx.x;
  #pragma unroll
  for (int i = 0; i < 4; ++i){
    int flat = i*1024 + t*4; int r = flat >> 6, c = flat & 63;
    float4 v = *(const float4*)(W + (size_t)(k0+r)*N + n0 + c);
    float gg = (g ? g[k0+r] : 1.f) * scale;
    Ts[r][c] = v.x*gg; Ts[r][c+1] = v.y*gg; Ts[r][c+2] = v.z*gg; Ts[r][c+3] = v.w*gg;
  }
  __syncthreads();
  #pragma unroll
  for (int i = 0; i < 4; ++i){
    int flat = i*1024 + t*4; int rn = flat >> 6, ck = flat & 63;
    ushort4v o;
    o.x = f2bf(Ts[ck][rn]);   o.y = f2bf(Ts[ck+1][rn]);
    o.z = f2bf(Ts[ck+2][rn]); o.w = f2bf(Ts[ck+3][rn]);
    *(ushort4v*)(Wt + (size_t)(n0+rn)*K + k0 + ck) = o;
  }
}

struct FDesc { const float* W; const float* g; ushort_t* dst; float scale; int K; int N; };
#define MAXFD 32
struct FoldTArgs { int cnt; FDesc d[MAXFD]; };

__global__ __launch_bounds__(256) void k_foldT_all(FoldTArgs a){
  const FDesc d = a.d[blockIdx.y];
  int nxb = d.N >> 6;
  int n0 = (blockIdx.x % nxb) * 64;
  int k0 = (blockIdx.x / nxb) * 64;
  if (k0 >= d.K) return;
  foldT_body(d.W, d.g, d.scale, d.dst, d.K, d.N, n0, k0);
}

// ---------------- batched bias fold ----------------------------------------
DEV void foldBias_body(const float* __restrict__ W, const float* __restrict__ bvec,
                       float scale, float* __restrict__ bias, int K, int N, int o0){
  int t = threadIdx.x;
  int ol = t & 31, kc = t >> 5;
  int o = o0 + ol;
  int chunk = K >> 3;
  int c0 = kc*chunk, c1 = c0 + chunk;
  float s0 = 0, s1 = 0, s2 = 0, s3 = 0;
  for (int c = c0; c < c1; c += 4){
    s0 += bvec[c+0]*W[(size_t)(c+0)*N + o];
    s1 += bvec[c+1]*W[(size_t)(c+1)*N + o];
    s2 += bvec[c+2]*W[(size_t)(c+2)*N + o];
    s3 += bvec[c+3]*W[(size_t)(c+3)*N + o];
  }
  __shared__ float red[8][32];
  red[kc][ol] = (s0+s1)+(s2+s3);
  __syncthreads();
  if (kc == 0){
    float tot = 0;
    #pragma unroll
    for (int jj = 0; jj < 8; ++jj) tot += red[jj][ol];
    bias[o] = tot * scale;
  }
}

struct BDesc { const float* W; const float* b; float* dst; float scale; int K; int N; };
#define MAXBD 25
struct BiasArgs { int cnt; BDesc d[MAXBD]; };

__global__ __launch_bounds__(256) void k_foldBias_all(BiasArgs a){
  const BDesc d = a.d[blockIdx.y];
  int o0 = blockIdx.x * 32;
  if (o0 >= d.N) return;
  foldBias_body(d.W, d.b, d.scale, d.dst, d.K, d.N, o0);
}

// ---------------- 64-row i8 GEMM (small shapes, 2+ blocks/CU) --------------
// BM=64; BN in {64,128}. 4 waves in 2x2 quadrants: wave = (BM/2)x(BN/2) out.
// LDS layout: row-major 64B K-windows, 16B chunks, chunk ^= (row&3) swizzle
// (applied on the pre-swizzled global source; gload_lds dest stays linear).
// OUTMODE: 0 = bf16 store, 1 = bf16 relu store, 2 = f32 accumulate.
template<int OUTMODE, int BN>
__global__ __launch_bounds__(256, 4) void k_gemm_sm(const int8_t* __restrict__ A,
        const int8_t* __restrict__ Bt, const float* __restrict__ sAr,
        const float* __restrict__ sBr, const float* __restrict__ bias,
        void* __restrict__ Cp, int M, int N, int Kb){
  constexpr int BM = 64;
  constexpr int NIF = BN/32;          // col frags per wave (2 or 4)
  const int n0 = blockIdx.x * BN;
  const int m0 = blockIdx.y * BM;
  __shared__ __align__(16) char sA[2][BM*64];
  __shared__ __align__(16) char sB[2][BN*64];
  const int tid = threadIdx.x;
  const int wave = tid >> 6, lane = tid & 63;
  const int lo = lane & 15, hi = lane >> 4;
  const int wr = wave >> 1, wc = wave & 1;

  auto stage = [&](int buf, int k0){          // k0 in BYTES
    {
      int r = tid >> 2;
      int c = (tid & 3) ^ (r & 3);
      const int8_t* gp = A + (size_t)(m0 + r)*Kb + k0 + c*16;
      GLOAD16(gp, &sA[buf][0] + tid*16);
    }
    #pragma unroll
    for (int p = 0; p < BN/64; ++p){
      int r = p*64 + (tid >> 2);
      int c = (tid & 3) ^ (r & 3);
      const int8_t* gp = Bt + (size_t)(n0 + r)*Kb + k0 + c*16;
      GLOAD16(gp, &sB[buf][0] + p*4096 + tid*16);
    }
  };

  int4v acc[2][NIF] = {};
  stage(0, 0);
  const int nk = Kb >> 6;
  for (int ks = 0; ks < nk; ++ks){
    __syncthreads();
    if (ks + 1 < nk) stage((ks+1)&1, (ks+1) << 6);
    const int buf = ks & 1;
    int4v af[2], bfr[NIF];
    #pragma unroll
    for (int mi = 0; mi < 2; ++mi){
      int row = wr*(BM/2) + mi*16 + lo;
      af[mi] = *(const int4v*)(&sA[buf][row*64 + ((hi ^ (row & 3))*16)]);
    }
    #pragma unroll
    for (int ni = 0; ni < NIF; ++ni){
      int row = wc*(BN/2) + ni*16 + lo;
      bfr[ni] = *(const int4v*)(&sB[buf][row*64 + ((hi ^ (row & 3))*16)]);
    }
    #pragma unroll
    for (int mi = 0; mi < 2; ++mi)
      #pragma unroll
      for (int ni = 0; ni < NIF; ++ni)
        acc[mi][ni] = MFMAI8(af[mi], bfr[ni], acc[mi][ni]);
  }
  #pragma unroll
  for (int ni = 0; ni < NIF; ++ni){
    int col = n0 + wc*(BN/2) + ni*16 + lo;
    float bv = bias ? bias[col] : 0.f;
    float sb = sBr[col];
    #pragma unroll
    for (int mi = 0; mi < 2; ++mi){
      int rbase = m0 + wr*(BM/2) + mi*16 + hi*4;
      #pragma unroll
      for (int rr = 0; rr < 4; ++rr){
        int row = rbase + rr;
        float v = (float)acc[mi][ni][rr] * (sAr[row]*sb) + bv;
        size_t off = (size_t)row*N + col;
        if (OUTMODE == 0)      ((ushort_t*)Cp)[off] = f2bf(v);
        else if (OUTMODE == 1) ((ushort_t*)Cp)[off] = f2bf(fmaxf(v, 0.f));
        else                   ((float*)Cp)[off] += v;
      }
    }
  }
}

// ---------------- 256x256 8-phase bf16 GEMM (down-proj) --------------------
template<bool SKIP, int NXB>
__global__ __launch_bounds__(512, 2) void k_gemm256p8(const ushort_t* __restrict__ A,
        const ushort_t* __restrict__ Bt, const float* __restrict__ bias,
        ushort_t* __restrict__ Cp, int M, int N, int K, const int* __restrict__ cnt){
  int bx, by;
  xcd_remapN<NXB>(blockIdx.x, gridDim.x, bx, by);
  const int n0 = bx * 256;
  const int m0 = by * 256;
  if (SKIP){ int b = m0 >> 11; if ((m0 & 2047) >= cnt[b]) return; }
  __shared__ __align__(16) ushort_t sA[2][256*64];
  __shared__ __align__(16) ushort_t sB[2][256*64];
  const int tid = threadIdx.x;
  const int wave = tid >> 6, lane = tid & 63;
  const int lo = lane & 15, hi = lane >> 4;
  const int wm = wave >> 2, wn = wave & 3;
  const int srow = lane >> 3;
  const int schunk = (lane & 7) ^ srow;
  auto stageHalf = [&](ushort_t* dst, const ushort_t* __restrict__ G, int grow0,
                       int half, int k0){
    #pragma unroll
    for (int p = 0; p < 2; ++p){
      int rbase = half*128 + p*64 + wave*8;
      const ushort_t* gp = G + (size_t)(grow0 + rbase + srow)*K + k0 + schunk*8;
      char* lp = (char*)dst + (size_t)rbase*128;
      GLOAD16(gp, lp);
    }
  };
  auto ldsA = [&](int buf, int row, int kk)->short8{
    int ch = ((kk<<2) + hi) ^ (row & 7);
    return *(const short8*)((const char*)sA + (size_t)buf*32768 + (size_t)row*128 + ch*16);
  };
  auto ldsB = [&](int buf, int row, int kk)->short8{
    int ch = ((kk<<2) + hi) ^ (row & 7);
    return *(const short8*)((const char*)sB + (size_t)buf*32768 + (size_t)row*128 + ch*16);
  };
  f32x4 acc[8][4] = {};

  short8 af[4][2], bg[2][2];
#define LOADA(BUF, AH) \
    _Pragma("unroll") for (int mi_ = 0; mi_ < 4; ++mi_) \
      _Pragma("unroll") for (int kk_ = 0; kk_ < 2; ++kk_) \
        af[mi_][kk_] = ldsA(BUF, (AH)*128 + wm*64 + mi_*16 + lo, kk_);
#define LOADB(BUF, BH) \
    _Pragma("unroll") for (int nj_ = 0; nj_ < 2; ++nj_) \
      _Pragma("unroll") for (int kk_ = 0; kk_ < 2; ++kk_) \
        bg[nj_][kk_] = ldsB(BUF, (BH)*128 + wn*32 + nj_*16 + lo, kk_);
#define MMQ(AH, BH) \
    __builtin_amdgcn_s_barrier(); CFENCE; \
    __builtin_amdgcn_s_setprio(1); \
    _Pragma("unroll") for (int mi_ = 0; mi_ < 4; ++mi_) \
      _Pragma("unroll") for (int nj_ = 0; nj_ < 2; ++nj_) \
        _Pragma("unroll") for (int kk_ = 0; kk_ < 2; ++kk_) \
          acc[(AH)*4+mi_][(BH)*2+nj_] = \
            MFMA16(af[mi_][kk_], bg[nj_][kk_], acc[(AH)*4+mi_][(BH)*2+nj_]); \
    __builtin_amdgcn_s_setprio(0); CFENCE; \
    __builtin_amdgcn_s_barrier(); CFENCE;

  stageHalf(&sA[0][0], A,  m0, 0, 0);
  stageHalf(&sB[0][0], Bt, n0, 0, 0);
  stageHalf(&sA[0][0], A,  m0, 1, 0);
  stageHalf(&sB[0][0], Bt, n0, 1, 0);
  stageHalf(&sA[1][0], A,  m0, 0, 64);
  stageHalf(&sB[1][0], Bt, n0, 1, 64);
  VMCNT(4);
  __builtin_amdgcn_s_barrier();
  CFENCE;

  const int NI = K >> 7;
  for (int i = 0; i < NI; ++i){
    const int kt = i << 7;
    const bool lastI = (i == NI-1);
    LOADA(0,0) LOADB(0,0)
    stageHalf(&sA[1][0], A,  m0, 1, kt+64);
    MMQ(0,0)
    LOADB(0,1)
    stageHalf(&sB[1][0], Bt, n0, 0, kt+64);
    MMQ(0,1)
    LOADA(0,1)
    if (!lastI) stageHalf(&sA[0][0], A,  m0, 0, kt+128);
    MMQ(1,1)
    LOADB(0,0)
    if (!lastI) stageHalf(&sB[0][0], Bt, n0, 1, kt+128);
    if (lastI){ VMCNT(0); } else { VMCNT(4); }
    MMQ(1,0)
    LOADA(1,0) LOADB(1,0)
    if (!lastI) stageHalf(&sA[0][0], A,  m0, 1, kt+128);
    MMQ(0,0)
    LOADB(1,1)
    if (!lastI) stageHalf(&sB[0][0], Bt, n0, 0, kt+128);
    MMQ(0,1)
    LOADA(1,1)
    if (!lastI) stageHalf(&sA[1][0], A,  m0, 0, kt+192);
    MMQ(1,1)
    LOADB(1,0)
    if (!lastI){ stageHalf(&sB[1][0], Bt, n0, 1, kt+192); VMCNT(4); }
    MMQ(1,0)
  }
#undef LOADA
#undef LOADB
#undef MMQ

  #pragma unroll
  for (int b2 = 0; b2 < 2; ++b2)
    #pragma unroll
    for (int nj = 0; nj < 2; ++nj){
      int col = n0 + b2*128 + wn*32 + nj*16 + lo;
      float bv = bias ? bias[col] : 0.f;
      #pragma unroll
      for (int a2 = 0; a2 < 2; ++a2)
        #pragma unroll
        for (int mi4 = 0; mi4 < 4; ++mi4){
          int rbase = m0 + a2*128 + wm*64 + mi4*16 + hi*4;
          #pragma unroll
          for (int rr = 0; rr < 4; ++rr){
            float v = acc[a2*4+mi4][b2*2+nj][rr] + bv;
            Cp[(size_t)(rbase + rr)*N + col] = f2bf(v);
          }
        }
    }
}

// ---------------- 256x256 8-phase i8 GEMM (KV projections) -----------------
template<bool SKIP, int NXB>
__global__ __launch_bounds__(512, 2) void k_gemm256i8(const int8_t* __restrict__ A,
        const int8_t* __restrict__ Bt, const float* __restrict__ sAr,
        const float* __restrict__ sBr, const float* __restrict__ bias,
        ushort_t* __restrict__ Cp, int M, int N, int Kb, const int* __restrict__ cnt){
  int bx, by;
  xcd_remapN<NXB>(blockIdx.x, gridDim.x, bx, by);
  const int n0 = bx * 256;
  const int m0 = by * 256;
  if (SKIP){ int b = m0 >> 11; if ((m0 & 2047) >= cnt[b]) return; }
  __shared__ __align__(16) char sAl[2][256*128];
  __shared__ __align__(16) char sBl[2][256*128];
  const int tid = threadIdx.x;
  const int wave = tid >> 6, lane = tid & 63;
  const int lo = lane & 15, hi = lane >> 4;
  const int wm = wave >> 2, wn = wave & 3;
  const int srow = lane >> 3;
  const int schunk = (lane & 7) ^ srow;
  auto stageHalf = [&](char* dst, const int8_t* __restrict__ G, int grow0,
                       int half, int k0){            // k0 in BYTES
    #pragma unroll
    for (int p = 0; p < 2; ++p){
      int rbase = half*128 + p*64 + wave*8;
      const int8_t* gp = G + (size_t)(grow0 + rbase + srow)*Kb + k0 + schunk*16;
      char* lp = dst + (size_t)rbase*128;
      GLOAD16(gp, lp);
    }
  };
  auto ldsA = [&](int buf, int row, int kk)->int4v{
    int ch = ((kk<<2) + hi) ^ (row & 7);
    return *(const int4v*)((const char*)sAl + (size_t)buf*32768 + (size_t)row*128 + ch*16);
  };
  auto ldsB = [&](int buf, int row, int kk)->int4v{
    int ch = ((kk<<2) + hi) ^ (row & 7);
    return *(const int4v*)((const char*)sBl + (size_t)buf*32768 + (size_t)row*128 + ch*16);
  };
  int4v acc[8][4] = {};

  int4v af[4][2], bg[2][2];
#define LOADA(BUF, AH) \
    _Pragma("unroll") for (int mi_ = 0; mi_ < 4; ++mi_) \
      _Pragma("unroll") for (int kk_ = 0; kk_ < 2; ++kk_) \
        af[mi_][kk_] = ldsA(BUF, (AH)*128 + wm*64 + mi_*16 + lo, kk_);
#define LOADB(BUF, BH) \
    _Pragma("unroll") for (int nj_ = 0; nj_ < 2; ++nj_) \
      _Pragma("unroll") for (int kk_ = 0; kk_ < 2; ++kk_) \
        bg[nj_][kk_] = ldsB(BUF, (BH)*128 + wn*32 + nj_*16 + lo, kk_);
#define MMQ(AH, BH) \
    __builtin_amdgcn_s_barrier(); CFENCE; \
    __builtin_amdgcn_s_setprio(1); \
    _Pragma("unroll") for (int mi_ = 0; mi_ < 4; ++mi_) \
      _Pragma("unroll") for (int nj_ = 0; nj_ < 2; ++nj_) \
        _Pragma("unroll") for (int kk_ = 0; kk_ < 2; ++kk_) \
          acc[(AH)*4+mi_][(BH)*2+nj_] = \
            MFMAI8(af[mi_][kk_], bg[nj_][kk_], acc[(AH)*4+mi_][(BH)*2+nj_]); \
    __builtin_amdgcn_s_setprio(0); CFENCE; \
    __builtin_amdgcn_s_barrier(); CFENCE;

  stageHalf(&sAl[0][0], A,  m0, 0, 0);
  stageHalf(&sBl[0][0], Bt, n0, 0, 0);
  stageHalf(&sAl[0][0], A,  m0, 1, 0);
  stageHalf(&sBl[0][0], Bt, n0, 1, 0);
  stageHalf(&sAl[1][0], A,  m0, 0, 128);
  stageHalf(&sBl[1][0], Bt, n0, 1, 128);
  VMCNT(4);
  __builtin_amdgcn_s_barrier();
  CFENCE;

  const int NI = Kb >> 8;
  for (int i = 0; i < NI; ++i){
    const int kt = i << 8;
    const bool lastI = (i == NI-1);
    LOADA(0,0) LOADB(0,0)
    stageHalf(&sAl[1][0], A,  m0, 1, kt+128);
    MMQ(0,0)
    LOADB(0,1)
    stageHalf(&sBl[1][0], Bt, n0, 0, kt+128);
    MMQ(0,1)
    LOADA(0,1)
    if (!lastI) stageHalf(&sAl[0][0], A,  m0, 0, kt+256);
    MMQ(1,1)
    LOADB(0,0)
    if (!lastI) stageHalf(&sBl[0][0], Bt, n0, 1, kt+256);
    if (lastI){ VMCNT(0); } else { VMCNT(4); }
    MMQ(1,0)
    LOADA(1,0) LOADB(1,0)
    if (!lastI) stageHalf(&sAl[0][0], A,  m0, 1, kt+256);
    MMQ(0,0)
    LOADB(1,1)
    if (!lastI) stageHalf(&sBl[0][0], Bt, n0, 0, kt+256);
    MMQ(0,1)
    LOADA(1,1)
    if (!lastI) stageHalf(&sAl[1][0], A,  m0, 0, kt+384);
    MMQ(1,1)
    LOADB(1,0)
    if (!lastI){ stageHalf(&sBl[1][0], Bt, n0, 1, kt+384); VMCNT(4); }
    MMQ(1,0)
  }
#undef LOADA
#undef LOADB
#undef MMQ

  #pragma unroll
  for (int b2 = 0; b2 < 2; ++b2)
    #pragma unroll
    for (int nj = 0; nj < 2; ++nj){
      int col = n0 + b2*128 + wn*32 + nj*16 + lo;
      float bv = bias ? bias[col] : 0.f;
      float sb = sBr[col];
      #pragma unroll
      for (int a2 = 0; a2 < 2; ++a2)
        #pragma unroll
        for (int mi4 = 0; mi4 < 4; ++mi4){
          int rbase = m0 + a2*128 + wm*64 + mi4*16 + hi*4;
          #pragma unroll
          for (int rr = 0; rr < 4; ++rr){
            int row = rbase + rr;
            float v = (float)acc[a2*4+mi4][b2*2+nj][rr] * (sAr[row]*sb) + bv;
            Cp[(size_t)row*N + col] = f2bf(v);
          }
        }
    }
}

// ---------------- flash attention (pipelined): one block per (b,h) ---------
__global__ __launch_bounds__(256) void k_attn(const ushort_t* __restrict__ qb,
        const ushort_t* __restrict__ kvb, int kstride, const int* __restrict__ cnt,
        ushort_t* __restrict__ outb){
  const int bh = blockIdx.x;
  const int b = bh >> 4, h = bh & 15;
  const int t = threadIdx.x;
  const int wave = t >> 6, lane = t & 63, lo = lane & 15, hi = lane >> 4;
  __shared__ ushort_t Qs[64*64];
  __shared__ ushort_t Ks[2][64*64];
  __shared__ ushort_t Vt[2][64][72];
  __shared__ ushort_t Ps[4][16][72];

  const int count = cnt[b];

  #pragma unroll
  for (int p = 0; p < 2; ++p){
    int r = p*32 + wave*8 + (lane >> 3);
    int c = (lane & 7) ^ (r & 7);
    const ushort_t* gp = qb + (size_t)(b*64 + r)*1024 + h*64 + c*8;
    char* lp = (char*)Qs + p*4096 + wave*1024;
    GLOAD16(gp, lp);
  }

  auto stageK = [&](int buf, int tt){
    #pragma unroll
    for (int p = 0; p < 2; ++p){
      int r = p*32 + wave*8 + (lane >> 3);
      int c = (lane & 7) ^ (r & 7);
      const ushort_t* gp = kvb + (size_t)(b*2048 + tt*64 + r)*kstride + h*64 + c*8;
      char* lp = (char*)(&Ks[buf][0]) + p*4096 + wave*1024;
      GLOAD16(gp, lp);
    }
  };
  const int vjj = (t & 31)*2, vc = (t >> 5)*8;
  ushort4v va0, va1, vb0, vb1;
  auto issueV = [&](int tt){
    const ushort_t* g0 = kvb + (size_t)(b*2048 + tt*64 + vjj)*kstride + 1024 + h*64 + vc;
    va0 = *(const ushort4v*)(g0);
    va1 = *(const ushort4v*)(g0 + 4);
    vb0 = *(const ushort4v*)(g0 + kstride);
    vb1 = *(const ushort4v*)(g0 + kstride + 4);
  };
  auto writeV = [&](int buf, int tt){
    bool va  = (tt*64 + vjj)     < count;
    bool vb2 = (tt*64 + vjj + 1) < count;
    #pragma unroll
    for (int u = 0; u < 8; ++u){
      ushort_t ea = (u < 4) ? ((ushort_t*)&va0)[u] : ((ushort_t*)&va1)[u-4];
      ushort_t eb = (u < 4) ? ((ushort_t*)&vb0)[u] : ((ushort_t*)&vb1)[u-4];
      uint32_t word = (va ? (uint32_t)ea : 0u) | ((vb2 ? (uint32_t)eb : 0u) << 16);
      *(uint32_t*)(&Vt[buf][vc+u][vjj]) = word;
    }
  };

  f32x4 oacc[4] = {};
  float m[4], l[4];
  #pragma unroll
  for (int rr = 0; rr < 4; ++rr){ m[rr] = -__builtin_inff(); l[rr] = 0.f; }

  const int ntiles = (count + 63) >> 6;
  if (ntiles > 0){ stageK(0, 0); issueV(0); }

  for (int tt = 0; tt < ntiles; ++tt){
    const int buf = tt & 1;
    writeV(buf, tt);
    if (tt + 1 < ntiles){ stageK(buf^1, tt+1); issueV(tt+1); }
    asm volatile("s_waitcnt lgkmcnt(0)" ::: "memory");
    __builtin_amdgcn_s_barrier();
    CFENCE;

    f32x4 s[4] = {};
    #pragma unroll
    for (int kk = 0; kk < 2; ++kk){
      int rA = wave*16 + lo;
      short8 aq = *(const short8*)(&Qs[rA*64 + (((kk*4 + hi) ^ (rA & 7))*8)]);
      #pragma unroll
      for (int ni = 0; ni < 4; ++ni){
        int rB = ni*16 + lo;
        short8 bk = *(const short8*)(&Ks[buf][rB*64 + (((kk*4 + hi) ^ (rB & 7))*8)]);
        s[ni] = MFMA16(aq, bk, s[ni]);
      }
    }
    #pragma unroll
    for (int ni = 0; ni < 4; ++ni){
      if (tt*64 + ni*16 + lo >= count){
        s[ni][0] = s[ni][1] = s[ni][2] = s[ni][3] = -__builtin_inff();
      }
    }
    float p[4][4];
    #pragma unroll
    for (int rr = 0; rr < 4; ++rr){
      float mx = fmaxf(fmaxf(s[0][rr], s[1][rr]), fmaxf(s[2][rr], s[3][rr]));
      #pragma unroll
      for (int d = 1; d < 16; d <<= 1) mx = fmaxf(mx, __shfl_xor(mx, d));
      float mnew = fmaxf(m[rr], mx);
      float sc = __expf(m[rr] - mnew);
      float rsum = 0.f;
      #pragma unroll
      for (int ni = 0; ni < 4; ++ni){
        float pv = __expf(s[ni][rr] - mnew);
        p[ni][rr] = pv;
        rsum += pv;
      }
      #pragma unroll
      for (int d = 1; d < 16; d <<= 1) rsum += __shfl_xor(rsum, d);
      l[rr] = l[rr]*sc + rsum;
      m[rr] = mnew;
      #pragma unroll
      for (int ni = 0; ni < 4; ++ni) oacc[ni][rr] *= sc;
    }
    #pragma unroll
    for (int ni = 0; ni < 4; ++ni)
      #pragma unroll
      for (int rr = 0; rr < 4; ++rr)
        Ps[wave][hi*4+rr][ni*16+lo] = f2bf(p[ni][rr]);
    asm volatile("s_waitcnt lgkmcnt(0)" ::: "memory");
    #pragma unroll
    for (int kk = 0; kk < 2; ++kk){
      short8 pa = *(const short8*)(&Ps[wave][lo][kk*32 + hi*8]);
      #pragma unroll
      for (int ni = 0; ni < 4; ++ni){
        short8 bv = *(const short8*)(&Vt[buf][ni*16 + lo][kk*32 + hi*8]);
        oacc[ni] = MFMA16(pa, bv, oacc[ni]);
      }
    }
    CFENCE;
    __builtin_amdgcn_s_barrier();
    CFENCE;
  }
  #pragma unroll
  for (int rr = 0; rr < 4; ++rr){
    float inv = (l[rr] > 0.f) ? 1.f/l[rr] : 0.f;
    #pragma unroll
    for (int ni = 0; ni < 4; ++ni){
      size_t off = (size_t)(b*64 + wave*16 + hi*4 + rr)*1024 + h*64 + ni*16 + lo;
      outb[off] = f2bf(oacc[ni][rr] * inv);
    }
  }
}

// ---------------------------------------------------------------------------
extern "C" void kernel_launch(void* const* d_in, const int* in_sizes, int n_in,
                              void* d_out, int out_size, void* d_ws, size_t ws_size,
                              hipStream_t stream){
  const float* features = (const float*)d_in[0];
  const int*   mask     = (const int*)  d_in[1];
  const float* latents  = (const float*)d_in[2];
  const float* W_down   = (const float*)d_in[3];
  const float* nin_g    = (const float*)d_in[4];
  const float* nin_b    = (const float*)d_in[5];
  const float* lf_g     = (const float*)d_in[6];
  const float* lf_b     = (const float*)d_in[7];
  const float* ll_g     = (const float*)d_in[8];
  const float* ll_b     = (const float*)d_in[9];
  const float* Wq       = (const float*)d_in[10];
  const float* Wk       = (const float*)d_in[11];
  const float* Wv       = (const float*)d_in[12];
  const float* ffln_g   = (const float*)d_in[13];
  const float* ffln_b   = (const float*)d_in[14];
  const float* ff_w1    = (const float*)d_in[15];
  const float* ff_w2    = (const float*)d_in[16];
  const float* nout_g   = (const float*)d_in[17];
  const float* nout_b   = (const float*)d_in[18];

  char* ws = (char*)d_ws;
  size_t off = 0;
  auto alloc = [&](size_t bytes)->char*{
    char* p = ws + off;
    off += (bytes + 255) & ~(size_t)255;
    return p;
  };
  const size_t SZW = (size_t)1024*1024*2;       // 2 MB (1024x1024 bf16)

  ushort_t* FHAT  = (ushort_t*)alloc((size_t)65536*1024*2);   // down-proj out
  int8_t*   I8A   = (int8_t*)  alloc((size_t)65536*1024);     // LN'd fhat, i8
  float*    SA    = (float*)   alloc((size_t)65536*4);
  int8_t*   I8KV  = (int8_t*)  alloc((size_t)12288*1024);     // KV weights i8
  float*    SKV   = (float*)   alloc((size_t)12288*4);
  int8_t*   I8Q   = (int8_t*)  alloc((size_t)6144*1024);      // Q weights i8
  float*    SQW   = (float*)   alloc((size_t)6144*4);
  int8_t*   I8W1  = (int8_t*)  alloc((size_t)12288*1024);     // FF1 weights i8
  float*    SW1   = (float*)   alloc((size_t)12288*4);
  int8_t*   I8W2  = (int8_t*)  alloc((size_t)6144*2048);      // FF2 weights i8 (K=2048)
  float*    SW2   = (float*)   alloc((size_t)6144*4);
  ushort_t* WDT   = (ushort_t*)alloc(SZW);
  ushort_t* WQT6  = (ushort_t*)alloc(SZW*6);
  ushort_t* WKVT6 = (ushort_t*)alloc(SZW*2*6);
  ushort_t* W1T6  = (ushort_t*)alloc(SZW*2*6);
  ushort_t* W2T6  = (ushort_t*)alloc(SZW*2*6);
  float* BD   = (float*)alloc(1024*4);
  float* BQ6  = (float*)alloc(1024*4*6);
  float* BKV6 = (float*)alloc(2048*4*6);
  float* B16  = (float*)alloc(2048*4*6);
  float*    X    = (float*)   alloc((size_t)2048*1024*4);
  int8_t*   I8X  = (int8_t*)  alloc((size_t)2048*1024);
  float*    SX   = (float*)   alloc((size_t)2048*4);
  ushort_t* QP   = (ushort_t*)alloc((size_t)2048*1024*2);
  ushort_t* OUTB = (ushort_t*)alloc((size_t)2048*1024*2);
  int8_t*   I8O  = (int8_t*)  alloc((size_t)2048*1024);
  float*    SO   = (float*)   alloc((size_t)2048*4);
  ushort_t* H1   = (ushort_t*)alloc((size_t)2048*2048*2);
  int8_t*   I8H  = (int8_t*)  alloc((size_t)2048*2048);
  float*    SH   = (float*)   alloc((size_t)2048*4);
  int* CNT = (int*)alloc(32*4);
  int* IDX = (int*)alloc((size_t)65536*4);
  ushort_t* KVBUF = (ushort_t*)alloc((size_t)65536*2048*2);   // 256 MB
  ushort_t* FNORM = KVBUF;   // transient alias (dead before KV GEMM writes)
  (void)in_sizes; (void)n_in; (void)out_size; (void)ws_size;

  const float scale = 0.125f;  // DH^-0.5

  // ---- batched weight folds (all depth-independent) ----
  FoldTArgs fa; int nf = 0;
  auto addF = [&](const float* W, const float* g, float sc, ushort_t* dst, int K, int N){
    fa.d[nf++] = FDesc{W, g, dst, sc, K, N};
  };
  addF(W_down, nin_g, 1.f, WDT, 1024, 1024);
  for (int i = 0; i < 6; ++i){
    const float* Wqi = Wq + (size_t)i*1024*1024;
    const float* Wki = Wk + (size_t)i*1024*1024;
    const float* Wvi = Wv + (size_t)i*1024*1024;
    const float* W1i = ff_w1 + (size_t)i*1024*2048;
    const float* W2i = ff_w2 + (size_t)i*2048*1024;
    addF(Wqi, ll_g + i*1024, scale, WQT6  + i*(SZW/2),        1024, 1024);
    addF(Wki, lf_g + i*1024, 1.f,   WKVT6 + i*SZW,            1024, 1024);
    addF(Wvi, lf_g + i*1024, 1.f,   WKVT6 + i*SZW + (SZW/2),  1024, 1024);
    addF(W1i, ffln_g + i*1024, 1.f, W1T6  + i*SZW,            1024, 2048);
    addF(W2i, nullptr, 1.f,         W2T6  + i*SZW,            2048, 1024);
  }
  fa.cnt = nf;

  BiasArgs ba; int nb = 0;
  auto addB = [&](const float* W, const float* b, float sc, float* dst, int K, int N){
    ba.d[nb++] = BDesc{W, b, dst, sc, K, N};
  };
  addB(W_down, nin_b, 1.f, BD, 1024, 1024);
  for (int i = 0; i < 6; ++i){
    const float* Wqi = Wq + (size_t)i*1024*1024;
    const float* Wki = Wk + (size_t)i*1024*1024;
    const float* Wvi = Wv + (size_t)i*1024*1024;
    const float* W1i = ff_w1 + (size_t)i*1024*2048;
    addB(Wqi, ll_b + i*1024, scale, BQ6  + i*1024,        1024, 1024);
    addB(Wki, lf_b + i*1024, 1.f,   BKV6 + i*2048,        1024, 1024);
    addB(Wvi, lf_b + i*1024, 1.f,   BKV6 + i*2048 + 1024, 1024, 1024);
    addB(W1i, ffln_b + i*1024, 1.f, B16  + i*2048,        1024, 2048);
  }
  ba.cnt = nb;

  // ---- setup ----
  k_compact     <<<32,    256, 0, stream>>>(mask, IDX, CNT);
  k_gather_norm <<<16384, 256, 0, stream>>>(features, IDX, CNT, FNORM);
  k_foldT_all   <<<dim3(512, nf), 256, 0, stream>>>(fa);
  k_foldBias_all<<<dim3(64,  nb), 256, 0, stream>>>(ba);
  k_quant_rows<16><<<3072, 256, 0, stream>>>(WKVT6, I8KV, SKV);  // 12288 rows K=1024
  k_quant_rows<16><<<1536, 256, 0, stream>>>(WQT6,  I8Q,  SQW);  //  6144 rows K=1024
  k_quant_rows<16><<<3072, 256, 0, stream>>>(W1T6,  I8W1, SW1);  // 12288 rows K=1024
  k_quant_rows<32><<<1536, 256, 0, stream>>>(W2T6,  I8W2, SW2);  //  6144 rows K=2048
  k_gemm256p8<true,4><<<1024, 512, 0, stream>>>(FNORM, WDT, BD, FHAT, 65536, 1024, 1024, CNT);
  k_rownorm_i8  <<<16384, 256, 0, stream>>>(FHAT, I8A, SA, CNT);
  k_init_x      <<<2048,  256, 0, stream>>>(latents, X);

  for (int i = 0; i < 6; ++i){
    k_gemm256i8<true,8><<<2048, 512, 0, stream>>>(I8A, I8KV + (size_t)i*2048*1024,
                                                  SA, SKV + i*2048, BKV6 + i*2048,
                                                  KVBUF, 65536, 2048, 1024, CNT);
    k_rownorm_f32_i8<<<512, 256, 0, stream>>>(X, I8X, SX);
    k_gemm_sm<0,64><<<dim3(16,32), 256, 0, stream>>>(I8X, I8Q + (size_t)i*1024*1024,
                                                     SX, SQW + i*1024, BQ6 + i*1024,
                                                     QP, 2048, 1024, 1024);
    k_attn<<<512, 256, 0, stream>>>(QP, KVBUF, 2048, CNT, OUTB);
    k_rownorm_i8<<<512, 256, 0, stream>>>(OUTB, I8O, SO, nullptr);
    k_gemm_sm<1,128><<<dim3(16,32), 256, 0, stream>>>(I8O, I8W1 + (size_t)i*2048*1024,
                                                      SO, SW1 + i*2048, B16 + i*2048,
                                                      H1, 2048, 2048, 1024);
    k_quant_rows<32><<<512, 256, 0, stream>>>(H1, I8H, SH);
    k_gemm_sm<2,64><<<dim3(16,32), 256, 0, stream>>>(I8H, I8W2 + (size_t)i*1024*2048,
                                                     SH, SW2 + i*1024, nullptr,
                                                     X, 2048, 1024, 2048);
  }
  k_final_ln<<<512, 256, 0, stream>>>(X, nout_g, nout_b, (float*)d_out);
}